// Round 3
// baseline (391.222 us; speedup 1.0000x reference)
//
#include <hip/hip_runtime.h>
#include <stdint.h>

typedef unsigned short u16;
typedef __bf16 bf16x8 __attribute__((ext_vector_type(8)));
typedef float f32x4 __attribute__((ext_vector_type(4)));

#define SEQ    2048
#define NHEAD  16
#define DH     64
#define DMODEL 1024
#define NBH    64     // B*H

__device__ __forceinline__ u16 f2bf(float f){
  union { float f; uint32_t i; } v; v.f = f;
  uint32_t x = v.i;
  return (u16)((x + 0x7fffu + ((x >> 16) & 1u)) >> 16);
}
__device__ __forceinline__ float bf2f(u16 u){
  union { uint32_t i; float f; } v; v.i = ((uint32_t)u) << 16; return v.f;
}

typedef const __attribute__((address_space(1))) uint32_t* gas_t;
typedef __attribute__((address_space(3))) uint32_t* las_t;
__device__ __forceinline__ void async16(const void* g, void* l){
  __builtin_amdgcn_global_load_lds((gas_t)g, (las_t)l, 16, 0, 0);
}

// ---------------- f32 -> bf16 convert (vectorized, memory-bound) ------------
__global__ void cvt_f32_bf16(const float* __restrict__ src, u16* __restrict__ dst, int n){
  int t = (blockIdx.x*blockDim.x + threadIdx.x)*4;
  if (t >= n) return;
  float4 v = *(const float4*)(src + t);
  ushort4 o;
  o.x = f2bf(v.x); o.y = f2bf(v.y); o.z = f2bf(v.z); o.w = f2bf(v.w);
  *(ushort4*)(dst + t) = o;
}

// ---------------- RoPE table: [2048][32] interleaved (cos,sin) pairs --------
__global__ void rope_table(float* __restrict__ tab){
  int t = blockIdx.x * blockDim.x + threadIdx.x;
  if (t >= SEQ*32) return;
  int s = t >> 5, j = t & 31;
  double freq = exp(-(double)(2*j) / 64.0 * log(10000.0));
  double ang = (double)s * freq;
  tab[s*64 + 2*j]     = (float)cos(ang);
  tab[s*64 + 2*j + 1] = (float)sin(ang);
}

// ---------------- GEMM: dst = A @ W^T + bias  (bf16 in, NT layout) ----------
// MODE 0: fused QKV (N=3072): scatter bf16 to per-head [B,H,S,Dh]; RoPE fused
//         into epilogue for q,k (wave's 64-col chunk == one full head).
// MODE 1: f32 dst linear [M][1024]
template<int MODE>
__global__ __launch_bounds__(256, 2)
void gemm_bt(const u16* __restrict__ A, const u16* __restrict__ W,
             const float* __restrict__ bias, float* __restrict__ fout,
             u16* __restrict__ dq, u16* __restrict__ dk, u16* __restrict__ dv,
             const float* __restrict__ tab)
{
  __shared__ u16 Ab[128*32];
  __shared__ u16 Bb[128*32];
  const int tid = threadIdx.x;
  const int lane = tid & 63;
  const int w = tid >> 6, wr = w >> 1, wc = w & 1;
  const int m0 = blockIdx.y * 128;
  const int n0 = blockIdx.x * 128;
  const int c0 = lane & 15, g = lane >> 4;

  f32x4 acc[4][4] = {};

  const int sr = tid >> 2;          // staging row 0..63
  const int sc = (tid & 3) * 8;     // staging col (elements)
  const u16* ga = A + (size_t)(m0 + sr) * DMODEL + sc;
  const u16* gb = W + (size_t)(n0 + sr) * DMODEL + sc;
  u16* la = Ab + sr*32 + sc;
  u16* lb = Bb + sr*32 + sc;

  for (int k0 = 0; k0 < DMODEL; k0 += 32) {
    __syncthreads();
    async16(ga + k0,             la);
    async16(ga + k0 + 64*DMODEL, la + 64*32);
    async16(gb + k0,             lb);
    async16(gb + k0 + 64*DMODEL, lb + 64*32);
    __syncthreads();
    bf16x8 afr[4], bfr[4];
#pragma unroll
    for (int i=0;i<4;i++) afr[i] = *(const bf16x8*)(Ab + (wr*64 + i*16 + c0)*32 + g*8);
#pragma unroll
    for (int j=0;j<4;j++) bfr[j] = *(const bf16x8*)(Bb + (wc*64 + j*16 + c0)*32 + g*8);
#pragma unroll
    for (int i=0;i<4;i++)
#pragma unroll
      for (int j=0;j<4;j++)
        acc[i][j] = __builtin_amdgcn_mfma_f32_16x16x32_bf16(afr[i], bfr[j], acc[i][j], 0,0,0);
  }

  const int nbase = n0 + wc*64;
  float bv4[4];
#pragma unroll
  for (int j=0;j<4;j++) bv4[j] = bias[nbase + j*16 + c0];

  if (MODE == 0) {
    const int t = n0 >> 10;                 // 0=q 1=k 2=v (tile never crosses)
    u16* dst = (t==0) ? dq : (t==1) ? dk : dv;
    const int h = (nbase >> 6) & (NHEAD-1);
#pragma unroll
    for (int i=0;i<4;i++){
      const int mbase = m0 + wr*64 + i*16 + g*4;
#pragma unroll
      for (int r=0;r<4;r++){
        const int mm = mbase + r;
        const int bb = mm >> 11, s = mm & (SEQ-1);
        const size_t rowbase = (((size_t)(bb*NHEAD + h))*SEQ + s)*DH;
        if (t < 2) {
          // RoPE fused: pair (dh, dh+32) = (acc[i][j2], acc[i][j2+2])
#pragma unroll
          for (int j2=0;j2<2;j2++){
            const int dh = j2*16 + c0;
            const float xl = acc[i][j2][r]   + bv4[j2];
            const float xh = acc[i][j2+2][r] + bv4[j2+2];
            const float2 cs = *(const float2*)(tab + (size_t)s*64 + dh*2);
            dst[rowbase + dh]      = f2bf(xl*cs.x - xh*cs.y);
            dst[rowbase + dh + 32] = f2bf(xh*cs.x + xl*cs.y);
          }
        } else {
#pragma unroll
          for (int j=0;j<4;j++)
            dst[rowbase + j*16 + c0] = f2bf(acc[i][j][r] + bv4[j]);
        }
      }
    }
  } else {
#pragma unroll
    for (int i=0;i<4;i++){
      const int mbase = m0 + wr*64 + i*16 + g*4;
#pragma unroll
      for (int j=0;j<4;j++){
#pragma unroll
        for (int r=0;r<4;r++)
          fout[(size_t)(mbase + r) * DMODEL + nbase + j*16 + c0] = acc[i][j][r] + bv4[j];
      }
    }
  }
}

// ---------------- Flash attention, causal, paired q-tiles, dbuf K/V ---------
__global__ __launch_bounds__(256, 3)
void attn_fwd(const u16* __restrict__ Q, const u16* __restrict__ K,
              const u16* __restrict__ V, u16* __restrict__ O)
{
  __shared__ u16 Kb[2][64*64];  // [kv][dh], XOR-swizzled (pre-swizzled source)
  __shared__ u16 Vt[2][64*64];  // [dh][kv], XOR-swizzled
  __shared__ u16 Pb[128*64];    // [q][kv] per-wave regions, XOR-swizzled
  const int pair = blockIdx.x;              // 0..7
  const int bh = blockIdx.y;
  const int tid = threadIdx.x, lane = tid & 63, w = tid >> 6;
  const int c0 = lane & 15, g = lane >> 4;
  const size_t hb = (size_t)bh * SEQ * DH;
  const int b = bh >> 4, h = bh & 15;
  u16* Pw = Pb + w*32*64;

  const int boff  = tid*16;
  const int sw1   = boff  ^ (((boff  >> 7)&7) << 4);
  const int boff2 = boff + 4096;
  const int sw2   = boff2 ^ (((boff2 >> 7)&7) << 4);
  const int rp = tid >> 3, dc = tid & 7;    // V-transpose roles
  union U4 { ushort4 v; u16 e[4]; };

#pragma unroll 1
  for (int half = 0; half < 2; half++){
    const int qt = half ? (15 - pair) : pair;       // paired: uniform 34 iters
    const int qrow_base = qt*128 + w*32;
    const int jt_end = 2*qt + 1;

    bf16x8 qf[2][2];
#pragma unroll
    for (int i=0;i<2;i++)
#pragma unroll
      for (int kc=0;kc<2;kc++)
        qf[i][kc] = *(const bf16x8*)(Q + hb + (size_t)(qrow_base + i*16 + c0)*DH + kc*32 + g*8);

    f32x4 oacc[2][4] = {};
    float mrun[2][4], lrun[2][4];
#pragma unroll
    for (int i=0;i<2;i++)
#pragma unroll
      for (int r=0;r<4;r++){ mrun[i][r] = -3.0e38f; lrun[i][r] = 0.f; }

    // ---- prologue: stage tile 0 into buffer 0 ----
    {
      const char* gk = (const char*)(K + hb);
      async16(gk + sw1, (char*)Kb[0] + boff);
      async16(gk + sw2, (char*)Kb[0] + boff2);
      const u16* gv = V + hb;
      U4 v0a, v0b, v1a, v1b;
      v0a.v = *(const ushort4*)(gv + (2*rp  )*DH + dc*8);
      v0b.v = *(const ushort4*)(gv + (2*rp  )*DH + dc*8 + 4);
      v1a.v = *(const ushort4*)(gv + (2*rp+1)*DH + dc*8);
      v1b.v = *(const ushort4*)(gv + (2*rp+1)*DH + dc*8 + 4);
#pragma unroll
      for (int e=0;e<8;e++){
        const int row = dc*8 + e;
        const int gbyte = row*128 + rp*4;
        const u16 a = (e<4) ? v0a.e[e] : v0b.e[e-4];
        const u16 bb2 = (e<4) ? v1a.e[e] : v1b.e[e-4];
        const uint32_t pk = (uint32_t)a | ((uint32_t)bb2 << 16);
        *(uint32_t*)((char*)Vt[0] + (gbyte ^ ((row&7)<<4))) = pk;
      }
    }
    __syncthreads();

    U4 v0a, v0b, v1a, v1b;   // prefetch regs
    for (int jt = 0; jt <= jt_end; jt++){
      const int cur = jt & 1, nxt = cur ^ 1;
      const bool pre = (jt < jt_end);
      if (pre){
        const char* gk = (const char*)(K + hb + (size_t)(jt+1)*64*DH);
        async16(gk + sw1, (char*)Kb[nxt] + boff);
        async16(gk + sw2, (char*)Kb[nxt] + boff2);
        const u16* gv = V + hb + (size_t)(jt+1)*64*DH;
        v0a.v = *(const ushort4*)(gv + (2*rp  )*DH + dc*8);
        v0b.v = *(const ushort4*)(gv + (2*rp  )*DH + dc*8 + 4);
        v1a.v = *(const ushort4*)(gv + (2*rp+1)*DH + dc*8);
        v1b.v = *(const ushort4*)(gv + (2*rp+1)*DH + dc*8 + 4);
      }

      if (jt*64 <= qrow_base + 31){   // wave-uniform causal skip
        // ---- scores = Q K^T ----
        f32x4 sacc[2][4] = {};
#pragma unroll
        for (int kc=0;kc<2;kc++){
          bf16x8 kf[4];
#pragma unroll
          for (int j=0;j<4;j++){
            const int rr = j*16 + c0;
            const int gb2 = rr*128 + kc*64 + g*16;
            kf[j] = *(const bf16x8*)((const char*)Kb[cur] + (gb2 ^ ((rr&7)<<4)));
          }
#pragma unroll
          for (int i=0;i<2;i++)
#pragma unroll
            for (int j=0;j<4;j++)
              sacc[i][j] = __builtin_amdgcn_mfma_f32_16x16x32_bf16(qf[i][kc], kf[j], sacc[i][j], 0,0,0);
        }
        // ---- online softmax ----
#pragma unroll
        for (int i=0;i<2;i++){
#pragma unroll
          for (int r=0;r<4;r++){
            const int qrow = qrow_base + i*16 + g*4 + r;
            float mx = -3.0e38f;
#pragma unroll
            for (int j=0;j<4;j++){
              const int kv = jt*64 + j*16 + c0;
              float sv = sacc[i][j][r] * 0.125f;
              sv = (kv <= qrow) ? sv : -3.0e38f;
              sacc[i][j][r] = sv;
              mx = fmaxf(mx, sv);
            }
            mx = fmaxf(mx, __shfl_xor(mx, 1));
            mx = fmaxf(mx, __shfl_xor(mx, 2));
            mx = fmaxf(mx, __shfl_xor(mx, 4));
            mx = fmaxf(mx, __shfl_xor(mx, 8));
            const float mnew = fmaxf(mrun[i][r], mx);
            const float corr = __expf(mrun[i][r] - mnew);
            mrun[i][r] = mnew;
            float lsum = 0.f;
#pragma unroll
            for (int j=0;j<4;j++){
              const float p = __expf(sacc[i][j][r] - mnew);
              lsum += p;
              const int prow = i*16 + g*4 + r;
              const int pbyte = prow*128 + (j*16 + c0)*2;
              *(u16*)((char*)Pw + (pbyte ^ ((prow&7)<<4))) = f2bf(p);
            }
            lsum += __shfl_xor(lsum, 1);
            lsum += __shfl_xor(lsum, 2);
            lsum += __shfl_xor(lsum, 4);
            lsum += __shfl_xor(lsum, 8);
            lrun[i][r] = lrun[i][r]*corr + lsum;
#pragma unroll
            for (int d=0; d<4; d++) oacc[i][d][r] *= corr;
          }
        }
        asm volatile("s_waitcnt lgkmcnt(0)" ::: "memory");  // wave-private P wr->rd
        // ---- O += P V ----
#pragma unroll
        for (int kc=0;kc<2;kc++){
          bf16x8 pa[2];
#pragma unroll
          for (int i=0;i<2;i++){
            const int rr = i*16 + c0;
            const int gb2 = rr*128 + kc*64 + g*16;
            pa[i] = *(const bf16x8*)((const char*)Pw + (gb2 ^ ((rr&7)<<4)));
          }
#pragma unroll
          for (int d=0; d<4; d++){
            const int rr = d*16 + c0;
            const int gb2 = rr*128 + kc*64 + g*16;
            const bf16x8 vf = *(const bf16x8*)((const char*)Vt[cur] + (gb2 ^ ((rr&7)<<4)));
#pragma unroll
            for (int i=0;i<2;i++)
              oacc[i][d] = __builtin_amdgcn_mfma_f32_16x16x32_bf16(pa[i], vf, oacc[i][d], 0,0,0);
          }
        }
      }

      if (pre){
        // write prefetched V regs into Vt[nxt] (compiler waits the loads)
#pragma unroll
        for (int e=0;e<8;e++){
          const int row = dc*8 + e;
          const int gbyte = row*128 + rp*4;
          const u16 a = (e<4) ? v0a.e[e] : v0b.e[e-4];
          const u16 bb2 = (e<4) ? v1a.e[e] : v1b.e[e-4];
          const uint32_t pk = (uint32_t)a | ((uint32_t)bb2 << 16);
          *(uint32_t*)((char*)Vt[nxt] + (gbyte ^ ((row&7)<<4))) = pk;
        }
      }
      __syncthreads();
    }

    // write attn output to [B,S,H*Dh] (bf16)
#pragma unroll
    for (int i=0;i<2;i++){
#pragma unroll
      for (int r=0;r<4;r++){
        const float inv = 1.0f / lrun[i][r];
        const int mm = qrow_base + i*16 + g*4 + r;
#pragma unroll
        for (int d=0; d<4; d++)
          O[(((size_t)b*SEQ + mm)*NHEAD + h)*DH + d*16 + c0] = f2bf(oacc[i][d][r] * inv);
      }
    }
  }
}

// ---------------------------------------------------------------------------
extern "C" void kernel_launch(void* const* d_in, const int* in_sizes, int n_in,
                              void* d_out, int out_size, void* d_ws, size_t ws_size,
                              hipStream_t stream)
{
  const float* x  = (const float*)d_in[0];
  const float* Wq = (const float*)d_in[1];
  const float* bq = (const float*)d_in[2];
  const float* Wk = (const float*)d_in[3];
  const float* bk = (const float*)d_in[4];
  const float* Wv = (const float*)d_in[5];
  const float* bv = (const float*)d_in[6];
  const float* Wo = (const float*)d_in[7];
  const float* bo = (const float*)d_in[8];
  // d_in[9]: causal mask (int32) — implemented analytically, not read.

  const size_t MB = 1024*1024;
  char* ws = (char*)d_ws;
  u16*  xb   = (u16*)(ws);                 // [0,16MB)  x bf16; dead after QKV
  u16*  aw   = (u16*)(ws);                 // attn out reuses region
  u16*  vw   = (u16*)(ws + 16*MB);         // [16,32MB) V [B,H,S,Dh]
  u16*  wqkv = (u16*)(ws + 32*MB);         // [32,38MB) Wq|Wk|Wv bf16 [3072][1024]
  u16*  wob  = (u16*)(ws + 38*MB);         // [38,40MB)
  float* bcat = (float*)(ws + 40*MB);      // 12KB  bq|bk|bv
  float* tab  = (float*)(ws + 41*MB);      // 512KB
  // d_out (32MB f32) doubles as scratch for q/k (bf16, dead before final GEMM)
  u16*  qw = (u16*)d_out;
  u16*  kw = (u16*)d_out + 8*MB;

  const int NX = 4*SEQ*DMODEL;   // 8,388,608
  const int NW = DMODEL*DMODEL;  // 1,048,576
  cvt_f32_bf16<<<dim3(NX/1024), dim3(256), 0, stream>>>(x,  xb, NX);
  cvt_f32_bf16<<<dim3(NW/1024), dim3(256), 0, stream>>>(Wq, wqkv,        NW);
  cvt_f32_bf16<<<dim3(NW/1024), dim3(256), 0, stream>>>(Wk, wqkv + NW,   NW);
  cvt_f32_bf16<<<dim3(NW/1024), dim3(256), 0, stream>>>(Wv, wqkv + 2*NW, NW);
  cvt_f32_bf16<<<dim3(NW/1024), dim3(256), 0, stream>>>(Wo, wob, NW);
  hipMemcpyAsync(bcat,        bq, DMODEL*4, hipMemcpyDeviceToDevice, stream);
  hipMemcpyAsync(bcat+DMODEL, bk, DMODEL*4, hipMemcpyDeviceToDevice, stream);
  hipMemcpyAsync(bcat+2*DMODEL, bv, DMODEL*4, hipMemcpyDeviceToDevice, stream);

  rope_table<<<dim3(256), dim3(256), 0, stream>>>(tab);

  // fused QKV projection + RoPE epilogue: N=3072
  gemm_bt<0><<<dim3(24, 64), dim3(256), 0, stream>>>(xb, wqkv, bcat, nullptr, qw, kw, vw, tab);

  attn_fwd<<<dim3(8, 64), dim3(256), 0, stream>>>(qw, kw, vw, aw);

  gemm_bt<1><<<dim3(8, 64), dim3(256), 0, stream>>>(aw, wob, bo, (float*)d_out, nullptr, nullptr, nullptr, nullptr);
}

// Round 4
// 239.863 us; speedup vs baseline: 1.6310x; 1.6310x over previous
//
#include <hip/hip_runtime.h>
#include <stdint.h>

typedef unsigned short u16;
typedef __bf16 bf16x8 __attribute__((ext_vector_type(8)));
typedef float f32x4 __attribute__((ext_vector_type(4)));

#define SEQ    2048
#define NHEAD  16
#define DH     64
#define DMODEL 1024
#define NBH    64     // B*H

__device__ __forceinline__ u16 f2bf(float f){
  union { float f; uint32_t i; } v; v.f = f;
  uint32_t x = v.i;
  return (u16)((x + 0x7fffu + ((x >> 16) & 1u)) >> 16);
}
__device__ __forceinline__ float bf2f(u16 u){
  union { uint32_t i; float f; } v; v.i = ((uint32_t)u) << 16; return v.f;
}

typedef const __attribute__((address_space(1))) uint32_t* gas_t;
typedef __attribute__((address_space(3))) uint32_t* las_t;
__device__ __forceinline__ void async16(const void* g, void* l){
  __builtin_amdgcn_global_load_lds((gas_t)g, (las_t)l, 16, 0, 0);
}

// ---------------- f32 -> bf16 convert (vectorized, memory-bound) ------------
__global__ void cvt_f32_bf16(const float* __restrict__ src, u16* __restrict__ dst, int n){
  int t = (blockIdx.x*blockDim.x + threadIdx.x)*4;
  if (t >= n) return;
  float4 v = *(const float4*)(src + t);
  ushort4 o;
  o.x = f2bf(v.x); o.y = f2bf(v.y); o.z = f2bf(v.z); o.w = f2bf(v.w);
  *(ushort4*)(dst + t) = o;
}

// ---------------- RoPE table: [2048][32] interleaved (cos,sin) pairs --------
__global__ void rope_table(float* __restrict__ tab){
  int t = blockIdx.x * blockDim.x + threadIdx.x;
  if (t >= SEQ*32) return;
  int s = t >> 5, j = t & 31;
  double freq = exp(-(double)(2*j) / 64.0 * log(10000.0));
  double ang = (double)s * freq;
  tab[s*64 + 2*j]     = (float)cos(ang);
  tab[s*64 + 2*j + 1] = (float)sin(ang);
}

// ---------------- GEMM: dst = A @ W^T + bias  (bf16 in, NT layout) ----------
// MODE 0: fused QKV (N=3072): scatter bf16 to per-head [B,H,S,Dh]; RoPE fused
// MODE 1: f32 dst linear [M][1024]
template<int MODE>
__global__ __launch_bounds__(256, 2)
void gemm_bt(const u16* __restrict__ A, const u16* __restrict__ W,
             const float* __restrict__ bias, float* __restrict__ fout,
             u16* __restrict__ dq, u16* __restrict__ dk, u16* __restrict__ dv,
             const float* __restrict__ tab)
{
  __shared__ u16 Ab[128*32];
  __shared__ u16 Bb[128*32];
  const int tid = threadIdx.x;
  const int lane = tid & 63;
  const int w = tid >> 6, wr = w >> 1, wc = w & 1;
  const int m0 = blockIdx.y * 128;
  const int n0 = blockIdx.x * 128;
  const int c0 = lane & 15, g = lane >> 4;

  f32x4 acc[4][4] = {};

  const int sr = tid >> 2;          // staging row 0..63
  const int sc = (tid & 3) * 8;     // staging col (elements)
  const u16* ga = A + (size_t)(m0 + sr) * DMODEL + sc;
  const u16* gb = W + (size_t)(n0 + sr) * DMODEL + sc;
  u16* la = Ab + sr*32 + sc;
  u16* lb = Bb + sr*32 + sc;

  for (int k0 = 0; k0 < DMODEL; k0 += 32) {
    __syncthreads();
    async16(ga + k0,             la);
    async16(ga + k0 + 64*DMODEL, la + 64*32);
    async16(gb + k0,             lb);
    async16(gb + k0 + 64*DMODEL, lb + 64*32);
    __syncthreads();
    bf16x8 afr[4], bfr[4];
#pragma unroll
    for (int i=0;i<4;i++) afr[i] = *(const bf16x8*)(Ab + (wr*64 + i*16 + c0)*32 + g*8);
#pragma unroll
    for (int j=0;j<4;j++) bfr[j] = *(const bf16x8*)(Bb + (wc*64 + j*16 + c0)*32 + g*8);
    __builtin_amdgcn_s_setprio(1);
#pragma unroll
    for (int i=0;i<4;i++)
#pragma unroll
      for (int j=0;j<4;j++)
        acc[i][j] = __builtin_amdgcn_mfma_f32_16x16x32_bf16(afr[i], bfr[j], acc[i][j], 0,0,0);
    __builtin_amdgcn_s_setprio(0);
  }

  const int nbase = n0 + wc*64;
  float bv4[4];
#pragma unroll
  for (int j=0;j<4;j++) bv4[j] = bias[nbase + j*16 + c0];

  if (MODE == 0) {
    const int t = n0 >> 10;                 // 0=q 1=k 2=v (tile never crosses)
    u16* dst = (t==0) ? dq : (t==1) ? dk : dv;
    const int h = (nbase >> 6) & (NHEAD-1);
#pragma unroll
    for (int i=0;i<4;i++){
      const int mbase = m0 + wr*64 + i*16 + g*4;
#pragma unroll
      for (int r=0;r<4;r++){
        const int mm = mbase + r;
        const int bb = mm >> 11, s = mm & (SEQ-1);
        const size_t rowbase = (((size_t)(bb*NHEAD + h))*SEQ + s)*DH;
        if (t < 2) {
#pragma unroll
          for (int j2=0;j2<2;j2++){
            const int dh = j2*16 + c0;
            const float xl = acc[i][j2][r]   + bv4[j2];
            const float xh = acc[i][j2+2][r] + bv4[j2+2];
            const float2 cs = *(const float2*)(tab + (size_t)s*64 + dh*2);
            dst[rowbase + dh]      = f2bf(xl*cs.x - xh*cs.y);
            dst[rowbase + dh + 32] = f2bf(xh*cs.x + xl*cs.y);
          }
        } else {
#pragma unroll
          for (int j=0;j<4;j++)
            dst[rowbase + j*16 + c0] = f2bf(acc[i][j][r] + bv4[j]);
        }
      }
    }
  } else {
#pragma unroll
    for (int i=0;i<4;i++){
      const int mbase = m0 + wr*64 + i*16 + g*4;
#pragma unroll
      for (int j=0;j<4;j++){
#pragma unroll
        for (int r=0;r<4;r++)
          fout[(size_t)(mbase + r) * DMODEL + nbase + j*16 + c0] = acc[i][j][r] + bv4[j];
      }
    }
  }
}

// ---------------- Flash attention, causal, swapped-operand softmax ----------
// grid (64, 8): x = bh (XCD locality: id%8 = bh%8), y = pair
__global__ __launch_bounds__(256, 3)
void attn_fwd(const u16* __restrict__ Q, const u16* __restrict__ K,
              const u16* __restrict__ V, u16* __restrict__ O)
{
  __shared__ u16 Kb[2][64*64];  // [kv][dh], XOR-swizzled (pre-swizzled source)
  __shared__ u16 Vt[2][64*64];  // [dh][kv], XOR-swizzled
  __shared__ u16 Pb[128*64];    // [q][kv] per-wave regions, XOR-swizzled
  const int bh = blockIdx.x;
  const int pair = blockIdx.y;              // 0..7
  const int tid = threadIdx.x, lane = tid & 63, w = tid >> 6;
  const int c0 = lane & 15, g = lane >> 4;
  const size_t hb = (size_t)bh * SEQ * DH;
  const int b = bh >> 4, h = bh & 15;
  u16* Pw = Pb + w*32*64;

  const int boff  = tid*16;
  const int sw1   = boff  ^ (((boff  >> 7)&7) << 4);
  const int boff2 = boff + 4096;
  const int sw2   = boff2 ^ (((boff2 >> 7)&7) << 4);
  const int rp = tid >> 3, dc = tid & 7;    // V-transpose roles
  union U4 { ushort4 v; u16 e[4]; };

#pragma unroll 1
  for (int half = 0; half < 2; half++){
    const int qt = half ? (15 - pair) : pair;       // paired: uniform 34 iters
    const int qrow_base = qt*128 + w*32;
    const int jt_end = 2*qt + 1;

    bf16x8 qf[2][2];
#pragma unroll
    for (int i=0;i<2;i++)
#pragma unroll
      for (int kc=0;kc<2;kc++)
        qf[i][kc] = *(const bf16x8*)(Q + hb + (size_t)(qrow_base + i*16 + c0)*DH + kc*32 + g*8);

    // transposed accumulators: oacc[i][d][r] = O[dh = d*16+g*4+r][q = i*16+c0]
    f32x4 oacc[2][4] = {};
    float mrun[2] = {-3.0e38f, -3.0e38f};
    float lrun[2] = {0.f, 0.f};

    // ---- prologue: stage tile 0 into buffer 0 ----
    {
      const char* gk = (const char*)(K + hb);
      async16(gk + sw1, (char*)Kb[0] + boff);
      async16(gk + sw2, (char*)Kb[0] + boff2);
      const u16* gv = V + hb;
      U4 v0a, v0b, v1a, v1b;
      v0a.v = *(const ushort4*)(gv + (2*rp  )*DH + dc*8);
      v0b.v = *(const ushort4*)(gv + (2*rp  )*DH + dc*8 + 4);
      v1a.v = *(const ushort4*)(gv + (2*rp+1)*DH + dc*8);
      v1b.v = *(const ushort4*)(gv + (2*rp+1)*DH + dc*8 + 4);
#pragma unroll
      for (int e=0;e<8;e++){
        const int row = dc*8 + e;
        const int gbyte = row*128 + rp*4;
        const u16 a = (e<4) ? v0a.e[e] : v0b.e[e-4];
        const u16 bb2 = (e<4) ? v1a.e[e] : v1b.e[e-4];
        const uint32_t pk = (uint32_t)a | ((uint32_t)bb2 << 16);
        *(uint32_t*)((char*)Vt[0] + (gbyte ^ ((row&7)<<4))) = pk;
      }
    }
    __syncthreads();

    U4 v0a, v0b, v1a, v1b;   // prefetch regs
    for (int jt = 0; jt <= jt_end; jt++){
      const int cur = jt & 1, nxt = cur ^ 1;
      const bool pre = (jt < jt_end);
      if (pre){
        const char* gk = (const char*)(K + hb + (size_t)(jt+1)*64*DH);
        async16(gk + sw1, (char*)Kb[nxt] + boff);
        async16(gk + sw2, (char*)Kb[nxt] + boff2);
        const u16* gv = V + hb + (size_t)(jt+1)*64*DH;
        v0a.v = *(const ushort4*)(gv + (2*rp  )*DH + dc*8);
        v0b.v = *(const ushort4*)(gv + (2*rp  )*DH + dc*8 + 4);
        v1a.v = *(const ushort4*)(gv + (2*rp+1)*DH + dc*8);
        v1b.v = *(const ushort4*)(gv + (2*rp+1)*DH + dc*8 + 4);
      }

      if (jt*64 <= qrow_base + 31){   // wave-uniform causal skip
        // ---- S^T = K Q^T : sT[i][j][r] = S[kv = j*16+g*4+r][q = i*16+c0] ----
        f32x4 sT[2][4] = {};
#pragma unroll
        for (int kc=0;kc<2;kc++){
          bf16x8 kf[4];
#pragma unroll
          for (int j=0;j<4;j++){
            const int rr = j*16 + c0;
            const int gb2 = rr*128 + kc*64 + g*16;
            kf[j] = *(const bf16x8*)((const char*)Kb[cur] + (gb2 ^ ((rr&7)<<4)));
          }
          __builtin_amdgcn_s_setprio(1);
#pragma unroll
          for (int i=0;i<2;i++)
#pragma unroll
            for (int j=0;j<4;j++)
              sT[i][j] = __builtin_amdgcn_mfma_f32_16x16x32_bf16(kf[j], qf[i][kc], sT[i][j], 0,0,0);
          __builtin_amdgcn_s_setprio(0);
        }
        // ---- online softmax: per-lane q-row, in-lane kv reduce ----
        float corr_s[2];
#pragma unroll
        for (int i=0;i<2;i++){
          const int q = qrow_base + i*16 + c0;
          float mx = -3.0e38f;
#pragma unroll
          for (int j=0;j<4;j++)
#pragma unroll
            for (int r=0;r<4;r++){
              const int kv = jt*64 + j*16 + g*4 + r;
              float sv = sT[i][j][r] * 0.125f;
              sv = (kv <= q) ? sv : -3.0e38f;
              sT[i][j][r] = sv;
              mx = fmaxf(mx, sv);
            }
          mx = fmaxf(mx, __shfl_xor(mx, 16));
          mx = fmaxf(mx, __shfl_xor(mx, 32));
          const float mnew = fmaxf(mrun[i], mx);
          const float corr = __expf(mrun[i] - mnew);
          mrun[i] = mnew;
          float lsum = 0.f;
          const int prow = i*16 + c0;
          char* pwb = (char*)Pw;
#pragma unroll
          for (int j=0;j<4;j++){
#pragma unroll
            for (int r2=0;r2<2;r2++){
              const float p0 = __expf(sT[i][j][2*r2]   - mnew);
              const float p1 = __expf(sT[i][j][2*r2+1] - mnew);
              lsum += p0 + p1;
              const uint32_t pk = (uint32_t)f2bf(p0) | ((uint32_t)f2bf(p1) << 16);
              const int pbyte = prow*128 + (j*16 + g*4 + 2*r2)*2;
              *(uint32_t*)(pwb + (pbyte ^ ((prow&7)<<4))) = pk;
            }
          }
          lsum += __shfl_xor(lsum, 16);
          lsum += __shfl_xor(lsum, 32);
          lrun[i] = lrun[i]*corr + lsum;
          corr_s[i] = corr;
        }
#pragma unroll
        for (int i=0;i<2;i++)
#pragma unroll
          for (int d=0;d<4;d++)
#pragma unroll
            for (int r=0;r<4;r++) oacc[i][d][r] *= corr_s[i];
        asm volatile("s_waitcnt lgkmcnt(0)" ::: "memory");  // wave-private P wr->rd
        // ---- O^T += V^T P^T ----
#pragma unroll
        for (int kc=0;kc<2;kc++){
          bf16x8 pa[2];
#pragma unroll
          for (int i=0;i<2;i++){
            const int rr = i*16 + c0;
            const int gb2 = rr*128 + kc*64 + g*16;
            pa[i] = *(const bf16x8*)((const char*)Pw + (gb2 ^ ((rr&7)<<4)));
          }
          bf16x8 vf[4];
#pragma unroll
          for (int d=0; d<4; d++){
            const int rr = d*16 + c0;
            const int gb2 = rr*128 + kc*64 + g*16;
            vf[d] = *(const bf16x8*)((const char*)Vt[cur] + (gb2 ^ ((rr&7)<<4)));
          }
          __builtin_amdgcn_s_setprio(1);
#pragma unroll
          for (int d=0; d<4; d++)
#pragma unroll
            for (int i=0;i<2;i++)
              oacc[i][d] = __builtin_amdgcn_mfma_f32_16x16x32_bf16(vf[d], pa[i], oacc[i][d], 0,0,0);
          __builtin_amdgcn_s_setprio(0);
        }
      }

      if (pre){
#pragma unroll
        for (int e=0;e<8;e++){
          const int row = dc*8 + e;
          const int gbyte = row*128 + rp*4;
          const u16 a = (e<4) ? v0a.e[e] : v0b.e[e-4];
          const u16 bb2 = (e<4) ? v1a.e[e] : v1b.e[e-4];
          const uint32_t pk = (uint32_t)a | ((uint32_t)bb2 << 16);
          *(uint32_t*)((char*)Vt[nxt] + (gbyte ^ ((row&7)<<4))) = pk;
        }
      }
      __syncthreads();
    }

    // ---- write attn output (transposed per-lane): O[b, q, h*64 + dh] ----
#pragma unroll
    for (int i=0;i<2;i++){
      const float inv = 1.0f / lrun[i];
      const int q = qrow_base + i*16 + c0;
      u16* orow = O + ((size_t)b*SEQ + q)*DMODEL + h*DH;
#pragma unroll
      for (int d=0;d<4;d++){
#pragma unroll
        for (int r2=0;r2<2;r2++){
          const u16 a0 = f2bf(oacc[i][d][2*r2]   * inv);
          const u16 a1 = f2bf(oacc[i][d][2*r2+1] * inv);
          *(uint32_t*)(orow + d*16 + g*4 + 2*r2) = (uint32_t)a0 | ((uint32_t)a1 << 16);
        }
      }
    }
  }
}

// ---------------------------------------------------------------------------
extern "C" void kernel_launch(void* const* d_in, const int* in_sizes, int n_in,
                              void* d_out, int out_size, void* d_ws, size_t ws_size,
                              hipStream_t stream)
{
  const float* x  = (const float*)d_in[0];
  const float* Wq = (const float*)d_in[1];
  const float* bq = (const float*)d_in[2];
  const float* Wk = (const float*)d_in[3];
  const float* bk = (const float*)d_in[4];
  const float* Wv = (const float*)d_in[5];
  const float* bv = (const float*)d_in[6];
  const float* Wo = (const float*)d_in[7];
  const float* bo = (const float*)d_in[8];
  // d_in[9]: causal mask (int32) — implemented analytically, not read.

  const size_t MB = 1024*1024;
  char* ws = (char*)d_ws;
  u16*  xb   = (u16*)(ws);                 // [0,16MB)  x bf16; dead after QKV
  u16*  aw   = (u16*)(ws);                 // attn out reuses region
  u16*  vw   = (u16*)(ws + 16*MB);         // [16,32MB) V [B,H,S,Dh]
  u16*  wqkv = (u16*)(ws + 32*MB);         // [32,38MB) Wq|Wk|Wv bf16 [3072][1024]
  u16*  wob  = (u16*)(ws + 38*MB);         // [38,40MB)
  float* bcat = (float*)(ws + 40*MB);      // 12KB  bq|bk|bv
  float* tab  = (float*)(ws + 41*MB);      // 512KB
  // d_out (32MB f32) doubles as scratch for q/k (bf16, dead before final GEMM)
  u16*  qw = (u16*)d_out;
  u16*  kw = (u16*)d_out + 8*MB;

  const int NX = 4*SEQ*DMODEL;   // 8,388,608
  const int NW = DMODEL*DMODEL;  // 1,048,576
  cvt_f32_bf16<<<dim3(NX/1024), dim3(256), 0, stream>>>(x,  xb, NX);
  cvt_f32_bf16<<<dim3(NW/1024), dim3(256), 0, stream>>>(Wq, wqkv,        NW);
  cvt_f32_bf16<<<dim3(NW/1024), dim3(256), 0, stream>>>(Wk, wqkv + NW,   NW);
  cvt_f32_bf16<<<dim3(NW/1024), dim3(256), 0, stream>>>(Wv, wqkv + 2*NW, NW);
  cvt_f32_bf16<<<dim3(NW/1024), dim3(256), 0, stream>>>(Wo, wob, NW);
  hipMemcpyAsync(bcat,          bq, DMODEL*4, hipMemcpyDeviceToDevice, stream);
  hipMemcpyAsync(bcat+DMODEL,   bk, DMODEL*4, hipMemcpyDeviceToDevice, stream);
  hipMemcpyAsync(bcat+2*DMODEL, bv, DMODEL*4, hipMemcpyDeviceToDevice, stream);

  rope_table<<<dim3(256), dim3(256), 0, stream>>>(tab);

  // fused QKV projection + RoPE epilogue: N=3072
  gemm_bt<0><<<dim3(24, 64), dim3(256), 0, stream>>>(xb, wqkv, bcat, nullptr, qw, kw, vw, tab);

  attn_fwd<<<dim3(64, 8), dim3(256), 0, stream>>>(qw, kw, vw, aw);

  gemm_bt<1><<<dim3(8, 64), dim3(256), 0, stream>>>(aw, wob, bo, (float*)d_out, nullptr, nullptr, nullptr, nullptr);
}

// Round 5
// 229.079 us; speedup vs baseline: 1.7078x; 1.0471x over previous
//
#include <hip/hip_runtime.h>
#include <stdint.h>

typedef unsigned short u16;
typedef __bf16 bf16x8 __attribute__((ext_vector_type(8)));
typedef float f32x4 __attribute__((ext_vector_type(4)));

#define SEQ    2048
#define NHEAD  16
#define DH     64
#define DMODEL 1024
#define NBH    64     // B*H

__device__ __forceinline__ u16 f2bf(float f){
  union { float f; uint32_t i; } v; v.f = f;
  uint32_t x = v.i;
  return (u16)((x + 0x7fffu + ((x >> 16) & 1u)) >> 16);
}
__device__ __forceinline__ float bf2f(u16 u){
  union { uint32_t i; float f; } v; v.i = ((uint32_t)u) << 16; return v.f;
}
// LDS XOR-swizzle: bits 4-6 (keeps 16B alignment for b128 reads)
__device__ __forceinline__ int swz(int row){ return (((row&7)^((row>>3)&7))<<4); }

typedef const __attribute__((address_space(1))) uint32_t* gas_t;
typedef __attribute__((address_space(3))) uint32_t* las_t;
__device__ __forceinline__ void async16(const void* g, void* l){
  __builtin_amdgcn_global_load_lds((gas_t)g, (las_t)l, 16, 0, 0);
}

// ---------------- f32 -> bf16 convert (vectorized, memory-bound) ------------
__global__ void cvt_f32_bf16(const float* __restrict__ src, u16* __restrict__ dst, int n){
  int t = (blockIdx.x*blockDim.x + threadIdx.x)*4;
  if (t >= n) return;
  float4 v = *(const float4*)(src + t);
  ushort4 o;
  o.x = f2bf(v.x); o.y = f2bf(v.y); o.z = f2bf(v.z); o.w = f2bf(v.w);
  *(ushort4*)(dst + t) = o;
}

// ---------------- RoPE table: [2048][32] interleaved (cos,sin) pairs --------
__global__ void rope_table(float* __restrict__ tab){
  int t = blockIdx.x * blockDim.x + threadIdx.x;
  if (t >= SEQ*32) return;
  int s = t >> 5, j = t & 31;
  double freq = exp(-(double)(2*j) / 64.0 * log(10000.0));
  double ang = (double)s * freq;
  tab[s*64 + 2*j]     = (float)cos(ang);
  tab[s*64 + 2*j + 1] = (float)sin(ang);
}

// ---------------- GEMM: dst = A @ W^T + bias  (bf16 in, NT layout) ----------
// MODE 0: fused QKV (N=3072): scatter bf16 to per-head [B,H,S,Dh]; RoPE fused;
//         Q additionally scaled by 0.125*log2(e) (softmax works in exp2 domain)
// MODE 1: f32 dst linear [M][1024]
template<int MODE>
__global__ __launch_bounds__(256, 2)
void gemm_bt(const u16* __restrict__ A, const u16* __restrict__ W,
             const float* __restrict__ bias, float* __restrict__ fout,
             u16* __restrict__ dq, u16* __restrict__ dk, u16* __restrict__ dv,
             const float* __restrict__ tab)
{
  __shared__ u16 Ab[128*32];
  __shared__ u16 Bb[128*32];
  const int tid = threadIdx.x;
  const int lane = tid & 63;
  const int w = tid >> 6, wr = w >> 1, wc = w & 1;
  const int m0 = blockIdx.y * 128;
  const int n0 = blockIdx.x * 128;
  const int c0 = lane & 15, g = lane >> 4;

  f32x4 acc[4][4] = {};

  const int sr = tid >> 2;          // staging row 0..63
  const int sc = (tid & 3) * 8;     // staging col (elements)
  const u16* ga = A + (size_t)(m0 + sr) * DMODEL + sc;
  const u16* gb = W + (size_t)(n0 + sr) * DMODEL + sc;
  u16* la = Ab + sr*32 + sc;
  u16* lb = Bb + sr*32 + sc;

  for (int k0 = 0; k0 < DMODEL; k0 += 32) {
    __syncthreads();
    async16(ga + k0,             la);
    async16(ga + k0 + 64*DMODEL, la + 64*32);
    async16(gb + k0,             lb);
    async16(gb + k0 + 64*DMODEL, lb + 64*32);
    __syncthreads();
    bf16x8 afr[4], bfr[4];
#pragma unroll
    for (int i=0;i<4;i++) afr[i] = *(const bf16x8*)(Ab + (wr*64 + i*16 + c0)*32 + g*8);
#pragma unroll
    for (int j=0;j<4;j++) bfr[j] = *(const bf16x8*)(Bb + (wc*64 + j*16 + c0)*32 + g*8);
    __builtin_amdgcn_s_setprio(1);
#pragma unroll
    for (int i=0;i<4;i++)
#pragma unroll
      for (int j=0;j<4;j++)
        acc[i][j] = __builtin_amdgcn_mfma_f32_16x16x32_bf16(afr[i], bfr[j], acc[i][j], 0,0,0);
    __builtin_amdgcn_s_setprio(0);
  }

  const int nbase = n0 + wc*64;
  float bv4[4];
#pragma unroll
  for (int j=0;j<4;j++) bv4[j] = bias[nbase + j*16 + c0];

  if (MODE == 0) {
    const int t = n0 >> 10;                 // 0=q 1=k 2=v (tile never crosses)
    u16* dst = (t==0) ? dq : (t==1) ? dk : dv;
    const float qs = (t==0) ? 0.18033688011f : 1.0f;   // 0.125*log2(e)
    const int h = (nbase >> 6) & (NHEAD-1);
#pragma unroll
    for (int i=0;i<4;i++){
      const int mbase = m0 + wr*64 + i*16 + g*4;
#pragma unroll
      for (int r=0;r<4;r++){
        const int mm = mbase + r;
        const int bb = mm >> 11, s = mm & (SEQ-1);
        const size_t rowbase = (((size_t)(bb*NHEAD + h))*SEQ + s)*DH;
        if (t < 2) {
#pragma unroll
          for (int j2=0;j2<2;j2++){
            const int dh = j2*16 + c0;
            const float xl = acc[i][j2][r]   + bv4[j2];
            const float xh = acc[i][j2+2][r] + bv4[j2+2];
            const float2 cs = *(const float2*)(tab + (size_t)s*64 + dh*2);
            dst[rowbase + dh]      = f2bf((xl*cs.x - xh*cs.y)*qs);
            dst[rowbase + dh + 32] = f2bf((xh*cs.x + xl*cs.y)*qs);
          }
        } else {
#pragma unroll
          for (int j=0;j<4;j++)
            dst[rowbase + j*16 + c0] = f2bf(acc[i][j][r] + bv4[j]);
        }
      }
    }
  } else {
#pragma unroll
    for (int i=0;i<4;i++){
      const int mbase = m0 + wr*64 + i*16 + g*4;
#pragma unroll
      for (int j=0;j<4;j++){
#pragma unroll
        for (int r=0;r<4;r++)
          fout[(size_t)(mbase + r) * DMODEL + nbase + j*16 + c0] = acc[i][j][r] + bv4[j];
      }
    }
  }
}

// ---------------- Flash attention, causal, QB=64, swapped-operand -----------
// grid (64, 16): x = bh (XCD locality: id%8 = bh%8), y = pair (qt = p / 31-p)
__global__ __launch_bounds__(256, 4)
void attn_fwd(const u16* __restrict__ Q, const u16* __restrict__ K,
              const u16* __restrict__ V, u16* __restrict__ O)
{
  __shared__ u16 Kb[2][64*64];  // [kv][dh], swizzled (pre-swizzled source)
  __shared__ u16 Vt[2][64*64];  // [dh][kv], swizzled
  __shared__ u16 Pb[4*16*64];   // per-wave [q16][kv64], swizzled
  const int bh = blockIdx.x;
  const int pair = blockIdx.y;              // 0..15
  const int tid = threadIdx.x, lane = tid & 63, w = tid >> 6;
  const int c0 = lane & 15, g = lane >> 4;
  const size_t hb = (size_t)bh * SEQ * DH;
  const int b = bh >> 4, h = bh & 15;
  u16* Pw = Pb + w*16*64;

  const int boff  = tid*16;
  const int sw1   = boff  ^ swz(boff  >> 7);
  const int boff2 = boff + 4096;
  const int sw2   = boff2 ^ swz(boff2 >> 7);
  const int rp = tid >> 3, dc = tid & 7;    // V-transpose roles
  union U4 { ushort4 v; u16 e[4]; };

#pragma unroll 1
  for (int half = 0; half < 2; half++){
    const int qt = half ? (31 - pair) : pair;       // paired: 33 iters/block
    const int qrow_base = qt*64 + w*16;
    const int jt_end = qt;
    const int q = qrow_base + c0;                   // this lane's q-row

    bf16x8 qf[2];
#pragma unroll
    for (int kc=0;kc<2;kc++)
      qf[kc] = *(const bf16x8*)(Q + hb + (size_t)q*DH + kc*32 + g*8);

    // transposed accumulators: oacc[d][r] = O[dh=d*16+g*4+r][q]
    f32x4 oacc[4] = {};
    float mrun = -3.0e38f, lrun = 0.f;

    // ---- prologue: stage tile 0 into buffer 0 ----
    {
      const char* gk = (const char*)(K + hb);
      async16(gk + sw1, (char*)Kb[0] + boff);
      async16(gk + sw2, (char*)Kb[0] + boff2);
      const u16* gv = V + hb;
      U4 v0a, v0b, v1a, v1b;
      v0a.v = *(const ushort4*)(gv + (2*rp  )*DH + dc*8);
      v0b.v = *(const ushort4*)(gv + (2*rp  )*DH + dc*8 + 4);
      v1a.v = *(const ushort4*)(gv + (2*rp+1)*DH + dc*8);
      v1b.v = *(const ushort4*)(gv + (2*rp+1)*DH + dc*8 + 4);
#pragma unroll
      for (int e=0;e<8;e++){
        const int row = dc*8 + e;
        const int gbyte = row*128 + rp*4;
        const u16 a = (e<4) ? v0a.e[e] : v0b.e[e-4];
        const u16 bb2 = (e<4) ? v1a.e[e] : v1b.e[e-4];
        const uint32_t pk = (uint32_t)a | ((uint32_t)bb2 << 16);
        *(uint32_t*)((char*)Vt[0] + (gbyte ^ swz(row))) = pk;
      }
    }
    __syncthreads();

    U4 v0a, v0b, v1a, v1b;   // prefetch regs
    for (int jt = 0; jt <= jt_end; jt++){
      const int cur = jt & 1, nxt = cur ^ 1;
      const bool pre = (jt < jt_end);
      if (pre){
        const char* gk = (const char*)(K + hb + (size_t)(jt+1)*64*DH);
        async16(gk + sw1, (char*)Kb[nxt] + boff);
        async16(gk + sw2, (char*)Kb[nxt] + boff2);
        const u16* gv = V + hb + (size_t)(jt+1)*64*DH;
        v0a.v = *(const ushort4*)(gv + (2*rp  )*DH + dc*8);
        v0b.v = *(const ushort4*)(gv + (2*rp  )*DH + dc*8 + 4);
        v1a.v = *(const ushort4*)(gv + (2*rp+1)*DH + dc*8);
        v1b.v = *(const ushort4*)(gv + (2*rp+1)*DH + dc*8 + 4);
      }

      // ---- S^T = K Q'^T (Q pre-scaled: values are log2-domain logits) ----
      f32x4 sT[4] = {};
#pragma unroll
      for (int kc=0;kc<2;kc++){
        bf16x8 kf[4];
#pragma unroll
        for (int j=0;j<4;j++){
          const int rr = j*16 + c0;
          const int gb2 = rr*128 + kc*64 + g*16;
          kf[j] = *(const bf16x8*)((const char*)Kb[cur] + (gb2 ^ swz(rr)));
        }
        __builtin_amdgcn_s_setprio(1);
#pragma unroll
        for (int j=0;j<4;j++)
          sT[j] = __builtin_amdgcn_mfma_f32_16x16x32_bf16(kf[j], qf[kc], sT[j], 0,0,0);
        __builtin_amdgcn_s_setprio(0);
      }
      // ---- causal mask: only the diagonal tile needs it ----
      if (jt == jt_end){
#pragma unroll
        for (int j=0;j<4;j++)
#pragma unroll
          for (int r=0;r<4;r++){
            const int kv = jt*64 + j*16 + g*4 + r;
            sT[j][r] = (kv <= q) ? sT[j][r] : -3.0e38f;
          }
      }
      // ---- online softmax (per-lane q-row; exp2 domain; defer-max) ----
      float mx = -3.0e38f;
#pragma unroll
      for (int j=0;j<4;j++)
#pragma unroll
        for (int r=0;r<4;r++) mx = fmaxf(mx, sT[j][r]);
      mx = fmaxf(mx, __shfl_xor(mx, 16));
      mx = fmaxf(mx, __shfl_xor(mx, 32));
      const bool grow = __any(mx > mrun + 8.0f);
      float corr = 1.0f;
      if (grow){
        const float mnew = fmaxf(mrun, mx);
        corr = exp2f(mrun - mnew);
        mrun = mnew;
      }
      float lsum = 0.f;
      {
        char* pwb = (char*)Pw;
        const int prow = c0;
        const int psw = swz(prow);
#pragma unroll
        for (int j=0;j<4;j++){
#pragma unroll
          for (int r2=0;r2<2;r2++){
            const float p0 = exp2f(sT[j][2*r2]   - mrun);
            const float p1 = exp2f(sT[j][2*r2+1] - mrun);
            lsum += p0 + p1;
            const uint32_t pk = (uint32_t)f2bf(p0) | ((uint32_t)f2bf(p1) << 16);
            const int pbyte = prow*128 + (j*16 + g*4 + 2*r2)*2;
            *(uint32_t*)(pwb + (pbyte ^ psw)) = pk;
          }
        }
      }
      lsum += __shfl_xor(lsum, 16);
      lsum += __shfl_xor(lsum, 32);
      lrun = lrun*corr + lsum;
      if (grow){
#pragma unroll
        for (int d=0;d<4;d++)
#pragma unroll
          for (int r=0;r<4;r++) oacc[d][r] *= corr;
      }
      asm volatile("s_waitcnt lgkmcnt(0)" ::: "memory");  // wave-private P wr->rd
      // ---- O^T += V^T P^T ----
#pragma unroll
      for (int kc=0;kc<2;kc++){
        const int gbp = c0*128 + kc*64 + g*16;
        const bf16x8 pa = *(const bf16x8*)((const char*)Pw + (gbp ^ swz(c0)));
        bf16x8 vf[4];
#pragma unroll
        for (int d=0; d<4; d++){
          const int rr = d*16 + c0;
          const int gb2 = rr*128 + kc*64 + g*16;
          vf[d] = *(const bf16x8*)((const char*)Vt[cur] + (gb2 ^ swz(rr)));
        }
        __builtin_amdgcn_s_setprio(1);
#pragma unroll
        for (int d=0; d<4; d++)
          oacc[d] = __builtin_amdgcn_mfma_f32_16x16x32_bf16(vf[d], pa, oacc[d], 0,0,0);
        __builtin_amdgcn_s_setprio(0);
      }

      if (pre){
#pragma unroll
        for (int e=0;e<8;e++){
          const int row = dc*8 + e;
          const int gbyte = row*128 + rp*4;
          const u16 a = (e<4) ? v0a.e[e] : v0b.e[e-4];
          const u16 bb2 = (e<4) ? v1a.e[e] : v1b.e[e-4];
          const uint32_t pk = (uint32_t)a | ((uint32_t)bb2 << 16);
          *(uint32_t*)((char*)Vt[nxt] + (gbyte ^ swz(row))) = pk;
        }
      }
      __syncthreads();
    }

    // ---- write attn output (per-lane q-row): O[b, q, h*64 + dh] ----
    {
      const float inv = 1.0f / lrun;
      u16* orow = O + ((size_t)b*SEQ + q)*DMODEL + h*DH;
#pragma unroll
      for (int d=0;d<4;d++){
#pragma unroll
        for (int r2=0;r2<2;r2++){
          const u16 a0 = f2bf(oacc[d][2*r2]   * inv);
          const u16 a1 = f2bf(oacc[d][2*r2+1] * inv);
          *(uint32_t*)(orow + d*16 + g*4 + 2*r2) = (uint32_t)a0 | ((uint32_t)a1 << 16);
        }
      }
    }
  }
}

// ---------------------------------------------------------------------------
extern "C" void kernel_launch(void* const* d_in, const int* in_sizes, int n_in,
                              void* d_out, int out_size, void* d_ws, size_t ws_size,
                              hipStream_t stream)
{
  const float* x  = (const float*)d_in[0];
  const float* Wq = (const float*)d_in[1];
  const float* bq = (const float*)d_in[2];
  const float* Wk = (const float*)d_in[3];
  const float* bk = (const float*)d_in[4];
  const float* Wv = (const float*)d_in[5];
  const float* bv = (const float*)d_in[6];
  const float* Wo = (const float*)d_in[7];
  const float* bo = (const float*)d_in[8];
  // d_in[9]: causal mask (int32) — implemented analytically, not read.

  const size_t MB = 1024*1024;
  char* ws = (char*)d_ws;
  u16*  xb   = (u16*)(ws);                 // [0,16MB)  x bf16; dead after QKV
  u16*  aw   = (u16*)(ws);                 // attn out reuses region
  u16*  vw   = (u16*)(ws + 16*MB);         // [16,32MB) V [B,H,S,Dh]
  u16*  wqkv = (u16*)(ws + 32*MB);         // [32,38MB) Wq|Wk|Wv bf16 [3072][1024]
  u16*  wob  = (u16*)(ws + 38*MB);         // [38,40MB)
  float* bcat = (float*)(ws + 40*MB);      // 12KB  bq|bk|bv
  float* tab  = (float*)(ws + 41*MB);      // 512KB
  // d_out (32MB f32) doubles as scratch for q/k (bf16, dead before final GEMM)
  u16*  qw = (u16*)d_out;
  u16*  kw = (u16*)d_out + 8*MB;

  const int NX = 4*SEQ*DMODEL;   // 8,388,608
  const int NW = DMODEL*DMODEL;  // 1,048,576
  cvt_f32_bf16<<<dim3(NX/1024), dim3(256), 0, stream>>>(x,  xb, NX);
  cvt_f32_bf16<<<dim3(NW/1024), dim3(256), 0, stream>>>(Wq, wqkv,        NW);
  cvt_f32_bf16<<<dim3(NW/1024), dim3(256), 0, stream>>>(Wk, wqkv + NW,   NW);
  cvt_f32_bf16<<<dim3(NW/1024), dim3(256), 0, stream>>>(Wv, wqkv + 2*NW, NW);
  cvt_f32_bf16<<<dim3(NW/1024), dim3(256), 0, stream>>>(Wo, wob, NW);
  hipMemcpyAsync(bcat,          bq, DMODEL*4, hipMemcpyDeviceToDevice, stream);
  hipMemcpyAsync(bcat+DMODEL,   bk, DMODEL*4, hipMemcpyDeviceToDevice, stream);
  hipMemcpyAsync(bcat+2*DMODEL, bv, DMODEL*4, hipMemcpyDeviceToDevice, stream);

  rope_table<<<dim3(256), dim3(256), 0, stream>>>(tab);

  // fused QKV projection + RoPE epilogue: N=3072
  gemm_bt<0><<<dim3(24, 64), dim3(256), 0, stream>>>(xb, wqkv, bcat, nullptr, qw, kw, vw, tab);

  attn_fwd<<<dim3(64, 16), dim3(256), 0, stream>>>(qw, kw, vw, aw);

  gemm_bt<1><<<dim3(8, 64), dim3(256), 0, stream>>>(aw, wob, bo, (float*)d_out, nullptr, nullptr, nullptr, nullptr);
}

// Round 6
// 200.925 us; speedup vs baseline: 1.9471x; 1.1401x over previous
//
#include <hip/hip_runtime.h>
#include <stdint.h>

typedef unsigned short u16;
typedef __bf16 bf16x8 __attribute__((ext_vector_type(8)));
typedef __bf16 bf16x2 __attribute__((ext_vector_type(2)));
typedef float f32x4 __attribute__((ext_vector_type(4)));

#define SEQ    2048
#define NHEAD  16
#define DH     64
#define DMODEL 1024
#define NBH    64     // B*H

// native bf16 converts (compiler emits v_cvt_pk_bf16_f32 for pairs)
__device__ __forceinline__ u16 cvt1(float f){
  union { __bf16 h; u16 u; } c; c.h = (__bf16)f; return c.u;
}
__device__ __forceinline__ uint32_t cvt2(float a, float b){
  union { bf16x2 v; uint32_t u; } c; c.v = bf16x2{(__bf16)a, (__bf16)b}; return c.u;
}
// LDS XOR-swizzle: bits 4-6 (keeps 16B alignment for b128 reads)
__device__ __forceinline__ int swz(int row){ return (((row&7)^((row>>3)&7))<<4); }

typedef const __attribute__((address_space(1))) uint32_t* gas_t;
typedef __attribute__((address_space(3))) uint32_t* las_t;
__device__ __forceinline__ void async16(const void* g, void* l){
  __builtin_amdgcn_global_load_lds((gas_t)g, (las_t)l, 16, 0, 0);
}

// ---------------- fused prep: 5x f32->bf16 convert + RoPE table -------------
// blocks [0,4096) x; [4096,4608) Wq; [4608,5120) Wk; [5120,5632) Wv;
// [5632,6144) Wo; [6144,6400) rope table
__global__ void prep(const float* __restrict__ x,  const float* __restrict__ Wq,
                     const float* __restrict__ Wk, const float* __restrict__ Wv,
                     const float* __restrict__ Wo,
                     u16* __restrict__ xb, u16* __restrict__ wqkv,
                     u16* __restrict__ wob, float* __restrict__ tab)
{
  const int bid = blockIdx.x, tid = threadIdx.x;
  if (bid < 6144){
    const float* src; u16* dst; int lb;
    if      (bid < 4096){ src = x;  dst = xb;              lb = bid; }
    else if (bid < 4608){ src = Wq; dst = wqkv;            lb = bid-4096; }
    else if (bid < 5120){ src = Wk; dst = wqkv + 1048576;  lb = bid-4608; }
    else if (bid < 5632){ src = Wv; dst = wqkv + 2097152;  lb = bid-5120; }
    else                { src = Wo; dst = wob;             lb = bid-5632; }
    const size_t off = (size_t)lb*2048 + tid*8;
    float4 a = *(const float4*)(src+off);
    float4 b = *(const float4*)(src+off+4);
    bf16x8 o = { (__bf16)a.x,(__bf16)a.y,(__bf16)a.z,(__bf16)a.w,
                 (__bf16)b.x,(__bf16)b.y,(__bf16)b.z,(__bf16)b.w };
    *(bf16x8*)(dst+off) = o;
  } else {
    const int t = (bid-6144)*256 + tid;          // < 65536
    const int s = t >> 5, j = t & 31;
    double freq = exp(-(double)(2*j)/64.0*log(10000.0));
    double ang = (double)s*freq;
    tab[s*64 + 2*j]     = (float)cos(ang);
    tab[s*64 + 2*j + 1] = (float)sin(ang);
  }
}

// ---------------- GEMM: dst = A @ W^T + bias  (bf16 in, NT layout) ----------
// MODE 0: fused QKV (N=3072): scatter bf16 to per-head [B,H,S,Dh]; RoPE fused;
//         Q additionally scaled by 0.125*log2(e) (softmax in exp2 domain)
// MODE 1: f32 dst linear [M][1024], bias = b0
template<int MODE>
__global__ __launch_bounds__(256, 2)
void gemm_bt(const u16* __restrict__ A, const u16* __restrict__ W,
             const float* __restrict__ b0, const float* __restrict__ b1,
             const float* __restrict__ b2, float* __restrict__ fout,
             u16* __restrict__ dq, u16* __restrict__ dk, u16* __restrict__ dv,
             const float* __restrict__ tab)
{
  __shared__ u16 Ab[128*32];
  __shared__ u16 Bb[128*32];
  const int tid = threadIdx.x;
  const int lane = tid & 63;
  const int w = tid >> 6, wr = w >> 1, wc = w & 1;
  const int m0 = blockIdx.y * 128;
  const int n0 = blockIdx.x * 128;
  const int c0 = lane & 15, g = lane >> 4;

  f32x4 acc[4][4] = {};

  const int sr = tid >> 2;          // staging row 0..63
  const int sc = (tid & 3) * 8;     // staging col (elements)
  const u16* ga = A + (size_t)(m0 + sr) * DMODEL + sc;
  const u16* gb = W + (size_t)(n0 + sr) * DMODEL + sc;
  u16* la = Ab + sr*32 + sc;
  u16* lb = Bb + sr*32 + sc;

  for (int k0 = 0; k0 < DMODEL; k0 += 32) {
    __syncthreads();
    async16(ga + k0,             la);
    async16(ga + k0 + 64*DMODEL, la + 64*32);
    async16(gb + k0,             lb);
    async16(gb + k0 + 64*DMODEL, lb + 64*32);
    __syncthreads();
    bf16x8 afr[4], bfr[4];
#pragma unroll
    for (int i=0;i<4;i++) afr[i] = *(const bf16x8*)(Ab + (wr*64 + i*16 + c0)*32 + g*8);
#pragma unroll
    for (int j=0;j<4;j++) bfr[j] = *(const bf16x8*)(Bb + (wc*64 + j*16 + c0)*32 + g*8);
    __builtin_amdgcn_s_setprio(1);
#pragma unroll
    for (int i=0;i<4;i++)
#pragma unroll
      for (int j=0;j<4;j++)
        acc[i][j] = __builtin_amdgcn_mfma_f32_16x16x32_bf16(afr[i], bfr[j], acc[i][j], 0,0,0);
    __builtin_amdgcn_s_setprio(0);
  }

  const int nbase = n0 + wc*64;
  const int t = n0 >> 10;                 // 0=q 1=k 2=v (tiles never cross)
  const float* bias = (MODE==1) ? b0 : (t==0) ? b0 : (t==1) ? b1 : b2;
  float bv4[4];
#pragma unroll
  for (int j=0;j<4;j++) bv4[j] = bias[(nbase & 1023) + j*16 + c0];

  if (MODE == 0) {
    u16* dst = (t==0) ? dq : (t==1) ? dk : dv;
    const float qs = (t==0) ? 0.18033688011f : 1.0f;   // 0.125*log2(e)
    const int h = (nbase >> 6) & (NHEAD-1);
#pragma unroll
    for (int i=0;i<4;i++){
      const int mbase = m0 + wr*64 + i*16 + g*4;
#pragma unroll
      for (int r=0;r<4;r++){
        const int mm = mbase + r;
        const int bb = mm >> 11, s = mm & (SEQ-1);
        const size_t rowbase = (((size_t)(bb*NHEAD + h))*SEQ + s)*DH;
        if (t < 2) {
#pragma unroll
          for (int j2=0;j2<2;j2++){
            const int dh = j2*16 + c0;
            const float xl = acc[i][j2][r]   + bv4[j2];
            const float xh = acc[i][j2+2][r] + bv4[j2+2];
            const float2 cs = *(const float2*)(tab + (size_t)s*64 + dh*2);
            dst[rowbase + dh]      = cvt1((xl*cs.x - xh*cs.y)*qs);
            dst[rowbase + dh + 32] = cvt1((xh*cs.x + xl*cs.y)*qs);
          }
        } else {
#pragma unroll
          for (int j=0;j<4;j++)
            dst[rowbase + j*16 + c0] = cvt1(acc[i][j][r] + bv4[j]);
        }
      }
    }
  } else {
#pragma unroll
    for (int i=0;i<4;i++){
      const int mbase = m0 + wr*64 + i*16 + g*4;
#pragma unroll
      for (int j=0;j<4;j++){
#pragma unroll
        for (int r=0;r<4;r++)
          fout[(size_t)(mbase + r) * DMODEL + nbase + j*16 + c0] = acc[i][j][r] + bv4[j];
      }
    }
  }
}

// ---------------- Flash attention: in-register P via sigma-permuted V -------
// grid (64, 16): x = bh (XCD locality: id%8 = bh%8), y = pair (qt = p / 31-p)
// V-tile stored with kv-position permutation sigma so the PV B-operand is
// formed entirely in-lane from the softmax outputs (no P LDS round-trip).
__global__ __launch_bounds__(256, 4)
void attn_fwd(const u16* __restrict__ Q, const u16* __restrict__ K,
              const u16* __restrict__ V, u16* __restrict__ O)
{
  __shared__ u16 Kb[2][64*64];  // [kv][dh], swizzled (pre-swizzled source)
  __shared__ u16 Vt[2][64*64];  // [dh][pos], swizzled; pos = sigma^-1(kv)
  const int bh = blockIdx.x;
  const int pair = blockIdx.y;              // 0..15
  const int tid = threadIdx.x, lane = tid & 63, w = tid >> 6;
  const int c0 = lane & 15, g = lane >> 4;
  const size_t hb = (size_t)bh * SEQ * DH;
  const int b = bh >> 4, h = bh & 15;

  const int boff  = tid*16;
  const int sw1   = boff  ^ swz(boff  >> 7);
  const int boff2 = boff + 4096;
  const int sw2   = boff2 ^ swz(boff2 >> 7);
  const int rp = tid >> 3, dc = tid & 7;    // V-transpose roles
  // kv pair (2rp, 2rp+1) -> byte col = perm(2rp)*2 (sigma^-1 fixes bits 1:0)
  const int kv0 = 2*rp;
  const int vpos = (kv0 & 0x23) | ((kv0 & 0x10) >> 2) | ((kv0 & 0x0C) << 1);
  union U4 { ushort4 v; u16 e[4]; };

#pragma unroll 1
  for (int half = 0; half < 2; half++){
    const int qt = half ? (31 - pair) : pair;       // paired: 33 iters/block
    const int qrow_base = qt*64 + w*16;
    const int jt_end = qt;
    const int q = qrow_base + c0;                   // this lane's q-row

    bf16x8 qf[2];
#pragma unroll
    for (int kc=0;kc<2;kc++)
      qf[kc] = *(const bf16x8*)(Q + hb + (size_t)q*DH + kc*32 + g*8);

    // transposed accumulators: oacc[d][r] = O[dh=d*16+g*4+r][q]
    f32x4 oacc[4] = {};
    float mrun = -3.0e38f, lrun = 0.f;

    // ---- prologue: stage tile 0 into buffer 0 ----
    {
      const char* gk = (const char*)(K + hb);
      async16(gk + sw1, (char*)Kb[0] + boff);
      async16(gk + sw2, (char*)Kb[0] + boff2);
      const u16* gv = V + hb;
      U4 v0a, v0b, v1a, v1b;
      v0a.v = *(const ushort4*)(gv + (kv0  )*DH + dc*8);
      v0b.v = *(const ushort4*)(gv + (kv0  )*DH + dc*8 + 4);
      v1a.v = *(const ushort4*)(gv + (kv0+1)*DH + dc*8);
      v1b.v = *(const ushort4*)(gv + (kv0+1)*DH + dc*8 + 4);
#pragma unroll
      for (int e=0;e<8;e++){
        const int row = dc*8 + e;
        const int gbyte = row*128 + vpos*2;
        const u16 a   = (e<4) ? v0a.e[e] : v0b.e[e-4];
        const u16 bb2 = (e<4) ? v1a.e[e] : v1b.e[e-4];
        *(uint32_t*)((char*)Vt[0] + (gbyte ^ swz(row))) = (uint32_t)a | ((uint32_t)bb2 << 16);
      }
    }
    __syncthreads();

    U4 v0a, v0b, v1a, v1b;   // prefetch regs
    for (int jt = 0; jt <= jt_end; jt++){
      const int cur = jt & 1, nxt = cur ^ 1;
      const bool pre = (jt < jt_end);
      if (pre){
        const char* gk = (const char*)(K + hb + (size_t)(jt+1)*64*DH);
        async16(gk + sw1, (char*)Kb[nxt] + boff);
        async16(gk + sw2, (char*)Kb[nxt] + boff2);
        const u16* gv = V + hb + (size_t)(jt+1)*64*DH;
        v0a.v = *(const ushort4*)(gv + (kv0  )*DH + dc*8);
        v0b.v = *(const ushort4*)(gv + (kv0  )*DH + dc*8 + 4);
        v1a.v = *(const ushort4*)(gv + (kv0+1)*DH + dc*8);
        v1b.v = *(const ushort4*)(gv + (kv0+1)*DH + dc*8 + 4);
      }

      // ---- S^T = K Q'^T (Q pre-scaled: log2-domain logits) ----
      f32x4 sT[4] = {};
#pragma unroll
      for (int kc=0;kc<2;kc++){
        bf16x8 kf[4];
#pragma unroll
        for (int j=0;j<4;j++){
          const int rr = j*16 + c0;
          const int gb2 = rr*128 + kc*64 + g*16;
          kf[j] = *(const bf16x8*)((const char*)Kb[cur] + (gb2 ^ swz(rr)));
        }
        __builtin_amdgcn_s_setprio(1);
#pragma unroll
        for (int j=0;j<4;j++)
          sT[j] = __builtin_amdgcn_mfma_f32_16x16x32_bf16(kf[j], qf[kc], sT[j], 0,0,0);
        __builtin_amdgcn_s_setprio(0);
      }
      // ---- causal mask: only the diagonal tile needs it ----
      if (jt == jt_end){
#pragma unroll
        for (int j=0;j<4;j++)
#pragma unroll
          for (int r=0;r<4;r++){
            const int kv = jt*64 + j*16 + g*4 + r;
            sT[j][r] = (kv <= q) ? sT[j][r] : -3.0e38f;
          }
      }
      // ---- online softmax (per-lane q-row; exp2 domain; defer-max) ----
      float mx = -3.0e38f;
#pragma unroll
      for (int j=0;j<4;j++)
#pragma unroll
        for (int r=0;r<4;r++) mx = fmaxf(mx, sT[j][r]);
      mx = fmaxf(mx, __shfl_xor(mx, 16));
      mx = fmaxf(mx, __shfl_xor(mx, 32));
      const bool grow = __any(mx > mrun + 8.0f);
      float corr = 1.0f;
      if (grow){
        const float mnew = fmaxf(mrun, mx);
        corr = exp2f(mrun - mnew);
        mrun = mnew;
      }
      // P in-register: pa[kc][e] = p[2kc + (e>>2)][e&3]  (matches sigma-V)
      bf16x8 pa0, pa1;
      float lsum = 0.f;
#pragma unroll
      for (int j=0;j<4;j++){
#pragma unroll
        for (int r=0;r<4;r++){
          const float p = exp2f(sT[j][r] - mrun);
          lsum += p;
          if (j<2) pa0[(j&1)*4 + r] = (__bf16)p;
          else     pa1[(j&1)*4 + r] = (__bf16)p;
        }
      }
      lsum += __shfl_xor(lsum, 16);
      lsum += __shfl_xor(lsum, 32);
      lrun = lrun*corr + lsum;
      if (grow){
#pragma unroll
        for (int d=0;d<4;d++)
#pragma unroll
          for (int r=0;r<4;r++) oacc[d][r] *= corr;
      }
      // ---- O^T += V^T P^T (pa formed in-lane; no LDS for P) ----
#pragma unroll
      for (int kc=0;kc<2;kc++){
        const bf16x8 pa = kc ? pa1 : pa0;
        bf16x8 vf[4];
#pragma unroll
        for (int d=0; d<4; d++){
          const int rr = d*16 + c0;
          const int gb2 = rr*128 + kc*64 + g*16;
          vf[d] = *(const bf16x8*)((const char*)Vt[cur] + (gb2 ^ swz(rr)));
        }
        __builtin_amdgcn_s_setprio(1);
#pragma unroll
        for (int d=0; d<4; d++)
          oacc[d] = __builtin_amdgcn_mfma_f32_16x16x32_bf16(vf[d], pa, oacc[d], 0,0,0);
        __builtin_amdgcn_s_setprio(0);
      }

      if (pre){
#pragma unroll
        for (int e=0;e<8;e++){
          const int row = dc*8 + e;
          const int gbyte = row*128 + vpos*2;
          const u16 a   = (e<4) ? v0a.e[e] : v0b.e[e-4];
          const u16 bb2 = (e<4) ? v1a.e[e] : v1b.e[e-4];
          *(uint32_t*)((char*)Vt[nxt] + (gbyte ^ swz(row))) = (uint32_t)a | ((uint32_t)bb2 << 16);
        }
      }
      __syncthreads();
    }

    // ---- write attn output (per-lane q-row): O[b, q, h*64 + dh] ----
    {
      const float inv = 1.0f / lrun;
      u16* orow = O + ((size_t)b*SEQ + q)*DMODEL + h*DH;
#pragma unroll
      for (int d=0;d<4;d++)
#pragma unroll
        for (int r2=0;r2<2;r2++)
          *(uint32_t*)(orow + d*16 + g*4 + 2*r2) =
            cvt2(oacc[d][2*r2]*inv, oacc[d][2*r2+1]*inv);
    }
  }
}

// ---------------------------------------------------------------------------
extern "C" void kernel_launch(void* const* d_in, const int* in_sizes, int n_in,
                              void* d_out, int out_size, void* d_ws, size_t ws_size,
                              hipStream_t stream)
{
  const float* x  = (const float*)d_in[0];
  const float* Wq = (const float*)d_in[1];
  const float* bq = (const float*)d_in[2];
  const float* Wk = (const float*)d_in[3];
  const float* bk = (const float*)d_in[4];
  const float* Wv = (const float*)d_in[5];
  const float* bv = (const float*)d_in[6];
  const float* Wo = (const float*)d_in[7];
  const float* bo = (const float*)d_in[8];
  // d_in[9]: causal mask (int32) — implemented analytically, not read.

  const size_t MB = 1024*1024;
  char* ws = (char*)d_ws;
  u16*  xb   = (u16*)(ws);                 // [0,16MB)  x bf16; dead after QKV
  u16*  aw   = (u16*)(ws);                 // attn out reuses region
  u16*  vw   = (u16*)(ws + 16*MB);         // [16,32MB) V [B,H,S,Dh]
  u16*  wqkv = (u16*)(ws + 32*MB);         // [32,38MB) Wq|Wk|Wv bf16 [3072][1024]
  u16*  wob  = (u16*)(ws + 38*MB);         // [38,40MB)
  float* tab = (float*)(ws + 41*MB);       // 512KB
  // d_out (32MB f32) doubles as scratch for q/k (bf16, dead before final GEMM)
  u16*  qw = (u16*)d_out;
  u16*  kw = (u16*)d_out + 8*MB;

  prep<<<dim3(6400), dim3(256), 0, stream>>>(x, Wq, Wk, Wv, Wo, xb, wqkv, wob, tab);

  // fused QKV projection + RoPE epilogue: N=3072
  gemm_bt<0><<<dim3(24, 64), dim3(256), 0, stream>>>(xb, wqkv, bq, bk, bv,
                                                     nullptr, qw, kw, vw, tab);

  attn_fwd<<<dim3(64, 16), dim3(256), 0, stream>>>(qw, kw, vw, aw);

  gemm_bt<1><<<dim3(8, 64), dim3(256), 0, stream>>>(aw, wob, bo, nullptr, nullptr,
                                                    (float*)d_out, nullptr, nullptr, nullptr, nullptr);
}

// Round 7
// 197.576 us; speedup vs baseline: 1.9801x; 1.0170x over previous
//
#include <hip/hip_runtime.h>
#include <stdint.h>

typedef unsigned short u16;
typedef __bf16 bf16x8 __attribute__((ext_vector_type(8)));
typedef __bf16 bf16x2 __attribute__((ext_vector_type(2)));
typedef float f32x4 __attribute__((ext_vector_type(4)));
typedef float f32x16 __attribute__((ext_vector_type(16)));

#define SEQ    2048
#define NHEAD  16
#define DH     64
#define DMODEL 1024
#define NBH    64     // B*H

// native bf16 converts (compiler emits v_cvt_pk_bf16_f32 for pairs)
__device__ __forceinline__ u16 cvt1(float f){
  union { __bf16 h; u16 u; } c; c.h = (__bf16)f; return c.u;
}
__device__ __forceinline__ uint32_t cvt2(float a, float b){
  union { bf16x2 v; uint32_t u; } c; c.v = bf16x2{(__bf16)a, (__bf16)b}; return c.u;
}
// LDS XOR-swizzle: bits 4-6 (keeps 16B alignment for b128 reads)
__device__ __forceinline__ int swz(int row){ return (((row&7)^((row>>3)&7))<<4); }

typedef const __attribute__((address_space(1))) uint32_t* gas_t;
typedef __attribute__((address_space(3))) uint32_t* las_t;
__device__ __forceinline__ void async16(const void* g, void* l){
  __builtin_amdgcn_global_load_lds((gas_t)g, (las_t)l, 16, 0, 0);
}

// ---------------- fused prep: 5x f32->bf16 convert + RoPE table -------------
__global__ void prep(const float* __restrict__ x,  const float* __restrict__ Wq,
                     const float* __restrict__ Wk, const float* __restrict__ Wv,
                     const float* __restrict__ Wo,
                     u16* __restrict__ xb, u16* __restrict__ wqkv,
                     u16* __restrict__ wob, float* __restrict__ tab)
{
  const int bid = blockIdx.x, tid = threadIdx.x;
  if (bid < 6144){
    const float* src; u16* dst; int lb;
    if      (bid < 4096){ src = x;  dst = xb;              lb = bid; }
    else if (bid < 4608){ src = Wq; dst = wqkv;            lb = bid-4096; }
    else if (bid < 5120){ src = Wk; dst = wqkv + 1048576;  lb = bid-4608; }
    else if (bid < 5632){ src = Wv; dst = wqkv + 2097152;  lb = bid-5120; }
    else                { src = Wo; dst = wob;             lb = bid-5632; }
    const size_t off = (size_t)lb*2048 + tid*8;
    float4 a = *(const float4*)(src+off);
    float4 b = *(const float4*)(src+off+4);
    bf16x8 o = { (__bf16)a.x,(__bf16)a.y,(__bf16)a.z,(__bf16)a.w,
                 (__bf16)b.x,(__bf16)b.y,(__bf16)b.z,(__bf16)b.w };
    *(bf16x8*)(dst+off) = o;
  } else {
    const int t = (bid-6144)*256 + tid;          // < 65536
    const int s = t >> 5, j = t & 31;
    double freq = exp(-(double)(2*j)/64.0*log(10000.0));
    double ang = (double)s*freq;
    tab[s*64 + 2*j]     = (float)cos(ang);
    tab[s*64 + 2*j + 1] = (float)sin(ang);
  }
}

// ---------------- GEMM: dst = A @ W^T + bias  (bf16 in, NT layout) ----------
template<int MODE>
__global__ __launch_bounds__(256, 2)
void gemm_bt(const u16* __restrict__ A, const u16* __restrict__ W,
             const float* __restrict__ b0, const float* __restrict__ b1,
             const float* __restrict__ b2, float* __restrict__ fout,
             u16* __restrict__ dq, u16* __restrict__ dk, u16* __restrict__ dv,
             const float* __restrict__ tab)
{
  __shared__ u16 Ab[128*32];
  __shared__ u16 Bb[128*32];
  const int tid = threadIdx.x;
  const int lane = tid & 63;
  const int w = tid >> 6, wr = w >> 1, wc = w & 1;
  const int m0 = blockIdx.y * 128;
  const int n0 = blockIdx.x * 128;
  const int c0 = lane & 15, g = lane >> 4;

  f32x4 acc[4][4] = {};

  const int sr = tid >> 2;          // staging row 0..63
  const int sc = (tid & 3) * 8;     // staging col (elements)
  const u16* ga = A + (size_t)(m0 + sr) * DMODEL + sc;
  const u16* gb = W + (size_t)(n0 + sr) * DMODEL + sc;
  u16* la = Ab + sr*32 + sc;
  u16* lb = Bb + sr*32 + sc;

  for (int k0 = 0; k0 < DMODEL; k0 += 32) {
    __syncthreads();
    async16(ga + k0,             la);
    async16(ga + k0 + 64*DMODEL, la + 64*32);
    async16(gb + k0,             lb);
    async16(gb + k0 + 64*DMODEL, lb + 64*32);
    __syncthreads();
    bf16x8 afr[4], bfr[4];
#pragma unroll
    for (int i=0;i<4;i++) afr[i] = *(const bf16x8*)(Ab + (wr*64 + i*16 + c0)*32 + g*8);
#pragma unroll
    for (int j=0;j<4;j++) bfr[j] = *(const bf16x8*)(Bb + (wc*64 + j*16 + c0)*32 + g*8);
    __builtin_amdgcn_s_setprio(1);
#pragma unroll
    for (int i=0;i<4;i++)
#pragma unroll
      for (int j=0;j<4;j++)
        acc[i][j] = __builtin_amdgcn_mfma_f32_16x16x32_bf16(afr[i], bfr[j], acc[i][j], 0,0,0);
    __builtin_amdgcn_s_setprio(0);
  }

  const int nbase = n0 + wc*64;
  const int t = n0 >> 10;                 // 0=q 1=k 2=v (tiles never cross)
  const float* bias = (MODE==1) ? b0 : (t==0) ? b0 : (t==1) ? b1 : b2;
  float bv4[4];
#pragma unroll
  for (int j=0;j<4;j++) bv4[j] = bias[(nbase & 1023) + j*16 + c0];

  if (MODE == 0) {
    u16* dst = (t==0) ? dq : (t==1) ? dk : dv;
    const float qs = (t==0) ? 0.18033688011f : 1.0f;   // 0.125*log2(e)
    const int h = (nbase >> 6) & (NHEAD-1);
#pragma unroll
    for (int i=0;i<4;i++){
      const int mbase = m0 + wr*64 + i*16 + g*4;
#pragma unroll
      for (int r=0;r<4;r++){
        const int mm = mbase + r;
        const int bb = mm >> 11, s = mm & (SEQ-1);
        const size_t rowbase = (((size_t)(bb*NHEAD + h))*SEQ + s)*DH;
        if (t < 2) {
#pragma unroll
          for (int j2=0;j2<2;j2++){
            const int dh = j2*16 + c0;
            const float xl = acc[i][j2][r]   + bv4[j2];
            const float xh = acc[i][j2+2][r] + bv4[j2+2];
            const float2 cs = *(const float2*)(tab + (size_t)s*64 + dh*2);
            dst[rowbase + dh]      = cvt1((xl*cs.x - xh*cs.y)*qs);
            dst[rowbase + dh + 32] = cvt1((xh*cs.x + xl*cs.y)*qs);
          }
        } else {
#pragma unroll
          for (int j=0;j<4;j++)
            dst[rowbase + j*16 + c0] = cvt1(acc[i][j][r] + bv4[j]);
        }
      }
    }
  } else {
#pragma unroll
    for (int i=0;i<4;i++){
      const int mbase = m0 + wr*64 + i*16 + g*4;
#pragma unroll
      for (int j=0;j<4;j++){
#pragma unroll
        for (int r=0;r<4;r++)
          fout[(size_t)(mbase + r) * DMODEL + nbase + j*16 + c0] = acc[i][j][r] + bv4[j];
      }
    }
  }
}

// ---------------- Flash attention: 8 waves x 32q, 32x32x16 MFMA -------------
// grid (64, 4): x = bh (XCD locality), y = pair; qt = pair / 7-pair (36 iters)
// V stored kv-position-permuted (sigma) so PV's B-operand is the softmax
// output in-register; sigma fixes bits 1:0 so packed dword stores survive.
__global__ __launch_bounds__(512, 1)
void attn_fwd(const u16* __restrict__ Q, const u16* __restrict__ K,
              const u16* __restrict__ V, u16* __restrict__ O)
{
  __shared__ u16 Kb[2][64*64];  // [kv][dh], swizzled (pre-swizzled source)
  __shared__ u16 Vt[2][64*64];  // [dh][pos], swizzled; pos = sigma^-1(kv)
  const int bh = blockIdx.x;
  const int pair = blockIdx.y;              // 0..3
  const int tid = threadIdx.x, lane = tid & 63, w = tid >> 6;
  const int c31 = lane & 31, hi = lane >> 5;
  const size_t hb = (size_t)bh * SEQ * DH;
  const int b = bh >> 4, h = bh & 15;

  // K staging: one async16 per thread (512 x 16B = 8KB tile)
  const int boff = tid*16;
  const int ksw  = boff ^ swz(boff >> 7);
  // V staging: kv pair (2rp,2rp+1), dh 4-chunk dc
  const int rp = tid >> 4, dc = tid & 15;
  const int kv0 = 2*rp;
  const int vpos = (kv0 & 0x33) | ((kv0 & 4) << 1) | ((kv0 & 8) >> 1);
  union U4 { ushort4 v; u16 e[4]; };

#pragma unroll 1
  for (int half = 0; half < 2; half++){
    const int qt = half ? (7 - pair) : pair;
    const int qrow_base = qt*256 + w*32;
    const int jt_last  = 4*qt + 3;
    const int jt_end_w = 4*qt + (w>>1);     // this wave's diagonal tile
    const int q = qrow_base + c31;          // this lane's q-row

    bf16x8 qf[4];
#pragma unroll
    for (int kc=0;kc<4;kc++)
      qf[kc] = *(const bf16x8*)(Q + hb + (size_t)q*DH + kc*16 + hi*8);

    f32x16 oacc0 = {}, oacc1 = {};          // O^T[dh = dhb*32 + pat][q]
    float mrun = -3.0e38f, lrun = 0.f;

    // ---- prologue: stage tile 0 into buffer 0 ----
    {
      const char* gk = (const char*)(K + hb);
      async16(gk + ksw, (char*)Kb[0] + boff);
      const u16* gv = V + hb;
      U4 va, vb;
      va.v = *(const ushort4*)(gv + kv0*DH + dc*4);
      vb.v = *(const ushort4*)(gv + (kv0+1)*DH + dc*4);
#pragma unroll
      for (int d=0; d<4; d++){
        const int row = dc*4 + d;
        *(uint32_t*)((char*)Vt[0] + ((row*128 + vpos*2) ^ swz(row))) =
          (uint32_t)va.e[d] | ((uint32_t)vb.e[d] << 16);
      }
    }
    __syncthreads();

    U4 va, vb;   // prefetch regs
    for (int jt = 0; jt <= jt_last; jt++){
      const int cur = jt & 1, nxt = cur ^ 1;
      const bool pre = (jt < jt_last);
      if (pre){
        const char* gk = (const char*)(K + hb + (size_t)(jt+1)*64*DH);
        async16(gk + ksw, (char*)Kb[nxt] + boff);
        const u16* gv = V + hb + (size_t)(jt+1)*64*DH;
        va.v = *(const ushort4*)(gv + kv0*DH + dc*4);
        vb.v = *(const ushort4*)(gv + (kv0+1)*DH + dc*4);
      }

      if (jt <= jt_end_w){
        // ---- S^T = K Q'^T : sT[kvb][r] = S[kv][q], kv=(r&3)+8(r>>2)+4hi ----
        f32x16 sT[2] = {};
#pragma unroll
        for (int kc=0;kc<4;kc++){
          const int col = (kc*16 + hi*8)*2;
          const int r0 = c31, r1 = 32 + c31;
          const bf16x8 kf0 = *(const bf16x8*)((const char*)Kb[cur] + ((r0*128 + col) ^ swz(r0)));
          const bf16x8 kf1 = *(const bf16x8*)((const char*)Kb[cur] + ((r1*128 + col) ^ swz(r1)));
          __builtin_amdgcn_s_setprio(1);
          sT[0] = __builtin_amdgcn_mfma_f32_32x32x16_bf16(kf0, qf[kc], sT[0], 0,0,0);
          sT[1] = __builtin_amdgcn_mfma_f32_32x32x16_bf16(kf1, qf[kc], sT[1], 0,0,0);
          __builtin_amdgcn_s_setprio(0);
        }
        // ---- causal mask: only this wave's diagonal tile ----
        if (jt == jt_end_w){
#pragma unroll
          for (int kvb=0;kvb<2;kvb++)
#pragma unroll
            for (int r=0;r<16;r++){
              const int kv = jt*64 + kvb*32 + (r&3) + 8*(r>>2) + 4*hi;
              sT[kvb][r] = (kv <= q) ? sT[kvb][r] : -3.0e38f;
            }
        }
        // ---- online softmax (per-lane q-col; exp2 domain; defer-max) ----
        float mx = -3.0e38f;
#pragma unroll
        for (int kvb=0;kvb<2;kvb++)
#pragma unroll
          for (int r=0;r<16;r++) mx = fmaxf(mx, sT[kvb][r]);
        mx = fmaxf(mx, __shfl_xor(mx, 32));
        const bool grow = __any(mx > mrun + 8.0f);
        float corr = 1.0f;
        if (grow){
          const float mnew = fmaxf(mrun, mx);
          corr = exp2f(mrun - mnew);
          mrun = mnew;
        }
        float lsum = 0.f;
#pragma unroll
        for (int kvb=0;kvb<2;kvb++)
#pragma unroll
          for (int r=0;r<16;r++){
            const float p = exp2f(sT[kvb][r] - mrun);
            sT[kvb][r] = p;
            lsum += p;
          }
        lsum += __shfl_xor(lsum, 32);
        lrun = lrun*corr + lsum;
        if (grow){
#pragma unroll
          for (int r=0;r<16;r++){ oacc0[r] *= corr; oacc1[r] *= corr; }
        }
        // ---- O^T += V^T P^T (P in-register; V sigma-permuted in LDS) ----
#pragma unroll
        for (int kvb=0;kvb<2;kvb++)
#pragma unroll
          for (int s=0;s<2;s++){
            union { bf16x8 v; uint32_t d[4]; } pa;
#pragma unroll
            for (int j=0;j<4;j++)
              pa.d[j] = cvt2(sT[kvb][s*8+2*j], sT[kvb][s*8+2*j+1]);
            const int col = (kvb*32 + s*16 + hi*8)*2;
            const int r0 = c31, r1 = 32 + c31;
            const bf16x8 vf0 = *(const bf16x8*)((const char*)Vt[cur] + ((r0*128 + col) ^ swz(r0)));
            const bf16x8 vf1 = *(const bf16x8*)((const char*)Vt[cur] + ((r1*128 + col) ^ swz(r1)));
            __builtin_amdgcn_s_setprio(1);
            oacc0 = __builtin_amdgcn_mfma_f32_32x32x16_bf16(vf0, pa.v, oacc0, 0,0,0);
            oacc1 = __builtin_amdgcn_mfma_f32_32x32x16_bf16(vf1, pa.v, oacc1, 0,0,0);
            __builtin_amdgcn_s_setprio(0);
          }
      }

      if (pre){
#pragma unroll
        for (int d=0; d<4; d++){
          const int row = dc*4 + d;
          *(uint32_t*)((char*)Vt[nxt] + ((row*128 + vpos*2) ^ swz(row))) =
            (uint32_t)va.e[d] | ((uint32_t)vb.e[d] << 16);
        }
      }
      __syncthreads();
    }

    // ---- write attn output (per-lane q-col): O[b, q, h*64 + dh] ----
    {
      const float inv = 1.0f / lrun;
      u16* orow = O + ((size_t)b*SEQ + q)*DMODEL + h*DH;
#pragma unroll
      for (int r2=0;r2<8;r2++){
        const int dh0 = 2*(r2&1) + 8*(r2>>1) + 4*hi;
        *(uint32_t*)(orow + dh0)      = cvt2(oacc0[2*r2]*inv, oacc0[2*r2+1]*inv);
        *(uint32_t*)(orow + 32 + dh0) = cvt2(oacc1[2*r2]*inv, oacc1[2*r2+1]*inv);
      }
    }
  }
}

// ---------------------------------------------------------------------------
extern "C" void kernel_launch(void* const* d_in, const int* in_sizes, int n_in,
                              void* d_out, int out_size, void* d_ws, size_t ws_size,
                              hipStream_t stream)
{
  const float* x  = (const float*)d_in[0];
  const float* Wq = (const float*)d_in[1];
  const float* bq = (const float*)d_in[2];
  const float* Wk = (const float*)d_in[3];
  const float* bk = (const float*)d_in[4];
  const float* Wv = (const float*)d_in[5];
  const float* bv = (const float*)d_in[6];
  const float* Wo = (const float*)d_in[7];
  const float* bo = (const float*)d_in[8];
  // d_in[9]: causal mask (int32) — implemented analytically, not read.

  const size_t MB = 1024*1024;
  char* ws = (char*)d_ws;
  u16*  xb   = (u16*)(ws);                 // [0,16MB)  x bf16; dead after QKV
  u16*  aw   = (u16*)(ws);                 // attn out reuses region
  u16*  vw   = (u16*)(ws + 16*MB);         // [16,32MB) V [B,H,S,Dh]
  u16*  wqkv = (u16*)(ws + 32*MB);         // [32,38MB) Wq|Wk|Wv bf16 [3072][1024]
  u16*  wob  = (u16*)(ws + 38*MB);         // [38,40MB)
  float* tab = (float*)(ws + 41*MB);       // 512KB
  // d_out (32MB f32) doubles as scratch for q/k (bf16, dead before final GEMM)
  u16*  qw = (u16*)d_out;
  u16*  kw = (u16*)d_out + 8*MB;

  prep<<<dim3(6400), dim3(256), 0, stream>>>(x, Wq, Wk, Wv, Wo, xb, wqkv, wob, tab);

  // fused QKV projection + RoPE epilogue: N=3072
  gemm_bt<0><<<dim3(24, 64), dim3(256), 0, stream>>>(xb, wqkv, bq, bk, bv,
                                                     nullptr, qw, kw, vw, tab);

  attn_fwd<<<dim3(64, 4), dim3(512), 0, stream>>>(qw, kw, vw, aw);

  gemm_bt<1><<<dim3(8, 64), dim3(256), 0, stream>>>(aw, wob, bo, nullptr, nullptr,
                                                    (float*)d_out, nullptr, nullptr, nullptr, nullptr);
}

// Round 8
// 192.334 us; speedup vs baseline: 2.0341x; 1.0273x over previous
//
#include <hip/hip_runtime.h>
#include <stdint.h>

typedef unsigned short u16;
typedef __bf16 bf16x8 __attribute__((ext_vector_type(8)));
typedef __bf16 bf16x2 __attribute__((ext_vector_type(2)));
typedef float f32x4 __attribute__((ext_vector_type(4)));
typedef float f32x16 __attribute__((ext_vector_type(16)));

#define SEQ    2048
#define NHEAD  16
#define DH     64
#define DMODEL 1024
#define NBH    64     // B*H

// native bf16 converts (compiler emits v_cvt_pk_bf16_f32 for pairs)
__device__ __forceinline__ u16 cvt1(float f){
  union { __bf16 h; u16 u; } c; c.h = (__bf16)f; return c.u;
}
__device__ __forceinline__ uint32_t cvt2(float a, float b){
  union { bf16x2 v; uint32_t u; } c; c.v = bf16x2{(__bf16)a, (__bf16)b}; return c.u;
}
// LDS XOR-swizzle: bits 4-6 (keeps 16B alignment for b128 reads)
__device__ __forceinline__ int swz(int row){ return (((row&7)^((row>>3)&7))<<4); }

typedef const __attribute__((address_space(1))) uint32_t* gas_t;
typedef __attribute__((address_space(3))) uint32_t* las_t;
__device__ __forceinline__ void async16(const void* g, void* l){
  __builtin_amdgcn_global_load_lds((gas_t)g, (las_t)l, 16, 0, 0);
}

// ---------------- fused prep: 5x f32->bf16 convert + RoPE table -------------
__global__ void prep(const float* __restrict__ x,  const float* __restrict__ Wq,
                     const float* __restrict__ Wk, const float* __restrict__ Wv,
                     const float* __restrict__ Wo,
                     u16* __restrict__ xb, u16* __restrict__ wqkv,
                     u16* __restrict__ wob, float* __restrict__ tab)
{
  const int bid = blockIdx.x, tid = threadIdx.x;
  if (bid < 6144){
    const float* src; u16* dst; int lb;
    if      (bid < 4096){ src = x;  dst = xb;              lb = bid; }
    else if (bid < 4608){ src = Wq; dst = wqkv;            lb = bid-4096; }
    else if (bid < 5120){ src = Wk; dst = wqkv + 1048576;  lb = bid-4608; }
    else if (bid < 5632){ src = Wv; dst = wqkv + 2097152;  lb = bid-5120; }
    else                { src = Wo; dst = wob;             lb = bid-5632; }
    const size_t off = (size_t)lb*2048 + tid*8;
    float4 a = *(const float4*)(src+off);
    float4 b = *(const float4*)(src+off+4);
    bf16x8 o = { (__bf16)a.x,(__bf16)a.y,(__bf16)a.z,(__bf16)a.w,
                 (__bf16)b.x,(__bf16)b.y,(__bf16)b.z,(__bf16)b.w };
    *(bf16x8*)(dst+off) = o;
  } else {
    const int t = (bid-6144)*256 + tid;          // < 65536
    const int s = t >> 5, j = t & 31;
    double freq = exp(-(double)(2*j)/64.0*log(10000.0));
    double ang = (double)s*freq;
    tab[s*64 + 2*j]     = (float)cos(ang);
    tab[s*64 + 2*j + 1] = (float)sin(ang);
  }
}

// ---------------- GEMM: dst = A @ W^T + bias  (bf16 in, NT layout) ----------
template<int MODE>
__global__ __launch_bounds__(256, 2)
void gemm_bt(const u16* __restrict__ A, const u16* __restrict__ W,
             const float* __restrict__ b0, const float* __restrict__ b1,
             const float* __restrict__ b2, float* __restrict__ fout,
             u16* __restrict__ dq, u16* __restrict__ dk, u16* __restrict__ dv,
             const float* __restrict__ tab)
{
  __shared__ u16 Ab[128*32];
  __shared__ u16 Bb[128*32];
  const int tid = threadIdx.x;
  const int lane = tid & 63;
  const int w = tid >> 6, wr = w >> 1, wc = w & 1;
  const int m0 = blockIdx.y * 128;
  const int n0 = blockIdx.x * 128;
  const int c0 = lane & 15, g = lane >> 4;

  f32x4 acc[4][4] = {};

  const int sr = tid >> 2;          // staging row 0..63
  const int sc = (tid & 3) * 8;     // staging col (elements)
  const u16* ga = A + (size_t)(m0 + sr) * DMODEL + sc;
  const u16* gb = W + (size_t)(n0 + sr) * DMODEL + sc;
  u16* la = Ab + sr*32 + sc;
  u16* lb = Bb + sr*32 + sc;

  for (int k0 = 0; k0 < DMODEL; k0 += 32) {
    __syncthreads();
    async16(ga + k0,             la);
    async16(ga + k0 + 64*DMODEL, la + 64*32);
    async16(gb + k0,             lb);
    async16(gb + k0 + 64*DMODEL, lb + 64*32);
    __syncthreads();
    bf16x8 afr[4], bfr[4];
#pragma unroll
    for (int i=0;i<4;i++) afr[i] = *(const bf16x8*)(Ab + (wr*64 + i*16 + c0)*32 + g*8);
#pragma unroll
    for (int j=0;j<4;j++) bfr[j] = *(const bf16x8*)(Bb + (wc*64 + j*16 + c0)*32 + g*8);
    __builtin_amdgcn_s_setprio(1);
#pragma unroll
    for (int i=0;i<4;i++)
#pragma unroll
      for (int j=0;j<4;j++)
        acc[i][j] = __builtin_amdgcn_mfma_f32_16x16x32_bf16(afr[i], bfr[j], acc[i][j], 0,0,0);
    __builtin_amdgcn_s_setprio(0);
  }

  const int nbase = n0 + wc*64;
  const int t = n0 >> 10;                 // 0=q 1=k 2=v (tiles never cross)
  const float* bias = (MODE==1) ? b0 : (t==0) ? b0 : (t==1) ? b1 : b2;
  float bv4[4];
#pragma unroll
  for (int j=0;j<4;j++) bv4[j] = bias[(nbase & 1023) + j*16 + c0];

  if (MODE == 0) {
    u16* dst = (t==0) ? dq : (t==1) ? dk : dv;
    const float qs = (t==0) ? 0.18033688011f : 1.0f;   // 0.125*log2(e)
    const int h = (nbase >> 6) & (NHEAD-1);
#pragma unroll
    for (int i=0;i<4;i++){
      const int mbase = m0 + wr*64 + i*16 + g*4;
#pragma unroll
      for (int r=0;r<4;r++){
        const int mm = mbase + r;
        const int bb = mm >> 11, s = mm & (SEQ-1);
        const size_t rowbase = (((size_t)(bb*NHEAD + h))*SEQ + s)*DH;
        if (t < 2) {
#pragma unroll
          for (int j2=0;j2<2;j2++){
            const int dh = j2*16 + c0;
            const float xl = acc[i][j2][r]   + bv4[j2];
            const float xh = acc[i][j2+2][r] + bv4[j2+2];
            const float2 cs = *(const float2*)(tab + (size_t)s*64 + dh*2);
            dst[rowbase + dh]      = cvt1((xl*cs.x - xh*cs.y)*qs);
            dst[rowbase + dh + 32] = cvt1((xh*cs.x + xl*cs.y)*qs);
          }
        } else {
#pragma unroll
          for (int j=0;j<4;j++)
            dst[rowbase + j*16 + c0] = cvt1(acc[i][j][r] + bv4[j]);
        }
      }
    }
  } else {
#pragma unroll
    for (int i=0;i<4;i++){
      const int mbase = m0 + wr*64 + i*16 + g*4;
#pragma unroll
      for (int j=0;j<4;j++){
#pragma unroll
        for (int r=0;r<4;r++)
          fout[(size_t)(mbase + r) * DMODEL + nbase + j*16 + c0] = acc[i][j][r] + bv4[j];
      }
    }
  }
}

// ---------------- Flash attention: 4 waves x 32q (QB=128), 32x32x16 ---------
// grid (64, 8): x = bh (XCD: id%8 = bh%8), y = pair; qt = pair / 15-pair
// -> uniform 34 iters/block; 512 blocks = 2 independent blocks/CU so barrier
// stalls of one block hide under the other block's compute.
__global__ __launch_bounds__(256, 2)
void attn_fwd(const u16* __restrict__ Q, const u16* __restrict__ K,
              const u16* __restrict__ V, u16* __restrict__ O)
{
  __shared__ u16 Kb[2][64*64];  // [kv][dh], swizzled (pre-swizzled source)
  __shared__ u16 Vt[2][64*64];  // [dh][pos], swizzled; pos = sigma^-1(kv)
  const int bh = blockIdx.x;
  const int pair = blockIdx.y;              // 0..7
  const int tid = threadIdx.x, lane = tid & 63, w = tid >> 6;  // w in [0,4)
  const int c31 = lane & 31, hi = lane >> 5;
  const size_t hb = (size_t)bh * SEQ * DH;
  const int b = bh >> 4, h = bh & 15;

  // K staging: two async16 per thread (256 x 2 x 16B = 8KB tile)
  const int boff1 = tid*16;
  const int ksw1  = boff1 ^ swz(boff1 >> 7);
  const int boff2 = boff1 + 4096;
  const int ksw2  = boff2 ^ swz(boff2 >> 7);
  // V staging: kv pair (2rp,2rp+1), dh 8-chunk dc
  const int rp = tid >> 3, dc = tid & 7;
  const int kv0 = 2*rp;
  const int vpos = (kv0 & 0x33) | ((kv0 & 4) << 1) | ((kv0 & 8) >> 1);
  union U4 { ushort4 v; u16 e[4]; };

#pragma unroll 1
  for (int half = 0; half < 2; half++){
    const int qt = half ? (15 - pair) : pair;
    const int qrow_base = qt*128 + w*32;
    const int jt_last  = 2*qt + 1;
    const int jt_end_w = 2*qt + (w>>1);     // this wave's diagonal tile
    const int q = qrow_base + c31;          // this lane's q-row

    bf16x8 qf[4];
#pragma unroll
    for (int kc=0;kc<4;kc++)
      qf[kc] = *(const bf16x8*)(Q + hb + (size_t)q*DH + kc*16 + hi*8);

    f32x16 oacc0 = {}, oacc1 = {};          // O^T[dh][q]
    float mrun = -3.0e38f, lrun = 0.f;

    // ---- prologue: stage tile 0 into buffer 0 ----
    {
      const char* gk = (const char*)(K + hb);
      async16(gk + ksw1, (char*)Kb[0] + boff1);
      async16(gk + ksw2, (char*)Kb[0] + boff2);
      const u16* gv = V + hb;
      U4 v0a, v0b, v1a, v1b;
      v0a.v = *(const ushort4*)(gv + (kv0  )*DH + dc*8);
      v0b.v = *(const ushort4*)(gv + (kv0  )*DH + dc*8 + 4);
      v1a.v = *(const ushort4*)(gv + (kv0+1)*DH + dc*8);
      v1b.v = *(const ushort4*)(gv + (kv0+1)*DH + dc*8 + 4);
#pragma unroll
      for (int e=0;e<8;e++){
        const int row = dc*8 + e;
        const u16 a   = (e<4) ? v0a.e[e] : v0b.e[e-4];
        const u16 bb2 = (e<4) ? v1a.e[e] : v1b.e[e-4];
        *(uint32_t*)((char*)Vt[0] + ((row*128 + vpos*2) ^ swz(row))) =
          (uint32_t)a | ((uint32_t)bb2 << 16);
      }
    }
    __syncthreads();

    U4 v0a, v0b, v1a, v1b;   // prefetch regs
    for (int jt = 0; jt <= jt_last; jt++){
      const int cur = jt & 1, nxt = cur ^ 1;
      const bool pre = (jt < jt_last);
      if (pre){
        const char* gk = (const char*)(K + hb + (size_t)(jt+1)*64*DH);
        async16(gk + ksw1, (char*)Kb[nxt] + boff1);
        async16(gk + ksw2, (char*)Kb[nxt] + boff2);
        const u16* gv = V + hb + (size_t)(jt+1)*64*DH;
        v0a.v = *(const ushort4*)(gv + (kv0  )*DH + dc*8);
        v0b.v = *(const ushort4*)(gv + (kv0  )*DH + dc*8 + 4);
        v1a.v = *(const ushort4*)(gv + (kv0+1)*DH + dc*8);
        v1b.v = *(const ushort4*)(gv + (kv0+1)*DH + dc*8 + 4);
      }

      if (jt <= jt_end_w){
        // ---- S^T = K Q'^T : sT[kvb][r] = S[kv][q], kv=(r&3)+8(r>>2)+4hi ----
        f32x16 sT[2] = {};
#pragma unroll
        for (int kc=0;kc<4;kc++){
          const int col = (kc*16 + hi*8)*2;
          const int r0 = c31, r1 = 32 + c31;
          const bf16x8 kf0 = *(const bf16x8*)((const char*)Kb[cur] + ((r0*128 + col) ^ swz(r0)));
          const bf16x8 kf1 = *(const bf16x8*)((const char*)Kb[cur] + ((r1*128 + col) ^ swz(r1)));
          __builtin_amdgcn_s_setprio(1);
          sT[0] = __builtin_amdgcn_mfma_f32_32x32x16_bf16(kf0, qf[kc], sT[0], 0,0,0);
          sT[1] = __builtin_amdgcn_mfma_f32_32x32x16_bf16(kf1, qf[kc], sT[1], 0,0,0);
          __builtin_amdgcn_s_setprio(0);
        }
        // ---- causal mask: only this wave's diagonal tile ----
        if (jt == jt_end_w){
#pragma unroll
          for (int kvb=0;kvb<2;kvb++)
#pragma unroll
            for (int r=0;r<16;r++){
              const int kv = jt*64 + kvb*32 + (r&3) + 8*(r>>2) + 4*hi;
              sT[kvb][r] = (kv <= q) ? sT[kvb][r] : -3.0e38f;
            }
        }
        // ---- online softmax (per-lane q-col; exp2 domain; defer-max) ----
        float mx = -3.0e38f;
#pragma unroll
        for (int kvb=0;kvb<2;kvb++)
#pragma unroll
          for (int r=0;r<16;r++) mx = fmaxf(mx, sT[kvb][r]);
        mx = fmaxf(mx, __shfl_xor(mx, 32));
        const bool grow = __any(mx > mrun + 8.0f);
        float corr = 1.0f;
        if (grow){
          const float mnew = fmaxf(mrun, mx);
          corr = exp2f(mrun - mnew);
          mrun = mnew;
        }
        float lsum = 0.f;
#pragma unroll
        for (int kvb=0;kvb<2;kvb++)
#pragma unroll
          for (int r=0;r<16;r++){
            const float p = exp2f(sT[kvb][r] - mrun);
            sT[kvb][r] = p;
            lsum += p;
          }
        lsum += __shfl_xor(lsum, 32);
        lrun = lrun*corr + lsum;
        if (grow){
#pragma unroll
          for (int r=0;r<16;r++){ oacc0[r] *= corr; oacc1[r] *= corr; }
        }
        // ---- O^T += V^T P^T (P in-register; V sigma-permuted in LDS) ----
#pragma unroll
        for (int kvb=0;kvb<2;kvb++)
#pragma unroll
          for (int s=0;s<2;s++){
            union { bf16x8 v; uint32_t d[4]; } pa;
#pragma unroll
            for (int j=0;j<4;j++)
              pa.d[j] = cvt2(sT[kvb][s*8+2*j], sT[kvb][s*8+2*j+1]);
            const int col = (kvb*32 + s*16 + hi*8)*2;
            const int r0 = c31, r1 = 32 + c31;
            const bf16x8 vf0 = *(const bf16x8*)((const char*)Vt[cur] + ((r0*128 + col) ^ swz(r0)));
            const bf16x8 vf1 = *(const bf16x8*)((const char*)Vt[cur] + ((r1*128 + col) ^ swz(r1)));
            __builtin_amdgcn_s_setprio(1);
            oacc0 = __builtin_amdgcn_mfma_f32_32x32x16_bf16(vf0, pa.v, oacc0, 0,0,0);
            oacc1 = __builtin_amdgcn_mfma_f32_32x32x16_bf16(vf1, pa.v, oacc1, 0,0,0);
            __builtin_amdgcn_s_setprio(0);
          }
      }

      if (pre){
#pragma unroll
        for (int e=0;e<8;e++){
          const int row = dc*8 + e;
          const u16 a   = (e<4) ? v0a.e[e] : v0b.e[e-4];
          const u16 bb2 = (e<4) ? v1a.e[e] : v1b.e[e-4];
          *(uint32_t*)((char*)Vt[nxt] + ((row*128 + vpos*2) ^ swz(row))) =
            (uint32_t)a | ((uint32_t)bb2 << 16);
        }
      }
      __syncthreads();
    }

    // ---- write attn output (per-lane q-col): O[b, q, h*64 + dh] ----
    {
      const float inv = 1.0f / lrun;
      u16* orow = O + ((size_t)b*SEQ + q)*DMODEL + h*DH;
#pragma unroll
      for (int r2=0;r2<8;r2++){
        const int dh0 = 2*(r2&1) + 8*(r2>>1) + 4*hi;
        *(uint32_t*)(orow + dh0)      = cvt2(oacc0[2*r2]*inv, oacc0[2*r2+1]*inv);
        *(uint32_t*)(orow + 32 + dh0) = cvt2(oacc1[2*r2]*inv, oacc1[2*r2+1]*inv);
      }
    }
  }
}

// ---------------------------------------------------------------------------
extern "C" void kernel_launch(void* const* d_in, const int* in_sizes, int n_in,
                              void* d_out, int out_size, void* d_ws, size_t ws_size,
                              hipStream_t stream)
{
  const float* x  = (const float*)d_in[0];
  const float* Wq = (const float*)d_in[1];
  const float* bq = (const float*)d_in[2];
  const float* Wk = (const float*)d_in[3];
  const float* bk = (const float*)d_in[4];
  const float* Wv = (const float*)d_in[5];
  const float* bv = (const float*)d_in[6];
  const float* Wo = (const float*)d_in[7];
  const float* bo = (const float*)d_in[8];
  // d_in[9]: causal mask (int32) — implemented analytically, not read.

  const size_t MB = 1024*1024;
  char* ws = (char*)d_ws;
  u16*  xb   = (u16*)(ws);                 // [0,16MB)  x bf16; dead after QKV
  u16*  aw   = (u16*)(ws);                 // attn out reuses region
  u16*  vw   = (u16*)(ws + 16*MB);         // [16,32MB) V [B,H,S,Dh]
  u16*  wqkv = (u16*)(ws + 32*MB);         // [32,38MB) Wq|Wk|Wv bf16 [3072][1024]
  u16*  wob  = (u16*)(ws + 38*MB);         // [38,40MB)
  float* tab = (float*)(ws + 41*MB);       // 512KB
  // d_out (32MB f32) doubles as scratch for q/k (bf16, dead before final GEMM)
  u16*  qw = (u16*)d_out;
  u16*  kw = (u16*)d_out + 8*MB;

  prep<<<dim3(6400), dim3(256), 0, stream>>>(x, Wq, Wk, Wv, Wo, xb, wqkv, wob, tab);

  // fused QKV projection + RoPE epilogue: N=3072
  gemm_bt<0><<<dim3(24, 64), dim3(256), 0, stream>>>(xb, wqkv, bq, bk, bv,
                                                     nullptr, qw, kw, vw, tab);

  attn_fwd<<<dim3(64, 8), dim3(256), 0, stream>>>(qw, kw, vw, aw);

  gemm_bt<1><<<dim3(8, 64), dim3(256), 0, stream>>>(aw, wob, bo, nullptr, nullptr,
                                                    (float*)d_out, nullptr, nullptr, nullptr, nullptr);
}

// Round 9
// 175.997 us; speedup vs baseline: 2.2229x; 1.0928x over previous
//
#include <hip/hip_runtime.h>
#include <stdint.h>

typedef unsigned short u16;
typedef __bf16 bf16x8 __attribute__((ext_vector_type(8)));
typedef __bf16 bf16x2 __attribute__((ext_vector_type(2)));
typedef float f32x4 __attribute__((ext_vector_type(4)));
typedef float f32x16 __attribute__((ext_vector_type(16)));

#define SEQ    2048
#define NHEAD  16
#define DH     64
#define DMODEL 1024
#define NBH    64     // B*H

// native bf16 converts (compiler emits v_cvt_pk_bf16_f32 for pairs)
__device__ __forceinline__ u16 cvt1(float f){
  union { __bf16 h; u16 u; } c; c.h = (__bf16)f; return c.u;
}
__device__ __forceinline__ uint32_t cvt2(float a, float b){
  union { bf16x2 v; uint32_t u; } c; c.v = bf16x2{(__bf16)a, (__bf16)b}; return c.u;
}
// LDS XOR-swizzle: bits 4-6 (keeps 16B alignment for b128 reads)
__device__ __forceinline__ int swz(int row){ return (((row&7)^((row>>3)&7))<<4); }

#if __has_builtin(__builtin_amdgcn_exp2f)
__device__ __forceinline__ float EXP2(float x){ return __builtin_amdgcn_exp2f(x); }
#else
__device__ __forceinline__ float EXP2(float x){ return exp2f(x); }
#endif
__device__ __forceinline__ float max3f(float a, float b, float c){
  float r; asm("v_max3_f32 %0, %1, %2, %3" : "=v"(r) : "v"(a), "v"(b), "v"(c));
  return r;
}

typedef const __attribute__((address_space(1))) uint32_t* gas_t;
typedef __attribute__((address_space(3))) uint32_t* las_t;
__device__ __forceinline__ void async16(const void* g, void* l){
  __builtin_amdgcn_global_load_lds((gas_t)g, (las_t)l, 16, 0, 0);
}

// pack V rows (kv0, kv0+1) into sigma-permuted transposed LDS tile via v_perm
__device__ __forceinline__ void vstore8(char* dst, uint2 a0, uint2 a1,
                                        uint2 b0, uint2 b1, int dc, int vpos){
  uint32_t pk[8];
  pk[0] = __builtin_amdgcn_perm(b0.x, a0.x, 0x05040100u);
  pk[1] = __builtin_amdgcn_perm(b0.x, a0.x, 0x07060302u);
  pk[2] = __builtin_amdgcn_perm(b0.y, a0.y, 0x05040100u);
  pk[3] = __builtin_amdgcn_perm(b0.y, a0.y, 0x07060302u);
  pk[4] = __builtin_amdgcn_perm(b1.x, a1.x, 0x05040100u);
  pk[5] = __builtin_amdgcn_perm(b1.x, a1.x, 0x07060302u);
  pk[6] = __builtin_amdgcn_perm(b1.y, a1.y, 0x05040100u);
  pk[7] = __builtin_amdgcn_perm(b1.y, a1.y, 0x07060302u);
#pragma unroll
  for (int e=0;e<8;e++){
    const int row = dc*8 + e;
    *(uint32_t*)(dst + ((row*128 + vpos*2) ^ swz(row))) = pk[e];
  }
}

// ---------------- fused prep: 5x f32->bf16 convert + RoPE table -------------
__global__ void prep(const float* __restrict__ x,  const float* __restrict__ Wq,
                     const float* __restrict__ Wk, const float* __restrict__ Wv,
                     const float* __restrict__ Wo,
                     u16* __restrict__ xb, u16* __restrict__ wqkv,
                     u16* __restrict__ wob, float* __restrict__ tab)
{
  const int bid = blockIdx.x, tid = threadIdx.x;
  if (bid < 6144){
    const float* src; u16* dst; int lb;
    if      (bid < 4096){ src = x;  dst = xb;              lb = bid; }
    else if (bid < 4608){ src = Wq; dst = wqkv;            lb = bid-4096; }
    else if (bid < 5120){ src = Wk; dst = wqkv + 1048576;  lb = bid-4608; }
    else if (bid < 5632){ src = Wv; dst = wqkv + 2097152;  lb = bid-5120; }
    else                { src = Wo; dst = wob;             lb = bid-5632; }
    const size_t off = (size_t)lb*2048 + tid*8;
    float4 a = *(const float4*)(src+off);
    float4 b = *(const float4*)(src+off+4);
    bf16x8 o = { (__bf16)a.x,(__bf16)a.y,(__bf16)a.z,(__bf16)a.w,
                 (__bf16)b.x,(__bf16)b.y,(__bf16)b.z,(__bf16)b.w };
    *(bf16x8*)(dst+off) = o;
  } else {
    const int t = (bid-6144)*256 + tid;          // < 65536
    const int s = t >> 5, j = t & 31;
    double freq = exp(-(double)(2*j)/64.0*log(10000.0));
    double ang = (double)s*freq;
    tab[s*64 + 2*j]     = (float)cos(ang);
    tab[s*64 + 2*j + 1] = (float)sin(ang);
  }
}

// ---------------- GEMM: dst = A @ W^T + bias  (bf16 in, NT layout) ----------
// 2-phase double-buffered: stage(next) overlaps ds_read+MFMA(cur); 1 barrier.
template<int MODE>
__global__ __launch_bounds__(256, 2)
void gemm_bt(const u16* __restrict__ A, const u16* __restrict__ W,
             const float* __restrict__ b0, const float* __restrict__ b1,
             const float* __restrict__ b2, float* __restrict__ fout,
             u16* __restrict__ dq, u16* __restrict__ dk, u16* __restrict__ dv,
             const float* __restrict__ tab)
{
  __shared__ u16 Ab[2][128*32];
  __shared__ u16 Bb[2][128*32];
  const int tid = threadIdx.x;
  const int lane = tid & 63;
  const int w = tid >> 6, wr = w >> 1, wc = w & 1;
  const int m0 = blockIdx.y * 128;
  const int n0 = blockIdx.x * 128;
  const int c0 = lane & 15, g = lane >> 4;

  f32x4 acc[4][4] = {};

  const int sr = tid >> 2;          // staging row 0..63
  const int sc = (tid & 3) * 8;     // staging col (elements)
  const int stoff = sr*32 + sc;
  const u16* ga = A + (size_t)(m0 + sr) * DMODEL + sc;
  const u16* gb = W + (size_t)(n0 + sr) * DMODEL + sc;

#define STAGE_G(buf, kk) do{ \
    async16(ga + (kk),             Ab[buf] + stoff); \
    async16(ga + (kk) + 64*DMODEL, Ab[buf] + stoff + 64*32); \
    async16(gb + (kk),             Bb[buf] + stoff); \
    async16(gb + (kk) + 64*DMODEL, Bb[buf] + stoff + 64*32); \
  }while(0)

  STAGE_G(0, 0);
  __syncthreads();

#pragma unroll 2
  for (int k0 = 0; k0 < DMODEL; k0 += 32) {
    const int cur = (k0 >> 5) & 1;
    if (k0 + 32 < DMODEL) STAGE_G(cur^1, k0 + 32);
    bf16x8 afr[4], bfr[4];
#pragma unroll
    for (int i=0;i<4;i++) afr[i] = *(const bf16x8*)(Ab[cur] + (wr*64 + i*16 + c0)*32 + g*8);
#pragma unroll
    for (int j=0;j<4;j++) bfr[j] = *(const bf16x8*)(Bb[cur] + (wc*64 + j*16 + c0)*32 + g*8);
    __builtin_amdgcn_s_setprio(1);
#pragma unroll
    for (int i=0;i<4;i++)
#pragma unroll
      for (int j=0;j<4;j++)
        acc[i][j] = __builtin_amdgcn_mfma_f32_16x16x32_bf16(afr[i], bfr[j], acc[i][j], 0,0,0);
    __builtin_amdgcn_s_setprio(0);
    __syncthreads();
  }
#undef STAGE_G

  const int nbase = n0 + wc*64;
  const int t = n0 >> 10;                 // 0=q 1=k 2=v (tiles never cross)
  const float* bias = (MODE==1) ? b0 : (t==0) ? b0 : (t==1) ? b1 : b2;
  float bv4[4];
#pragma unroll
  for (int j=0;j<4;j++) bv4[j] = bias[(nbase & 1023) + j*16 + c0];

  if (MODE == 0) {
    u16* dst = (t==0) ? dq : (t==1) ? dk : dv;
    const float qs = (t==0) ? 0.18033688011f : 1.0f;   // 0.125*log2(e)
    const int h = (nbase >> 6) & (NHEAD-1);
#pragma unroll
    for (int i=0;i<4;i++){
      const int mbase = m0 + wr*64 + i*16 + g*4;
#pragma unroll
      for (int r=0;r<4;r++){
        const int mm = mbase + r;
        const int bb = mm >> 11, s = mm & (SEQ-1);
        const size_t rowbase = (((size_t)(bb*NHEAD + h))*SEQ + s)*DH;
        if (t < 2) {
#pragma unroll
          for (int j2=0;j2<2;j2++){
            const int dh = j2*16 + c0;
            const float xl = acc[i][j2][r]   + bv4[j2];
            const float xh = acc[i][j2+2][r] + bv4[j2+2];
            const float2 cs = *(const float2*)(tab + (size_t)s*64 + dh*2);
            dst[rowbase + dh]      = cvt1((xl*cs.x - xh*cs.y)*qs);
            dst[rowbase + dh + 32] = cvt1((xh*cs.x + xl*cs.y)*qs);
          }
        } else {
#pragma unroll
          for (int j=0;j<4;j++)
            dst[rowbase + j*16 + c0] = cvt1(acc[i][j][r] + bv4[j]);
        }
      }
    }
  } else {
#pragma unroll
    for (int i=0;i<4;i++){
      const int mbase = m0 + wr*64 + i*16 + g*4;
#pragma unroll
      for (int j=0;j<4;j++){
#pragma unroll
        for (int r=0;r<4;r++)
          fout[(size_t)(mbase + r) * DMODEL + nbase + j*16 + c0] = acc[i][j][r] + bv4[j];
      }
    }
  }
}

// ---------------- Flash attention: 4 waves x 32q (QB=128), 32x32x16 ---------
// grid (64, 8): x = bh (XCD: id%8 = bh%8), y = pair; qt = pair / 15-pair
__global__ __launch_bounds__(256, 2)
void attn_fwd(const u16* __restrict__ Q, const u16* __restrict__ K,
              const u16* __restrict__ V, u16* __restrict__ O)
{
  __shared__ u16 Kb[2][64*64];  // [kv][dh], swizzled (pre-swizzled source)
  __shared__ u16 Vt[2][64*64];  // [dh][pos], swizzled; pos = sigma^-1(kv)
  const int bh = blockIdx.x;
  const int pair = blockIdx.y;              // 0..7
  const int tid = threadIdx.x, lane = tid & 63, w = tid >> 6;  // w in [0,4)
  const int c31 = lane & 31, hi = lane >> 5;
  const size_t hb = (size_t)bh * SEQ * DH;
  const int b = bh >> 4, h = bh & 15;

  // K staging: two async16 per thread (256 x 2 x 16B = 8KB tile)
  const int boff1 = tid*16;
  const int ksw1  = boff1 ^ swz(boff1 >> 7);
  const int boff2 = boff1 + 4096;
  const int ksw2  = boff2 ^ swz(boff2 >> 7);
  // V staging: kv pair (2rp,2rp+1), dh 8-chunk dc
  const int rp = tid >> 3, dc = tid & 7;
  const int kv0 = 2*rp;
  const int vpos = (kv0 & 0x33) | ((kv0 & 4) << 1) | ((kv0 & 8) >> 1);

#pragma unroll 1
  for (int half = 0; half < 2; half++){
    const int qt = half ? (15 - pair) : pair;
    const int qrow_base = qt*128 + w*32;
    const int jt_last  = 2*qt + 1;
    const int jt_end_w = 2*qt + (w>>1);     // this wave's diagonal tile
    const int q = qrow_base + c31;          // this lane's q-row

    bf16x8 qf[4];
#pragma unroll
    for (int kc=0;kc<4;kc++)
      qf[kc] = *(const bf16x8*)(Q + hb + (size_t)q*DH + kc*16 + hi*8);

    f32x16 oacc0 = {}, oacc1 = {};          // O^T[dh][q]
    float mrun = -3.0e38f, lrun = 0.f;

    // ---- prologue: stage tile 0 into buffer 0 ----
    {
      const char* gk = (const char*)(K + hb);
      async16(gk + ksw1, (char*)Kb[0] + boff1);
      async16(gk + ksw2, (char*)Kb[0] + boff2);
      const u16* gv = V + hb;
      uint2 a0 = *(const uint2*)(gv + (kv0  )*DH + dc*8);
      uint2 a1 = *(const uint2*)(gv + (kv0  )*DH + dc*8 + 4);
      uint2 b0 = *(const uint2*)(gv + (kv0+1)*DH + dc*8);
      uint2 b1 = *(const uint2*)(gv + (kv0+1)*DH + dc*8 + 4);
      vstore8((char*)Vt[0], a0, a1, b0, b1, dc, vpos);
    }
    __syncthreads();

    uint2 pa0, pa1, pb0, pb1;   // V prefetch regs
    for (int jt = 0; jt <= jt_last; jt++){
      const int cur = jt & 1, nxt = cur ^ 1;
      const bool pre = (jt < jt_last);
      if (pre){
        const char* gk = (const char*)(K + hb + (size_t)(jt+1)*64*DH);
        async16(gk + ksw1, (char*)Kb[nxt] + boff1);
        async16(gk + ksw2, (char*)Kb[nxt] + boff2);
        const u16* gv = V + hb + (size_t)(jt+1)*64*DH;
        pa0 = *(const uint2*)(gv + (kv0  )*DH + dc*8);
        pa1 = *(const uint2*)(gv + (kv0  )*DH + dc*8 + 4);
        pb0 = *(const uint2*)(gv + (kv0+1)*DH + dc*8);
        pb1 = *(const uint2*)(gv + (kv0+1)*DH + dc*8 + 4);
      }

      if (jt <= jt_end_w){
        // ---- S^T = K Q'^T : sT[kvb][r] = S[kv][q], kv=(r&3)+8(r>>2)+4hi ----
        f32x16 sT[2] = {};
#pragma unroll
        for (int kc=0;kc<4;kc++){
          const int col = (kc*16 + hi*8)*2;
          const int r0 = c31, r1 = 32 + c31;
          const bf16x8 kf0 = *(const bf16x8*)((const char*)Kb[cur] + ((r0*128 + col) ^ swz(r0)));
          const bf16x8 kf1 = *(const bf16x8*)((const char*)Kb[cur] + ((r1*128 + col) ^ swz(r1)));
          __builtin_amdgcn_s_setprio(1);
          sT[0] = __builtin_amdgcn_mfma_f32_32x32x16_bf16(kf0, qf[kc], sT[0], 0,0,0);
          sT[1] = __builtin_amdgcn_mfma_f32_32x32x16_bf16(kf1, qf[kc], sT[1], 0,0,0);
          __builtin_amdgcn_s_setprio(0);
        }
        // ---- causal mask: only this wave's diagonal tile ----
        if (jt == jt_end_w){
#pragma unroll
          for (int kvb=0;kvb<2;kvb++)
#pragma unroll
            for (int r=0;r<16;r++){
              const int kv = jt*64 + kvb*32 + (r&3) + 8*(r>>2) + 4*hi;
              sT[kvb][r] = (kv <= q) ? sT[kvb][r] : -3.0e38f;
            }
        }
        // ---- online softmax (exp2 domain; defer-max; parallel chains) ----
        float mx0 = -3.0e38f, mx1 = -3.0e38f;
#pragma unroll
        for (int r=0;r<16;r+=2){
          mx0 = max3f(mx0, sT[0][r], sT[0][r+1]);
          mx1 = max3f(mx1, sT[1][r], sT[1][r+1]);
        }
        float mx = fmaxf(mx0, mx1);
        mx = fmaxf(mx, __shfl_xor(mx, 32));
        const bool grow = __any(mx > mrun + 8.0f);
        float corr = 1.0f;
        if (grow){
          const float mnew = fmaxf(mrun, mx);
          corr = EXP2(mrun - mnew);
          mrun = mnew;
        }
        float ls[4] = {0.f, 0.f, 0.f, 0.f};
#pragma unroll
        for (int kvb=0;kvb<2;kvb++)
#pragma unroll
          for (int r=0;r<16;r++){
            const float p = EXP2(sT[kvb][r] - mrun);
            sT[kvb][r] = p;
            ls[r & 3] += p;
          }
        float lsum = (ls[0] + ls[1]) + (ls[2] + ls[3]);
        lsum += __shfl_xor(lsum, 32);
        lrun = lrun*corr + lsum;
        if (grow){
#pragma unroll
          for (int r=0;r<16;r++){ oacc0[r] *= corr; oacc1[r] *= corr; }
        }
        // ---- O^T += V^T P^T (P in-register; V sigma-permuted in LDS) ----
#pragma unroll
        for (int kvb=0;kvb<2;kvb++)
#pragma unroll
          for (int s=0;s<2;s++){
            union { bf16x8 v; uint32_t d[4]; } pa;
#pragma unroll
            for (int j=0;j<4;j++)
              pa.d[j] = cvt2(sT[kvb][s*8+2*j], sT[kvb][s*8+2*j+1]);
            const int col = (kvb*32 + s*16 + hi*8)*2;
            const int r0 = c31, r1 = 32 + c31;
            const bf16x8 vf0 = *(const bf16x8*)((const char*)Vt[cur] + ((r0*128 + col) ^ swz(r0)));
            const bf16x8 vf1 = *(const bf16x8*)((const char*)Vt[cur] + ((r1*128 + col) ^ swz(r1)));
            __builtin_amdgcn_s_setprio(1);
            oacc0 = __builtin_amdgcn_mfma_f32_32x32x16_bf16(vf0, pa.v, oacc0, 0,0,0);
            oacc1 = __builtin_amdgcn_mfma_f32_32x32x16_bf16(vf1, pa.v, oacc1, 0,0,0);
            __builtin_amdgcn_s_setprio(0);
          }
      }

      if (pre) vstore8((char*)Vt[nxt], pa0, pa1, pb0, pb1, dc, vpos);
      __syncthreads();
    }

    // ---- write attn output (per-lane q-col): O[b, q, h*64 + dh] ----
    {
      const float inv = 1.0f / lrun;
      u16* orow = O + ((size_t)b*SEQ + q)*DMODEL + h*DH;
#pragma unroll
      for (int r2=0;r2<8;r2++){
        const int dh0 = 2*(r2&1) + 8*(r2>>1) + 4*hi;
        *(uint32_t*)(orow + dh0)      = cvt2(oacc0[2*r2]*inv, oacc0[2*r2+1]*inv);
        *(uint32_t*)(orow + 32 + dh0) = cvt2(oacc1[2*r2]*inv, oacc1[2*r2+1]*inv);
      }
    }
  }
}

// ---------------------------------------------------------------------------
extern "C" void kernel_launch(void* const* d_in, const int* in_sizes, int n_in,
                              void* d_out, int out_size, void* d_ws, size_t ws_size,
                              hipStream_t stream)
{
  const float* x  = (const float*)d_in[0];
  const float* Wq = (const float*)d_in[1];
  const float* bq = (const float*)d_in[2];
  const float* Wk = (const float*)d_in[3];
  const float* bk = (const float*)d_in[4];
  const float* Wv = (const float*)d_in[5];
  const float* bv = (const float*)d_in[6];
  const float* Wo = (const float*)d_in[7];
  const float* bo = (const float*)d_in[8];
  // d_in[9]: causal mask (int32) — implemented analytically, not read.

  const size_t MB = 1024*1024;
  char* ws = (char*)d_ws;
  u16*  xb   = (u16*)(ws);                 // [0,16MB)  x bf16; dead after QKV
  u16*  aw   = (u16*)(ws);                 // attn out reuses region
  u16*  vw   = (u16*)(ws + 16*MB);         // [16,32MB) V [B,H,S,Dh]
  u16*  wqkv = (u16*)(ws + 32*MB);         // [32,38MB) Wq|Wk|Wv bf16 [3072][1024]
  u16*  wob  = (u16*)(ws + 38*MB);         // [38,40MB)
  float* tab = (float*)(ws + 41*MB);       // 512KB
  // d_out (32MB f32) doubles as scratch for q/k (bf16, dead before final GEMM)
  u16*  qw = (u16*)d_out;
  u16*  kw = (u16*)d_out + 8*MB;

  prep<<<dim3(6400), dim3(256), 0, stream>>>(x, Wq, Wk, Wv, Wo, xb, wqkv, wob, tab);

  // fused QKV projection + RoPE epilogue: N=3072
  gemm_bt<0><<<dim3(24, 64), dim3(256), 0, stream>>>(xb, wqkv, bq, bk, bv,
                                                     nullptr, qw, kw, vw, tab);

  attn_fwd<<<dim3(64, 8), dim3(256), 0, stream>>>(qw, kw, vw, aw);

  gemm_bt<1><<<dim3(8, 64), dim3(256), 0, stream>>>(aw, wob, bo, nullptr, nullptr,
                                                    (float*)d_out, nullptr, nullptr, nullptr, nullptr);
}

// Round 10
// 175.042 us; speedup vs baseline: 2.2350x; 1.0055x over previous
//
#include <hip/hip_runtime.h>
#include <stdint.h>

typedef unsigned short u16;
typedef __bf16 bf16x8 __attribute__((ext_vector_type(8)));
typedef __bf16 bf16x2 __attribute__((ext_vector_type(2)));
typedef float f32x4 __attribute__((ext_vector_type(4)));
typedef float f32x16 __attribute__((ext_vector_type(16)));

#define SEQ    2048
#define NHEAD  16
#define DH     64
#define DMODEL 1024
#define NBH    64     // B*H

// native bf16 converts (compiler emits v_cvt_pk_bf16_f32 for pairs)
__device__ __forceinline__ u16 cvt1(float f){
  union { __bf16 h; u16 u; } c; c.h = (__bf16)f; return c.u;
}
__device__ __forceinline__ uint32_t cvt2(float a, float b){
  union { bf16x2 v; uint32_t u; } c; c.v = bf16x2{(__bf16)a, (__bf16)b}; return c.u;
}
// LDS XOR-swizzle: bits 4-6 (keeps 16B alignment for b128 reads)
__device__ __forceinline__ int swz(int row){ return (((row&7)^((row>>3)&7))<<4); }

#if __has_builtin(__builtin_amdgcn_exp2f)
__device__ __forceinline__ float EXP2(float x){ return __builtin_amdgcn_exp2f(x); }
#else
__device__ __forceinline__ float EXP2(float x){ return exp2f(x); }
#endif
__device__ __forceinline__ float max3f(float a, float b, float c){
  float r; asm("v_max3_f32 %0, %1, %2, %3" : "=v"(r) : "v"(a), "v"(b), "v"(c));
  return r;
}

typedef const __attribute__((address_space(1))) uint32_t* gas_t;
typedef __attribute__((address_space(3))) uint32_t* las_t;
__device__ __forceinline__ void async16(const void* g, void* l){
  __builtin_amdgcn_global_load_lds((gas_t)g, (las_t)l, 16, 0, 0);
}

// pack V rows (kv0, kv0+1) into sigma-permuted transposed LDS tile via v_perm
__device__ __forceinline__ void vstore8(char* dst, uint2 a0, uint2 a1,
                                        uint2 b0, uint2 b1, int dc, int vpos){
  uint32_t pk[8];
  pk[0] = __builtin_amdgcn_perm(b0.x, a0.x, 0x05040100u);
  pk[1] = __builtin_amdgcn_perm(b0.x, a0.x, 0x07060302u);
  pk[2] = __builtin_amdgcn_perm(b0.y, a0.y, 0x05040100u);
  pk[3] = __builtin_amdgcn_perm(b0.y, a0.y, 0x07060302u);
  pk[4] = __builtin_amdgcn_perm(b1.x, a1.x, 0x05040100u);
  pk[5] = __builtin_amdgcn_perm(b1.x, a1.x, 0x07060302u);
  pk[6] = __builtin_amdgcn_perm(b1.y, a1.y, 0x05040100u);
  pk[7] = __builtin_amdgcn_perm(b1.y, a1.y, 0x07060302u);
#pragma unroll
  for (int e=0;e<8;e++){
    const int row = dc*8 + e;
    *(uint32_t*)(dst + ((row*128 + vpos*2) ^ swz(row))) = pk[e];
  }
}

// ---------------- fused prep: 5x f32->bf16 convert + RoPE table -------------
__global__ void prep(const float* __restrict__ x,  const float* __restrict__ Wq,
                     const float* __restrict__ Wk, const float* __restrict__ Wv,
                     const float* __restrict__ Wo,
                     u16* __restrict__ xb, u16* __restrict__ wqkv,
                     u16* __restrict__ wob, float* __restrict__ tab)
{
  const int bid = blockIdx.x, tid = threadIdx.x;
  if (bid < 6144){
    const float* src; u16* dst; int lb;
    if      (bid < 4096){ src = x;  dst = xb;              lb = bid; }
    else if (bid < 4608){ src = Wq; dst = wqkv;            lb = bid-4096; }
    else if (bid < 5120){ src = Wk; dst = wqkv + 1048576;  lb = bid-4608; }
    else if (bid < 5632){ src = Wv; dst = wqkv + 2097152;  lb = bid-5120; }
    else                { src = Wo; dst = wob;             lb = bid-5632; }
    const size_t off = (size_t)lb*2048 + tid*8;
    float4 a = *(const float4*)(src+off);
    float4 b = *(const float4*)(src+off+4);
    bf16x8 o = { (__bf16)a.x,(__bf16)a.y,(__bf16)a.z,(__bf16)a.w,
                 (__bf16)b.x,(__bf16)b.y,(__bf16)b.z,(__bf16)b.w };
    *(bf16x8*)(dst+off) = o;
  } else {
    const int t = (bid-6144)*256 + tid;          // < 65536
    const int s = t >> 5, j = t & 31;
    double freq = exp(-(double)(2*j)/64.0*log(10000.0));
    double ang = (double)s*freq;
    tab[s*64 + 2*j]     = (float)cos(ang);
    tab[s*64 + 2*j + 1] = (float)sin(ang);
  }
}

// ---------------- GEMM: dst = A @ W^T + bias  (bf16 in, NT layout) ----------
// R8 two-barrier structure (dbuf reverted: m99/m131 lesson, measured -30us) +
// bank-uniform LDS swizzle: linear dest, pre-swizzled source, swizzled read.
template<int MODE>
__global__ __launch_bounds__(256, 2)
void gemm_bt(const u16* __restrict__ A, const u16* __restrict__ W,
             const float* __restrict__ b0, const float* __restrict__ b1,
             const float* __restrict__ b2, float* __restrict__ fout,
             u16* __restrict__ dq, u16* __restrict__ dk, u16* __restrict__ dv,
             const float* __restrict__ tab)
{
  __shared__ u16 Ab[128*32];
  __shared__ u16 Bb[128*32];
  const int tid = threadIdx.x;
  const int lane = tid & 63;
  const int w = tid >> 6, wr = w >> 1, wc = w & 1;
  const int m0 = blockIdx.y * 128;
  const int n0 = blockIdx.x * 128;
  const int c0 = lane & 15, g = lane >> 4;

  f32x4 acc[4][4] = {};

  const int sr = tid >> 2;                        // staging row 0..63
  const int sc16 = tid & 3;                       // 16B chunk in 64B row
  const int stoff = sr*64 + sc16*16;              // linear LDS dest (bytes)
  const int gsw = (sc16*16) ^ ((sr & 3) << 4);    // pre-swizzled global col
  const char* ga = (const char*)A + (size_t)(m0 + sr)*DMODEL*2 + gsw;
  const char* gb = (const char*)W + (size_t)(n0 + sr)*DMODEL*2 + gsw;

  for (int k0 = 0; k0 < DMODEL; k0 += 32) {
    __syncthreads();
    async16(ga + 2*k0,              (char*)Ab + stoff);
    async16(ga + 2*k0 + 128*DMODEL, (char*)Ab + stoff + 4096);
    async16(gb + 2*k0,              (char*)Bb + stoff);
    async16(gb + 2*k0 + 128*DMODEL, (char*)Bb + stoff + 4096);
    __syncthreads();
    bf16x8 afr[4], bfr[4];
#pragma unroll
    for (int i=0;i<4;i++){
      const int row = wr*64 + i*16 + c0;
      afr[i] = *(const bf16x8*)((const char*)Ab + row*64 + ((g*16) ^ ((row&3)<<4)));
    }
#pragma unroll
    for (int j=0;j<4;j++){
      const int row = wc*64 + j*16 + c0;
      bfr[j] = *(const bf16x8*)((const char*)Bb + row*64 + ((g*16) ^ ((row&3)<<4)));
    }
    __builtin_amdgcn_s_setprio(1);
#pragma unroll
    for (int i=0;i<4;i++)
#pragma unroll
      for (int j=0;j<4;j++)
        acc[i][j] = __builtin_amdgcn_mfma_f32_16x16x32_bf16(afr[i], bfr[j], acc[i][j], 0,0,0);
    __builtin_amdgcn_s_setprio(0);
  }

  const int nbase = n0 + wc*64;
  const int t = n0 >> 10;                 // 0=q 1=k 2=v (tiles never cross)
  const float* bias = (MODE==1) ? b0 : (t==0) ? b0 : (t==1) ? b1 : b2;
  float bv4[4];
#pragma unroll
  for (int j=0;j<4;j++) bv4[j] = bias[(nbase & 1023) + j*16 + c0];

  if (MODE == 0) {
    u16* dst = (t==0) ? dq : (t==1) ? dk : dv;
    const float qs = (t==0) ? 0.18033688011f : 1.0f;   // 0.125*log2(e)
    const int h = (nbase >> 6) & (NHEAD-1);
#pragma unroll
    for (int i=0;i<4;i++){
      const int mbase = m0 + wr*64 + i*16 + g*4;
#pragma unroll
      for (int r=0;r<4;r++){
        const int mm = mbase + r;
        const int bb = mm >> 11, s = mm & (SEQ-1);
        const size_t rowbase = (((size_t)(bb*NHEAD + h))*SEQ + s)*DH;
        if (t < 2) {
#pragma unroll
          for (int j2=0;j2<2;j2++){
            const int dh = j2*16 + c0;
            const float xl = acc[i][j2][r]   + bv4[j2];
            const float xh = acc[i][j2+2][r] + bv4[j2+2];
            const float2 cs = *(const float2*)(tab + (size_t)s*64 + dh*2);
            dst[rowbase + dh]      = cvt1((xl*cs.x - xh*cs.y)*qs);
            dst[rowbase + dh + 32] = cvt1((xh*cs.x + xl*cs.y)*qs);
          }
        } else {
#pragma unroll
          for (int j=0;j<4;j++)
            dst[rowbase + j*16 + c0] = cvt1(acc[i][j][r] + bv4[j]);
        }
      }
    }
  } else {
#pragma unroll
    for (int i=0;i<4;i++){
      const int mbase = m0 + wr*64 + i*16 + g*4;
#pragma unroll
      for (int j=0;j<4;j++){
#pragma unroll
        for (int r=0;r<4;r++)
          fout[(size_t)(mbase + r) * DMODEL + nbase + j*16 + c0] = acc[i][j][r] + bv4[j];
      }
    }
  }
}

// ---------------- Flash attention: 4 waves x 32q (QB=128), 32x32x16 ---------
// grid (64, 8): x = bh (XCD: id%8 = bh%8), y = pair; qt = pair / 15-pair
__global__ __launch_bounds__(256, 2)
void attn_fwd(const u16* __restrict__ Q, const u16* __restrict__ K,
              const u16* __restrict__ V, u16* __restrict__ O)
{
  __shared__ u16 Kb[2][64*64];  // [kv][dh], swizzled (pre-swizzled source)
  __shared__ u16 Vt[2][64*64];  // [dh][pos], swizzled; pos = sigma^-1(kv)
  const int bh = blockIdx.x;
  const int pair = blockIdx.y;              // 0..7
  const int tid = threadIdx.x, lane = tid & 63, w = tid >> 6;  // w in [0,4)
  const int c31 = lane & 31, hi = lane >> 5;
  const size_t hb = (size_t)bh * SEQ * DH;
  const int b = bh >> 4, h = bh & 15;

  // K staging: two async16 per thread (256 x 2 x 16B = 8KB tile)
  const int boff1 = tid*16;
  const int ksw1  = boff1 ^ swz(boff1 >> 7);
  const int boff2 = boff1 + 4096;
  const int ksw2  = boff2 ^ swz(boff2 >> 7);
  // V staging: kv pair (2rp,2rp+1), dh 8-chunk dc
  const int rp = tid >> 3, dc = tid & 7;
  const int kv0 = 2*rp;
  const int vpos = (kv0 & 0x33) | ((kv0 & 4) << 1) | ((kv0 & 8) >> 1);

#pragma unroll 1
  for (int half = 0; half < 2; half++){
    const int qt = half ? (15 - pair) : pair;
    const int qrow_base = qt*128 + w*32;
    const int jt_last  = 2*qt + 1;
    const int jt_end_w = 2*qt + (w>>1);     // this wave's diagonal tile
    const int q = qrow_base + c31;          // this lane's q-row

    bf16x8 qf[4];
#pragma unroll
    for (int kc=0;kc<4;kc++)
      qf[kc] = *(const bf16x8*)(Q + hb + (size_t)q*DH + kc*16 + hi*8);

    f32x16 oacc0 = {}, oacc1 = {};          // O^T[dh][q]
    float mrun = -3.0e38f, lrun = 0.f;

    // ---- prologue: stage tile 0 into buffer 0 ----
    {
      const char* gk = (const char*)(K + hb);
      async16(gk + ksw1, (char*)Kb[0] + boff1);
      async16(gk + ksw2, (char*)Kb[0] + boff2);
      const u16* gv = V + hb;
      uint2 a0 = *(const uint2*)(gv + (kv0  )*DH + dc*8);
      uint2 a1 = *(const uint2*)(gv + (kv0  )*DH + dc*8 + 4);
      uint2 b0 = *(const uint2*)(gv + (kv0+1)*DH + dc*8);
      uint2 b1 = *(const uint2*)(gv + (kv0+1)*DH + dc*8 + 4);
      vstore8((char*)Vt[0], a0, a1, b0, b1, dc, vpos);
    }
    __syncthreads();

    uint2 pa0, pa1, pb0, pb1;   // V prefetch regs
    for (int jt = 0; jt <= jt_last; jt++){
      const int cur = jt & 1, nxt = cur ^ 1;
      const bool pre = (jt < jt_last);
      if (pre){
        const char* gk = (const char*)(K + hb + (size_t)(jt+1)*64*DH);
        async16(gk + ksw1, (char*)Kb[nxt] + boff1);
        async16(gk + ksw2, (char*)Kb[nxt] + boff2);
        const u16* gv = V + hb + (size_t)(jt+1)*64*DH;
        pa0 = *(const uint2*)(gv + (kv0  )*DH + dc*8);
        pa1 = *(const uint2*)(gv + (kv0  )*DH + dc*8 + 4);
        pb0 = *(const uint2*)(gv + (kv0+1)*DH + dc*8);
        pb1 = *(const uint2*)(gv + (kv0+1)*DH + dc*8 + 4);
      }

      if (jt <= jt_end_w){
        // ---- S^T = K Q'^T : sT[kvb][r] = S[kv][q], kv=(r&3)+8(r>>2)+4hi ----
        f32x16 sT[2] = {};
#pragma unroll
        for (int kc=0;kc<4;kc++){
          const int col = (kc*16 + hi*8)*2;
          const int r0 = c31, r1 = 32 + c31;
          const bf16x8 kf0 = *(const bf16x8*)((const char*)Kb[cur] + ((r0*128 + col) ^ swz(r0)));
          const bf16x8 kf1 = *(const bf16x8*)((const char*)Kb[cur] + ((r1*128 + col) ^ swz(r1)));
          __builtin_amdgcn_s_setprio(1);
          sT[0] = __builtin_amdgcn_mfma_f32_32x32x16_bf16(kf0, qf[kc], sT[0], 0,0,0);
          sT[1] = __builtin_amdgcn_mfma_f32_32x32x16_bf16(kf1, qf[kc], sT[1], 0,0,0);
          __builtin_amdgcn_s_setprio(0);
        }
        // ---- causal mask: only this wave's diagonal tile ----
        if (jt == jt_end_w){
#pragma unroll
          for (int kvb=0;kvb<2;kvb++)
#pragma unroll
            for (int r=0;r<16;r++){
              const int kv = jt*64 + kvb*32 + (r&3) + 8*(r>>2) + 4*hi;
              sT[kvb][r] = (kv <= q) ? sT[kvb][r] : -3.0e38f;
            }
        }
        // ---- online softmax (exp2 domain; defer-max; parallel chains) ----
        float mx0 = -3.0e38f, mx1 = -3.0e38f;
#pragma unroll
        for (int r=0;r<16;r+=2){
          mx0 = max3f(mx0, sT[0][r], sT[0][r+1]);
          mx1 = max3f(mx1, sT[1][r], sT[1][r+1]);
        }
        float mx = fmaxf(mx0, mx1);
        mx = fmaxf(mx, __shfl_xor(mx, 32));
        const bool grow = __any(mx > mrun + 8.0f);
        float corr = 1.0f;
        if (grow){
          const float mnew = fmaxf(mrun, mx);
          corr = EXP2(mrun - mnew);
          mrun = mnew;
        }
        float ls[4] = {0.f, 0.f, 0.f, 0.f};
#pragma unroll
        for (int kvb=0;kvb<2;kvb++)
#pragma unroll
          for (int r=0;r<16;r++){
            const float p = EXP2(sT[kvb][r] - mrun);
            sT[kvb][r] = p;
            ls[r & 3] += p;
          }
        float lsum = (ls[0] + ls[1]) + (ls[2] + ls[3]);
        lsum += __shfl_xor(lsum, 32);
        lrun = lrun*corr + lsum;
        if (grow){
#pragma unroll
          for (int r=0;r<16;r++){ oacc0[r] *= corr; oacc1[r] *= corr; }
        }
        // ---- O^T += V^T P^T (P in-register; V sigma-permuted in LDS) ----
#pragma unroll
        for (int kvb=0;kvb<2;kvb++)
#pragma unroll
          for (int s=0;s<2;s++){
            union { bf16x8 v; uint32_t d[4]; } pa;
#pragma unroll
            for (int j=0;j<4;j++)
              pa.d[j] = cvt2(sT[kvb][s*8+2*j], sT[kvb][s*8+2*j+1]);
            const int col = (kvb*32 + s*16 + hi*8)*2;
            const int r0 = c31, r1 = 32 + c31;
            const bf16x8 vf0 = *(const bf16x8*)((const char*)Vt[cur] + ((r0*128 + col) ^ swz(r0)));
            const bf16x8 vf1 = *(const bf16x8*)((const char*)Vt[cur] + ((r1*128 + col) ^ swz(r1)));
            __builtin_amdgcn_s_setprio(1);
            oacc0 = __builtin_amdgcn_mfma_f32_32x32x16_bf16(vf0, pa.v, oacc0, 0,0,0);
            oacc1 = __builtin_amdgcn_mfma_f32_32x32x16_bf16(vf1, pa.v, oacc1, 0,0,0);
            __builtin_amdgcn_s_setprio(0);
          }
      }

      if (pre) vstore8((char*)Vt[nxt], pa0, pa1, pb0, pb1, dc, vpos);
      __syncthreads();
    }

    // ---- write attn output (per-lane q-col): O[b, q, h*64 + dh] ----
    {
      const float inv = 1.0f / lrun;
      u16* orow = O + ((size_t)b*SEQ + q)*DMODEL + h*DH;
#pragma unroll
      for (int r2=0;r2<8;r2++){
        const int dh0 = 2*(r2&1) + 8*(r2>>1) + 4*hi;
        *(uint32_t*)(orow + dh0)      = cvt2(oacc0[2*r2]*inv, oacc0[2*r2+1]*inv);
        *(uint32_t*)(orow + 32 + dh0) = cvt2(oacc1[2*r2]*inv, oacc1[2*r2+1]*inv);
      }
    }
  }
}

// ---------------------------------------------------------------------------
extern "C" void kernel_launch(void* const* d_in, const int* in_sizes, int n_in,
                              void* d_out, int out_size, void* d_ws, size_t ws_size,
                              hipStream_t stream)
{
  const float* x  = (const float*)d_in[0];
  const float* Wq = (const float*)d_in[1];
  const float* bq = (const float*)d_in[2];
  const float* Wk = (const float*)d_in[3];
  const float* bk = (const float*)d_in[4];
  const float* Wv = (const float*)d_in[5];
  const float* bv = (const float*)d_in[6];
  const float* Wo = (const float*)d_in[7];
  const float* bo = (const float*)d_in[8];
  // d_in[9]: causal mask (int32) — implemented analytically, not read.

  const size_t MB = 1024*1024;
  char* ws = (char*)d_ws;
  u16*  xb   = (u16*)(ws);                 // [0,16MB)  x bf16; dead after QKV
  u16*  aw   = (u16*)(ws);                 // attn out reuses region
  u16*  vw   = (u16*)(ws + 16*MB);         // [16,32MB) V [B,H,S,Dh]
  u16*  wqkv = (u16*)(ws + 32*MB);         // [32,38MB) Wq|Wk|Wv bf16 [3072][1024]
  u16*  wob  = (u16*)(ws + 38*MB);         // [38,40MB)
  float* tab = (float*)(ws + 41*MB);       // 512KB
  // d_out (32MB f32) doubles as scratch for q/k (bf16, dead before final GEMM)
  u16*  qw = (u16*)d_out;
  u16*  kw = (u16*)d_out + 8*MB;

  prep<<<dim3(6400), dim3(256), 0, stream>>>(x, Wq, Wk, Wv, Wo, xb, wqkv, wob, tab);

  // fused QKV projection + RoPE epilogue: N=3072
  gemm_bt<0><<<dim3(24, 64), dim3(256), 0, stream>>>(xb, wqkv, bq, bk, bv,
                                                     nullptr, qw, kw, vw, tab);

  attn_fwd<<<dim3(64, 8), dim3(256), 0, stream>>>(qw, kw, vw, aw);

  gemm_bt<1><<<dim3(8, 64), dim3(256), 0, stream>>>(aw, wob, bo, nullptr, nullptr,
                                                    (float*)d_out, nullptr, nullptr, nullptr, nullptr);
}

// Round 11
// 172.208 us; speedup vs baseline: 2.2718x; 1.0165x over previous
//
#include <hip/hip_runtime.h>
#include <stdint.h>

typedef unsigned short u16;
typedef __bf16 bf16x8 __attribute__((ext_vector_type(8)));
typedef __bf16 bf16x2 __attribute__((ext_vector_type(2)));
typedef float f32x4 __attribute__((ext_vector_type(4)));
typedef float f32x16 __attribute__((ext_vector_type(16)));

#define SEQ    2048
#define NHEAD  16
#define DH     64
#define DMODEL 1024
#define NBH    64     // B*H

// native bf16 converts (compiler emits v_cvt_pk_bf16_f32 for pairs)
__device__ __forceinline__ u16 cvt1(float f){
  union { __bf16 h; u16 u; } c; c.h = (__bf16)f; return c.u;
}
__device__ __forceinline__ uint32_t cvt2(float a, float b){
  union { bf16x2 v; uint32_t u; } c; c.v = bf16x2{(__bf16)a, (__bf16)b}; return c.u;
}
// LDS XOR-swizzle: bits 4-6 (keeps 16B alignment for b128 reads)
__device__ __forceinline__ int swz(int row){ return (((row&7)^((row>>3)&7))<<4); }

#if __has_builtin(__builtin_amdgcn_exp2f)
__device__ __forceinline__ float EXP2(float x){ return __builtin_amdgcn_exp2f(x); }
#else
__device__ __forceinline__ float EXP2(float x){ return exp2f(x); }
#endif
__device__ __forceinline__ float max3f(float a, float b, float c){
  float r; asm("v_max3_f32 %0, %1, %2, %3" : "=v"(r) : "v"(a), "v"(b), "v"(c));
  return r;
}

typedef const __attribute__((address_space(1))) uint32_t* gas_t;
typedef __attribute__((address_space(3))) uint32_t* las_t;
__device__ __forceinline__ void async16(const void* g, void* l){
  __builtin_amdgcn_global_load_lds((gas_t)g, (las_t)l, 16, 0, 0);
}

// pack V rows (kv0, kv0+1) into sigma-permuted transposed LDS tile via v_perm
__device__ __forceinline__ void vstore8(char* dst, uint2 a0, uint2 a1,
                                        uint2 b0, uint2 b1, int dc, int vpos){
  uint32_t pk[8];
  pk[0] = __builtin_amdgcn_perm(b0.x, a0.x, 0x05040100u);
  pk[1] = __builtin_amdgcn_perm(b0.x, a0.x, 0x07060302u);
  pk[2] = __builtin_amdgcn_perm(b0.y, a0.y, 0x05040100u);
  pk[3] = __builtin_amdgcn_perm(b0.y, a0.y, 0x07060302u);
  pk[4] = __builtin_amdgcn_perm(b1.x, a1.x, 0x05040100u);
  pk[5] = __builtin_amdgcn_perm(b1.x, a1.x, 0x07060302u);
  pk[6] = __builtin_amdgcn_perm(b1.y, a1.y, 0x05040100u);
  pk[7] = __builtin_amdgcn_perm(b1.y, a1.y, 0x07060302u);
#pragma unroll
  for (int e=0;e<8;e++){
    const int row = dc*8 + e;
    *(uint32_t*)(dst + ((row*128 + vpos*2) ^ swz(row))) = pk[e];
  }
}

// ---------------- fused prep: 5x f32->bf16 convert + RoPE table -------------
__global__ void prep(const float* __restrict__ x,  const float* __restrict__ Wq,
                     const float* __restrict__ Wk, const float* __restrict__ Wv,
                     const float* __restrict__ Wo,
                     u16* __restrict__ xb, u16* __restrict__ wqkv,
                     u16* __restrict__ wob, float* __restrict__ tab)
{
  const int bid = blockIdx.x, tid = threadIdx.x;
  if (bid < 6144){
    const float* src; u16* dst; int lb;
    if      (bid < 4096){ src = x;  dst = xb;              lb = bid; }
    else if (bid < 4608){ src = Wq; dst = wqkv;            lb = bid-4096; }
    else if (bid < 5120){ src = Wk; dst = wqkv + 1048576;  lb = bid-4608; }
    else if (bid < 5632){ src = Wv; dst = wqkv + 2097152;  lb = bid-5120; }
    else                { src = Wo; dst = wob;             lb = bid-5632; }
    const size_t off = (size_t)lb*2048 + tid*8;
    float4 a = *(const float4*)(src+off);
    float4 b = *(const float4*)(src+off+4);
    bf16x8 o = { (__bf16)a.x,(__bf16)a.y,(__bf16)a.z,(__bf16)a.w,
                 (__bf16)b.x,(__bf16)b.y,(__bf16)b.z,(__bf16)b.w };
    *(bf16x8*)(dst+off) = o;
  } else {
    const int t = (bid-6144)*256 + tid;          // < 65536
    const int s = t >> 5, j = t & 31;
    double freq = exp(-(double)(2*j)/64.0*log(10000.0));
    double ang = (double)s*freq;
    tab[s*64 + 2*j]     = (float)cos(ang);
    tab[s*64 + 2*j + 1] = (float)sin(ang);
  }
}

// ---------------- GEMM: dst = A @ W^T + bias  (bf16 in, NT layout) ----------
// Double-buffered LDS + RAW s_barrier + counted vmcnt(4) (T4): tile k+1's
// global_load_lds stay in flight across the barrier while tile k computes.
// (The __syncthreads drain — vmcnt(0) per iter — was the 2-phase stall.)
template<int MODE>
__global__ __launch_bounds__(256, 2)
void gemm_bt(const u16* __restrict__ A, const u16* __restrict__ W,
             const float* __restrict__ b0, const float* __restrict__ b1,
             const float* __restrict__ b2, float* __restrict__ fout,
             u16* __restrict__ dq, u16* __restrict__ dk, u16* __restrict__ dv,
             const float* __restrict__ tab)
{
  __shared__ u16 Ab[2][128*32];
  __shared__ u16 Bb[2][128*32];
  const int tid = threadIdx.x;
  const int lane = tid & 63;
  const int w = tid >> 6, wr = w >> 1, wc = w & 1;
  const int m0 = blockIdx.y * 128;
  const int n0 = blockIdx.x * 128;
  const int c0 = lane & 15, g = lane >> 4;

  f32x4 acc[4][4] = {};

  const int sr = tid >> 2;                        // staging row 0..63
  const int sc16 = tid & 3;                       // 16B chunk in 64B row
  const int stoff = sr*64 + sc16*16;              // linear LDS dest (bytes)
  const int gsw = (sc16*16) ^ ((sr & 3) << 4);    // pre-swizzled global col
  const char* ga = (const char*)A + (size_t)(m0 + sr)*DMODEL*2 + gsw;
  const char* gb = (const char*)W + (size_t)(n0 + sr)*DMODEL*2 + gsw;

#define STAGE_G(buf, kk) do{ \
    async16(ga + 2*(kk),              (char*)Ab[buf] + stoff); \
    async16(ga + 2*(kk) + 128*DMODEL, (char*)Ab[buf] + stoff + 4096); \
    async16(gb + 2*(kk),              (char*)Bb[buf] + stoff); \
    async16(gb + 2*(kk) + 128*DMODEL, (char*)Bb[buf] + stoff + 4096); \
  }while(0)

#define COMPUTE_G(buf) do{ \
    bf16x8 afr[4], bfr[4]; \
    _Pragma("unroll") \
    for (int i=0;i<4;i++){ \
      const int row = wr*64 + i*16 + c0; \
      afr[i] = *(const bf16x8*)((const char*)Ab[buf] + row*64 + ((g*16) ^ ((row&3)<<4))); \
    } \
    _Pragma("unroll") \
    for (int j=0;j<4;j++){ \
      const int row = wc*64 + j*16 + c0; \
      bfr[j] = *(const bf16x8*)((const char*)Bb[buf] + row*64 + ((g*16) ^ ((row&3)<<4))); \
    } \
    __builtin_amdgcn_s_setprio(1); \
    _Pragma("unroll") \
    for (int i=0;i<4;i++) \
      _Pragma("unroll") \
      for (int j=0;j<4;j++) \
        acc[i][j] = __builtin_amdgcn_mfma_f32_16x16x32_bf16(afr[i], bfr[j], acc[i][j], 0,0,0); \
    __builtin_amdgcn_s_setprio(0); \
  }while(0)

  STAGE_G(0, 0);
#pragma unroll 2
  for (int k0 = 0; k0 < DMODEL - 32; k0 += 32) {
    const int cur = (k0 >> 5) & 1;
    STAGE_G(cur ^ 1, k0 + 32);                       // 4 new in flight
    asm volatile("s_waitcnt vmcnt(4)" ::: "memory"); // oldest 4 (cur) landed
    __builtin_amdgcn_s_barrier();
    __builtin_amdgcn_sched_barrier(0);
    COMPUTE_G(cur);
    __builtin_amdgcn_s_barrier();                    // all reads of cur done
    __builtin_amdgcn_sched_barrier(0);
  }
  asm volatile("s_waitcnt vmcnt(0)" ::: "memory");
  __builtin_amdgcn_s_barrier();
  __builtin_amdgcn_sched_barrier(0);
  COMPUTE_G(1);                                      // last tile: buf 1
#undef STAGE_G
#undef COMPUTE_G

  const int nbase = n0 + wc*64;
  const int t = n0 >> 10;                 // 0=q 1=k 2=v (tiles never cross)
  const float* bias = (MODE==1) ? b0 : (t==0) ? b0 : (t==1) ? b1 : b2;
  float bv4[4];
#pragma unroll
  for (int j=0;j<4;j++) bv4[j] = bias[(nbase & 1023) + j*16 + c0];

  if (MODE == 0) {
    u16* dst = (t==0) ? dq : (t==1) ? dk : dv;
    const float qs = (t==0) ? 0.18033688011f : 1.0f;   // 0.125*log2(e)
    const int h = (nbase >> 6) & (NHEAD-1);
#pragma unroll
    for (int i=0;i<4;i++){
      const int mbase = m0 + wr*64 + i*16 + g*4;
#pragma unroll
      for (int r=0;r<4;r++){
        const int mm = mbase + r;
        const int bb = mm >> 11, s = mm & (SEQ-1);
        const size_t rowbase = (((size_t)(bb*NHEAD + h))*SEQ + s)*DH;
        if (t < 2) {
#pragma unroll
          for (int j2=0;j2<2;j2++){
            const int dh = j2*16 + c0;
            const float xl = acc[i][j2][r]   + bv4[j2];
            const float xh = acc[i][j2+2][r] + bv4[j2+2];
            const float2 cs = *(const float2*)(tab + (size_t)s*64 + dh*2);
            dst[rowbase + dh]      = cvt1((xl*cs.x - xh*cs.y)*qs);
            dst[rowbase + dh + 32] = cvt1((xh*cs.x + xl*cs.y)*qs);
          }
        } else {
#pragma unroll
          for (int j=0;j<4;j++)
            dst[rowbase + j*16 + c0] = cvt1(acc[i][j][r] + bv4[j]);
        }
      }
    }
  } else {
#pragma unroll
    for (int i=0;i<4;i++){
      const int mbase = m0 + wr*64 + i*16 + g*4;
#pragma unroll
      for (int j=0;j<4;j++){
#pragma unroll
        for (int r=0;r<4;r++)
          fout[(size_t)(mbase + r) * DMODEL + nbase + j*16 + c0] = acc[i][j][r] + bv4[j];
      }
    }
  }
}

// ---------------- Flash attention: 4 waves x 32q (QB=128), 32x32x16 ---------
// grid (64, 8): x = bh (XCD: id%8 = bh%8), y = pair; qt = pair / 15-pair
__global__ __launch_bounds__(256, 2)
void attn_fwd(const u16* __restrict__ Q, const u16* __restrict__ K,
              const u16* __restrict__ V, u16* __restrict__ O)
{
  __shared__ u16 Kb[2][64*64];  // [kv][dh], swizzled (pre-swizzled source)
  __shared__ u16 Vt[2][64*64];  // [dh][pos], swizzled; pos = sigma^-1(kv)
  const int bh = blockIdx.x;
  const int pair = blockIdx.y;              // 0..7
  const int tid = threadIdx.x, lane = tid & 63, w = tid >> 6;  // w in [0,4)
  const int c31 = lane & 31, hi = lane >> 5;
  const size_t hb = (size_t)bh * SEQ * DH;
  const int b = bh >> 4, h = bh & 15;

  // K staging: two async16 per thread (256 x 2 x 16B = 8KB tile)
  const int boff1 = tid*16;
  const int ksw1  = boff1 ^ swz(boff1 >> 7);
  const int boff2 = boff1 + 4096;
  const int ksw2  = boff2 ^ swz(boff2 >> 7);
  // V staging: kv pair (2rp,2rp+1), dh 8-chunk dc
  const int rp = tid >> 3, dc = tid & 7;
  const int kv0 = 2*rp;
  const int vpos = (kv0 & 0x33) | ((kv0 & 4) << 1) | ((kv0 & 8) >> 1);

#pragma unroll 1
  for (int half = 0; half < 2; half++){
    const int qt = half ? (15 - pair) : pair;
    const int qrow_base = qt*128 + w*32;
    const int jt_last  = 2*qt + 1;
    const int jt_end_w = 2*qt + (w>>1);     // this wave's diagonal tile
    const int q = qrow_base + c31;          // this lane's q-row

    bf16x8 qf[4];
#pragma unroll
    for (int kc=0;kc<4;kc++)
      qf[kc] = *(const bf16x8*)(Q + hb + (size_t)q*DH + kc*16 + hi*8);

    f32x16 oacc0 = {}, oacc1 = {};          // O^T[dh][q]
    float mrun = -3.0e38f, lrun = 0.f;

    // ---- prologue: stage tile 0 into buffer 0 ----
    {
      const char* gk = (const char*)(K + hb);
      async16(gk + ksw1, (char*)Kb[0] + boff1);
      async16(gk + ksw2, (char*)Kb[0] + boff2);
      const u16* gv = V + hb;
      uint2 a0 = *(const uint2*)(gv + (kv0  )*DH + dc*8);
      uint2 a1 = *(const uint2*)(gv + (kv0  )*DH + dc*8 + 4);
      uint2 b0 = *(const uint2*)(gv + (kv0+1)*DH + dc*8);
      uint2 b1 = *(const uint2*)(gv + (kv0+1)*DH + dc*8 + 4);
      vstore8((char*)Vt[0], a0, a1, b0, b1, dc, vpos);
    }
    __syncthreads();

    uint2 pa0, pa1, pb0, pb1;   // V prefetch regs
    for (int jt = 0; jt <= jt_last; jt++){
      const int cur = jt & 1, nxt = cur ^ 1;
      const bool pre = (jt < jt_last);
      if (pre){
        const char* gk = (const char*)(K + hb + (size_t)(jt+1)*64*DH);
        async16(gk + ksw1, (char*)Kb[nxt] + boff1);
        async16(gk + ksw2, (char*)Kb[nxt] + boff2);
        const u16* gv = V + hb + (size_t)(jt+1)*64*DH;
        pa0 = *(const uint2*)(gv + (kv0  )*DH + dc*8);
        pa1 = *(const uint2*)(gv + (kv0  )*DH + dc*8 + 4);
        pb0 = *(const uint2*)(gv + (kv0+1)*DH + dc*8);
        pb1 = *(const uint2*)(gv + (kv0+1)*DH + dc*8 + 4);
      }

      if (jt <= jt_end_w){
        // ---- S^T = K Q'^T : sT[kvb][r] = S[kv][q], kv=(r&3)+8(r>>2)+4hi ----
        f32x16 sT[2] = {};
#pragma unroll
        for (int kc=0;kc<4;kc++){
          const int col = (kc*16 + hi*8)*2;
          const int r0 = c31, r1 = 32 + c31;
          const bf16x8 kf0 = *(const bf16x8*)((const char*)Kb[cur] + ((r0*128 + col) ^ swz(r0)));
          const bf16x8 kf1 = *(const bf16x8*)((const char*)Kb[cur] + ((r1*128 + col) ^ swz(r1)));
          __builtin_amdgcn_s_setprio(1);
          sT[0] = __builtin_amdgcn_mfma_f32_32x32x16_bf16(kf0, qf[kc], sT[0], 0,0,0);
          sT[1] = __builtin_amdgcn_mfma_f32_32x32x16_bf16(kf1, qf[kc], sT[1], 0,0,0);
          __builtin_amdgcn_s_setprio(0);
        }
        // ---- causal mask: only this wave's diagonal tile ----
        if (jt == jt_end_w){
#pragma unroll
          for (int kvb=0;kvb<2;kvb++)
#pragma unroll
            for (int r=0;r<16;r++){
              const int kv = jt*64 + kvb*32 + (r&3) + 8*(r>>2) + 4*hi;
              sT[kvb][r] = (kv <= q) ? sT[kvb][r] : -3.0e38f;
            }
        }
        // ---- online softmax (exp2 domain; defer-max; parallel chains) ----
        float mx0 = -3.0e38f, mx1 = -3.0e38f;
#pragma unroll
        for (int r=0;r<16;r+=2){
          mx0 = max3f(mx0, sT[0][r], sT[0][r+1]);
          mx1 = max3f(mx1, sT[1][r], sT[1][r+1]);
        }
        float mx = fmaxf(mx0, mx1);
        mx = fmaxf(mx, __shfl_xor(mx, 32));
        const bool grow = __any(mx > mrun + 8.0f);
        float corr = 1.0f;
        if (grow){
          const float mnew = fmaxf(mrun, mx);
          corr = EXP2(mrun - mnew);
          mrun = mnew;
        }
        float ls[4] = {0.f, 0.f, 0.f, 0.f};
#pragma unroll
        for (int kvb=0;kvb<2;kvb++)
#pragma unroll
          for (int r=0;r<16;r++){
            const float p = EXP2(sT[kvb][r] - mrun);
            sT[kvb][r] = p;
            ls[r & 3] += p;
          }
        float lsum = (ls[0] + ls[1]) + (ls[2] + ls[3]);
        lsum += __shfl_xor(lsum, 32);
        lrun = lrun*corr + lsum;
        if (grow){
#pragma unroll
          for (int r=0;r<16;r++){ oacc0[r] *= corr; oacc1[r] *= corr; }
        }
        // ---- O^T += V^T P^T (P in-register; V sigma-permuted in LDS) ----
#pragma unroll
        for (int kvb=0;kvb<2;kvb++)
#pragma unroll
          for (int s=0;s<2;s++){
            union { bf16x8 v; uint32_t d[4]; } pa;
#pragma unroll
            for (int j=0;j<4;j++)
              pa.d[j] = cvt2(sT[kvb][s*8+2*j], sT[kvb][s*8+2*j+1]);
            const int col = (kvb*32 + s*16 + hi*8)*2;
            const int r0 = c31, r1 = 32 + c31;
            const bf16x8 vf0 = *(const bf16x8*)((const char*)Vt[cur] + ((r0*128 + col) ^ swz(r0)));
            const bf16x8 vf1 = *(const bf16x8*)((const char*)Vt[cur] + ((r1*128 + col) ^ swz(r1)));
            __builtin_amdgcn_s_setprio(1);
            oacc0 = __builtin_amdgcn_mfma_f32_32x32x16_bf16(vf0, pa.v, oacc0, 0,0,0);
            oacc1 = __builtin_amdgcn_mfma_f32_32x32x16_bf16(vf1, pa.v, oacc1, 0,0,0);
            __builtin_amdgcn_s_setprio(0);
          }
      }

      if (pre) vstore8((char*)Vt[nxt], pa0, pa1, pb0, pb1, dc, vpos);
      __syncthreads();
    }

    // ---- write attn output (per-lane q-col): O[b, q, h*64 + dh] ----
    {
      const float inv = 1.0f / lrun;
      u16* orow = O + ((size_t)b*SEQ + q)*DMODEL + h*DH;
#pragma unroll
      for (int r2=0;r2<8;r2++){
        const int dh0 = 2*(r2&1) + 8*(r2>>1) + 4*hi;
        *(uint32_t*)(orow + dh0)      = cvt2(oacc0[2*r2]*inv, oacc0[2*r2+1]*inv);
        *(uint32_t*)(orow + 32 + dh0) = cvt2(oacc1[2*r2]*inv, oacc1[2*r2+1]*inv);
      }
    }
  }
}

// ---------------------------------------------------------------------------
extern "C" void kernel_launch(void* const* d_in, const int* in_sizes, int n_in,
                              void* d_out, int out_size, void* d_ws, size_t ws_size,
                              hipStream_t stream)
{
  const float* x  = (const float*)d_in[0];
  const float* Wq = (const float*)d_in[1];
  const float* bq = (const float*)d_in[2];
  const float* Wk = (const float*)d_in[3];
  const float* bk = (const float*)d_in[4];
  const float* Wv = (const float*)d_in[5];
  const float* bv = (const float*)d_in[6];
  const float* Wo = (const float*)d_in[7];
  const float* bo = (const float*)d_in[8];
  // d_in[9]: causal mask (int32) — implemented analytically, not read.

  const size_t MB = 1024*1024;
  char* ws = (char*)d_ws;
  u16*  xb   = (u16*)(ws);                 // [0,16MB)  x bf16; dead after QKV
  u16*  aw   = (u16*)(ws);                 // attn out reuses region
  u16*  vw   = (u16*)(ws + 16*MB);         // [16,32MB) V [B,H,S,Dh]
  u16*  wqkv = (u16*)(ws + 32*MB);         // [32,38MB) Wq|Wk|Wv bf16 [3072][1024]
  u16*  wob  = (u16*)(ws + 38*MB);         // [38,40MB)
  float* tab = (float*)(ws + 41*MB);       // 512KB
  // d_out (32MB f32) doubles as scratch for q/k (bf16, dead before final GEMM)
  u16*  qw = (u16*)d_out;
  u16*  kw = (u16*)d_out + 8*MB;

  prep<<<dim3(6400), dim3(256), 0, stream>>>(x, Wq, Wk, Wv, Wo, xb, wqkv, wob, tab);

  // fused QKV projection + RoPE epilogue: N=3072
  gemm_bt<0><<<dim3(24, 64), dim3(256), 0, stream>>>(xb, wqkv, bq, bk, bv,
                                                     nullptr, qw, kw, vw, tab);

  attn_fwd<<<dim3(64, 8), dim3(256), 0, stream>>>(qw, kw, vw, aw);

  gemm_bt<1><<<dim3(8, 64), dim3(256), 0, stream>>>(aw, wob, bo, nullptr, nullptr,
                                                    (float*)d_out, nullptr, nullptr, nullptr, nullptr);
}

// Round 12
// 166.303 us; speedup vs baseline: 2.3525x; 1.0355x over previous
//
#include <hip/hip_runtime.h>
#include <stdint.h>

typedef unsigned short u16;
typedef __bf16 bf16x8 __attribute__((ext_vector_type(8)));
typedef __bf16 bf16x2 __attribute__((ext_vector_type(2)));
typedef float f32x4 __attribute__((ext_vector_type(4)));
typedef float f32x16 __attribute__((ext_vector_type(16)));

#define SEQ    2048
#define NHEAD  16
#define DH     64
#define DMODEL 1024
#define NBH    64     // B*H

// native bf16 converts (compiler emits v_cvt_pk_bf16_f32 for pairs)
__device__ __forceinline__ u16 cvt1(float f){
  union { __bf16 h; u16 u; } c; c.h = (__bf16)f; return c.u;
}
__device__ __forceinline__ uint32_t cvt2(float a, float b){
  union { bf16x2 v; uint32_t u; } c; c.v = bf16x2{(__bf16)a, (__bf16)b}; return c.u;
}
// LDS XOR-swizzle: bits 4-6 (keeps 16B alignment for b128 reads)
__device__ __forceinline__ int swz(int row){ return (((row&7)^((row>>3)&7))<<4); }

#if __has_builtin(__builtin_amdgcn_exp2f)
__device__ __forceinline__ float EXP2(float x){ return __builtin_amdgcn_exp2f(x); }
#else
__device__ __forceinline__ float EXP2(float x){ return exp2f(x); }
#endif
__device__ __forceinline__ float max3f(float a, float b, float c){
  float r; asm("v_max3_f32 %0, %1, %2, %3" : "=v"(r) : "v"(a), "v"(b), "v"(c));
  return r;
}

typedef const __attribute__((address_space(1))) uint32_t* gas_t;
typedef __attribute__((address_space(3))) uint32_t* las_t;
__device__ __forceinline__ void async16(const void* g, void* l){
  __builtin_amdgcn_global_load_lds((gas_t)g, (las_t)l, 16, 0, 0);
}

// pack V rows (kv0, kv0+1) into sigma-permuted transposed LDS tile via v_perm
__device__ __forceinline__ void vstore8(char* dst, uint2 a0, uint2 a1,
                                        uint2 b0, uint2 b1, int dc, int vpos){
  uint32_t pk[8];
  pk[0] = __builtin_amdgcn_perm(b0.x, a0.x, 0x05040100u);
  pk[1] = __builtin_amdgcn_perm(b0.x, a0.x, 0x07060302u);
  pk[2] = __builtin_amdgcn_perm(b0.y, a0.y, 0x05040100u);
  pk[3] = __builtin_amdgcn_perm(b0.y, a0.y, 0x07060302u);
  pk[4] = __builtin_amdgcn_perm(b1.x, a1.x, 0x05040100u);
  pk[5] = __builtin_amdgcn_perm(b1.x, a1.x, 0x07060302u);
  pk[6] = __builtin_amdgcn_perm(b1.y, a1.y, 0x05040100u);
  pk[7] = __builtin_amdgcn_perm(b1.y, a1.y, 0x07060302u);
#pragma unroll
  for (int e=0;e<8;e++){
    const int row = dc*8 + e;
    *(uint32_t*)(dst + ((row*128 + vpos*2) ^ swz(row))) = pk[e];
  }
}

// ---------------- fused prep: 5x f32->bf16 convert + RoPE table -------------
__global__ void prep(const float* __restrict__ x,  const float* __restrict__ Wq,
                     const float* __restrict__ Wk, const float* __restrict__ Wv,
                     const float* __restrict__ Wo,
                     u16* __restrict__ xb, u16* __restrict__ wqkv,
                     u16* __restrict__ wob, float* __restrict__ tab)
{
  const int bid = blockIdx.x, tid = threadIdx.x;
  if (bid < 6144){
    const float* src; u16* dst; int lb;
    if      (bid < 4096){ src = x;  dst = xb;              lb = bid; }
    else if (bid < 4608){ src = Wq; dst = wqkv;            lb = bid-4096; }
    else if (bid < 5120){ src = Wk; dst = wqkv + 1048576;  lb = bid-4608; }
    else if (bid < 5632){ src = Wv; dst = wqkv + 2097152;  lb = bid-5120; }
    else                { src = Wo; dst = wob;             lb = bid-5632; }
    const size_t off = (size_t)lb*2048 + tid*8;
    float4 a = *(const float4*)(src+off);
    float4 b = *(const float4*)(src+off+4);
    bf16x8 o = { (__bf16)a.x,(__bf16)a.y,(__bf16)a.z,(__bf16)a.w,
                 (__bf16)b.x,(__bf16)b.y,(__bf16)b.z,(__bf16)b.w };
    *(bf16x8*)(dst+off) = o;
  } else {
    const int t = (bid-6144)*256 + tid;          // < 65536
    const int s = t >> 5, j = t & 31;
    double freq = exp(-(double)(2*j)/64.0*log(10000.0));
    double ang = (double)s*freq;
    tab[s*64 + 2*j]     = (float)cos(ang);
    tab[s*64 + 2*j + 1] = (float)sin(ang);
  }
}

// ---------------- GEMM: dst = A @ W^T + bias  (bf16 in, NT layout) ----------
// XCD-aware 1D block remap: xcd = id%8 owns an 8-M-tile slice -> its A-panel
// (2MB) stays L2-resident. Triple-buffered LDS, 2-deep prefetch, counted
// vmcnt(8): loads for tiles k+1,k+2 stay in flight across barriers.
template<int MODE>
__global__ __launch_bounds__(256, 2)
void gemm_bt(const u16* __restrict__ A, const u16* __restrict__ W,
             const float* __restrict__ b0, const float* __restrict__ b1,
             const float* __restrict__ b2, float* __restrict__ fout,
             u16* __restrict__ dq, u16* __restrict__ dk, u16* __restrict__ dv,
             const float* __restrict__ tab)
{
  __shared__ u16 Ab[3][128*32];
  __shared__ u16 Bb[3][128*32];
  const int tid = threadIdx.x;
  const int lane = tid & 63;
  const int w = tid >> 6, wr = w >> 1, wc = w & 1;
  const int id = blockIdx.x;
  const int bx = id >> 6;                              // N tile
  const int by = ((id & 7) << 3) | ((id >> 3) & 7);    // M tile (XCD-sliced)
  const int m0 = by * 128;
  const int n0 = bx * 128;
  const int c0 = lane & 15, g = lane >> 4;

  f32x4 acc[4][4] = {};

  const int sr = tid >> 2;                        // staging row 0..63
  const int sc16 = tid & 3;                       // 16B chunk in 64B row
  const int stoff = sr*64 + sc16*16;              // linear LDS dest (bytes)
  const int gsw = (sc16*16) ^ ((sr & 3) << 4);    // pre-swizzled global col
  const char* ga = (const char*)A + (size_t)(m0 + sr)*DMODEL*2 + gsw;
  const char* gb = (const char*)W + (size_t)(n0 + sr)*DMODEL*2 + gsw;

#define STAGE_G(buf, kk) do{ \
    async16(ga + 2*(kk),              (char*)Ab[buf] + stoff); \
    async16(ga + 2*(kk) + 128*DMODEL, (char*)Ab[buf] + stoff + 4096); \
    async16(gb + 2*(kk),              (char*)Bb[buf] + stoff); \
    async16(gb + 2*(kk) + 128*DMODEL, (char*)Bb[buf] + stoff + 4096); \
  }while(0)

#define COMPUTE_G(buf) do{ \
    bf16x8 afr[4], bfr[4]; \
    _Pragma("unroll") \
    for (int i=0;i<4;i++){ \
      const int row = wr*64 + i*16 + c0; \
      afr[i] = *(const bf16x8*)((const char*)Ab[buf] + row*64 + ((g*16) ^ ((row&3)<<4))); \
    } \
    _Pragma("unroll") \
    for (int j=0;j<4;j++){ \
      const int row = wc*64 + j*16 + c0; \
      bfr[j] = *(const bf16x8*)((const char*)Bb[buf] + row*64 + ((g*16) ^ ((row&3)<<4))); \
    } \
    __builtin_amdgcn_s_setprio(1); \
    _Pragma("unroll") \
    for (int i=0;i<4;i++) \
      _Pragma("unroll") \
      for (int j=0;j<4;j++) \
        acc[i][j] = __builtin_amdgcn_mfma_f32_16x16x32_bf16(afr[i], bfr[j], acc[i][j], 0,0,0); \
    __builtin_amdgcn_s_setprio(0); \
  }while(0)

#define PHASE_G(itv, sb, cb) do{ \
    STAGE_G(sb, ((itv)+2)*32); \
    asm volatile("s_waitcnt vmcnt(8)" ::: "memory"); \
    __builtin_amdgcn_s_barrier(); \
    __builtin_amdgcn_sched_barrier(0); \
    COMPUTE_G(cb); \
    __builtin_amdgcn_s_barrier(); \
    __builtin_amdgcn_sched_barrier(0); \
  }while(0)

  STAGE_G(0, 0);
  STAGE_G(1, 32);
#pragma unroll 1
  for (int j3 = 0; j3 < 10; ++j3) {     // iters 0..29, buffers cycle 0,1,2
    const int it = 3*j3;
    PHASE_G(it,   2, 0);
    PHASE_G(it+1, 0, 1);
    PHASE_G(it+2, 1, 2);
  }
  // epilogue: iters 30, 31 (no more staging)
  asm volatile("s_waitcnt vmcnt(4)" ::: "memory");
  __builtin_amdgcn_s_barrier();
  __builtin_amdgcn_sched_barrier(0);
  COMPUTE_G(0);
  __builtin_amdgcn_s_barrier();
  __builtin_amdgcn_sched_barrier(0);
  asm volatile("s_waitcnt vmcnt(0)" ::: "memory");
  __builtin_amdgcn_s_barrier();
  __builtin_amdgcn_sched_barrier(0);
  COMPUTE_G(1);
#undef STAGE_G
#undef COMPUTE_G
#undef PHASE_G

  const int nbase = n0 + wc*64;
  const int t = n0 >> 10;                 // 0=q 1=k 2=v (tiles never cross)
  const float* bias = (MODE==1) ? b0 : (t==0) ? b0 : (t==1) ? b1 : b2;
  float bv4[4];
#pragma unroll
  for (int j=0;j<4;j++) bv4[j] = bias[(nbase & 1023) + j*16 + c0];

  if (MODE == 0) {
    u16* dst = (t==0) ? dq : (t==1) ? dk : dv;
    const float qs = (t==0) ? 0.18033688011f : 1.0f;   // 0.125*log2(e)
    const int h = (nbase >> 6) & (NHEAD-1);
#pragma unroll
    for (int i=0;i<4;i++){
      const int mbase = m0 + wr*64 + i*16 + g*4;
#pragma unroll
      for (int r=0;r<4;r++){
        const int mm = mbase + r;
        const int bb = mm >> 11, s = mm & (SEQ-1);
        const size_t rowbase = (((size_t)(bb*NHEAD + h))*SEQ + s)*DH;
        if (t < 2) {
#pragma unroll
          for (int j2=0;j2<2;j2++){
            const int dh = j2*16 + c0;
            const float xl = acc[i][j2][r]   + bv4[j2];
            const float xh = acc[i][j2+2][r] + bv4[j2+2];
            const float2 cs = *(const float2*)(tab + (size_t)s*64 + dh*2);
            dst[rowbase + dh]      = cvt1((xl*cs.x - xh*cs.y)*qs);
            dst[rowbase + dh + 32] = cvt1((xh*cs.x + xl*cs.y)*qs);
          }
        } else {
#pragma unroll
          for (int j=0;j<4;j++)
            dst[rowbase + j*16 + c0] = cvt1(acc[i][j][r] + bv4[j]);
        }
      }
    }
  } else {
#pragma unroll
    for (int i=0;i<4;i++){
      const int mbase = m0 + wr*64 + i*16 + g*4;
#pragma unroll
      for (int j=0;j<4;j++){
#pragma unroll
        for (int r=0;r<4;r++)
          fout[(size_t)(mbase + r) * DMODEL + nbase + j*16 + c0] = acc[i][j][r] + bv4[j];
      }
    }
  }
}

// ---------------- Flash attention: 4 waves x 32q (QB=128), 32x32x16 ---------
// grid (64, 8): x = bh (XCD: id%8 = bh%8), y = pair; qt = pair / 15-pair
__global__ __launch_bounds__(256, 2)
void attn_fwd(const u16* __restrict__ Q, const u16* __restrict__ K,
              const u16* __restrict__ V, u16* __restrict__ O)
{
  __shared__ u16 Kb[2][64*64];  // [kv][dh], swizzled (pre-swizzled source)
  __shared__ u16 Vt[2][64*64];  // [dh][pos], swizzled; pos = sigma^-1(kv)
  const int bh = blockIdx.x;
  const int pair = blockIdx.y;              // 0..7
  const int tid = threadIdx.x, lane = tid & 63, w = tid >> 6;  // w in [0,4)
  const int c31 = lane & 31, hi = lane >> 5;
  const size_t hb = (size_t)bh * SEQ * DH;
  const int b = bh >> 4, h = bh & 15;

  // K staging: two async16 per thread (256 x 2 x 16B = 8KB tile)
  const int boff1 = tid*16;
  const int ksw1  = boff1 ^ swz(boff1 >> 7);
  const int boff2 = boff1 + 4096;
  const int ksw2  = boff2 ^ swz(boff2 >> 7);
  // V staging: kv pair (2rp,2rp+1), dh 8-chunk dc
  const int rp = tid >> 3, dc = tid & 7;
  const int kv0 = 2*rp;
  const int vpos = (kv0 & 0x33) | ((kv0 & 4) << 1) | ((kv0 & 8) >> 1);

#pragma unroll 1
  for (int half = 0; half < 2; half++){
    const int qt = half ? (15 - pair) : pair;
    const int qrow_base = qt*128 + w*32;
    const int jt_last  = 2*qt + 1;
    const int jt_end_w = 2*qt + (w>>1);     // this wave's diagonal tile
    const int q = qrow_base + c31;          // this lane's q-row

    bf16x8 qf[4];
#pragma unroll
    for (int kc=0;kc<4;kc++)
      qf[kc] = *(const bf16x8*)(Q + hb + (size_t)q*DH + kc*16 + hi*8);

    f32x16 oacc0 = {}, oacc1 = {};          // O^T[dh][q]
    float mrun = -3.0e38f, lrun = 0.f;

    // ---- prologue: stage tile 0 into buffer 0 ----
    {
      const char* gk = (const char*)(K + hb);
      async16(gk + ksw1, (char*)Kb[0] + boff1);
      async16(gk + ksw2, (char*)Kb[0] + boff2);
      const u16* gv = V + hb;
      uint2 a0 = *(const uint2*)(gv + (kv0  )*DH + dc*8);
      uint2 a1 = *(const uint2*)(gv + (kv0  )*DH + dc*8 + 4);
      uint2 b0 = *(const uint2*)(gv + (kv0+1)*DH + dc*8);
      uint2 b1 = *(const uint2*)(gv + (kv0+1)*DH + dc*8 + 4);
      vstore8((char*)Vt[0], a0, a1, b0, b1, dc, vpos);
    }
    __syncthreads();

    uint2 pa0, pa1, pb0, pb1;   // V prefetch regs
    for (int jt = 0; jt <= jt_last; jt++){
      const int cur = jt & 1, nxt = cur ^ 1;
      const bool pre = (jt < jt_last);
      if (pre){
        const char* gk = (const char*)(K + hb + (size_t)(jt+1)*64*DH);
        async16(gk + ksw1, (char*)Kb[nxt] + boff1);
        async16(gk + ksw2, (char*)Kb[nxt] + boff2);
        const u16* gv = V + hb + (size_t)(jt+1)*64*DH;
        pa0 = *(const uint2*)(gv + (kv0  )*DH + dc*8);
        pa1 = *(const uint2*)(gv + (kv0  )*DH + dc*8 + 4);
        pb0 = *(const uint2*)(gv + (kv0+1)*DH + dc*8);
        pb1 = *(const uint2*)(gv + (kv0+1)*DH + dc*8 + 4);
      }

      if (jt <= jt_end_w){
        // ---- S^T = K Q'^T : sT[kvb][r] = S[kv][q], kv=(r&3)+8(r>>2)+4hi ----
        f32x16 sT[2] = {};
#pragma unroll
        for (int kc=0;kc<4;kc++){
          const int col = (kc*16 + hi*8)*2;
          const int r0 = c31, r1 = 32 + c31;
          const bf16x8 kf0 = *(const bf16x8*)((const char*)Kb[cur] + ((r0*128 + col) ^ swz(r0)));
          const bf16x8 kf1 = *(const bf16x8*)((const char*)Kb[cur] + ((r1*128 + col) ^ swz(r1)));
          __builtin_amdgcn_s_setprio(1);
          sT[0] = __builtin_amdgcn_mfma_f32_32x32x16_bf16(kf0, qf[kc], sT[0], 0,0,0);
          sT[1] = __builtin_amdgcn_mfma_f32_32x32x16_bf16(kf1, qf[kc], sT[1], 0,0,0);
          __builtin_amdgcn_s_setprio(0);
        }
        // ---- causal mask: only this wave's diagonal tile ----
        if (jt == jt_end_w){
#pragma unroll
          for (int kvb=0;kvb<2;kvb++)
#pragma unroll
            for (int r=0;r<16;r++){
              const int kv = jt*64 + kvb*32 + (r&3) + 8*(r>>2) + 4*hi;
              sT[kvb][r] = (kv <= q) ? sT[kvb][r] : -3.0e38f;
            }
        }
        // ---- online softmax (exp2 domain; defer-max; parallel chains) ----
        float mx0 = -3.0e38f, mx1 = -3.0e38f;
#pragma unroll
        for (int r=0;r<16;r+=2){
          mx0 = max3f(mx0, sT[0][r], sT[0][r+1]);
          mx1 = max3f(mx1, sT[1][r], sT[1][r+1]);
        }
        float mx = fmaxf(mx0, mx1);
        mx = fmaxf(mx, __shfl_xor(mx, 32));
        const bool grow = __any(mx > mrun + 8.0f);
        float corr = 1.0f;
        if (grow){
          const float mnew = fmaxf(mrun, mx);
          corr = EXP2(mrun - mnew);
          mrun = mnew;
        }
        float ls[4] = {0.f, 0.f, 0.f, 0.f};
#pragma unroll
        for (int kvb=0;kvb<2;kvb++)
#pragma unroll
          for (int r=0;r<16;r++){
            const float p = EXP2(sT[kvb][r] - mrun);
            sT[kvb][r] = p;
            ls[r & 3] += p;
          }
        float lsum = (ls[0] + ls[1]) + (ls[2] + ls[3]);
        lsum += __shfl_xor(lsum, 32);
        lrun = lrun*corr + lsum;
        if (grow){
#pragma unroll
          for (int r=0;r<16;r++){ oacc0[r] *= corr; oacc1[r] *= corr; }
        }
        // ---- O^T += V^T P^T (P in-register; V sigma-permuted in LDS) ----
#pragma unroll
        for (int kvb=0;kvb<2;kvb++)
#pragma unroll
          for (int s=0;s<2;s++){
            union { bf16x8 v; uint32_t d[4]; } pa;
#pragma unroll
            for (int j=0;j<4;j++)
              pa.d[j] = cvt2(sT[kvb][s*8+2*j], sT[kvb][s*8+2*j+1]);
            const int col = (kvb*32 + s*16 + hi*8)*2;
            const int r0 = c31, r1 = 32 + c31;
            const bf16x8 vf0 = *(const bf16x8*)((const char*)Vt[cur] + ((r0*128 + col) ^ swz(r0)));
            const bf16x8 vf1 = *(const bf16x8*)((const char*)Vt[cur] + ((r1*128 + col) ^ swz(r1)));
            __builtin_amdgcn_s_setprio(1);
            oacc0 = __builtin_amdgcn_mfma_f32_32x32x16_bf16(vf0, pa.v, oacc0, 0,0,0);
            oacc1 = __builtin_amdgcn_mfma_f32_32x32x16_bf16(vf1, pa.v, oacc1, 0,0,0);
            __builtin_amdgcn_s_setprio(0);
          }
      }

      if (pre) vstore8((char*)Vt[nxt], pa0, pa1, pb0, pb1, dc, vpos);
      __syncthreads();
    }

    // ---- write attn output (per-lane q-col): O[b, q, h*64 + dh] ----
    {
      const float inv = 1.0f / lrun;
      u16* orow = O + ((size_t)b*SEQ + q)*DMODEL + h*DH;
#pragma unroll
      for (int r2=0;r2<8;r2++){
        const int dh0 = 2*(r2&1) + 8*(r2>>1) + 4*hi;
        *(uint32_t*)(orow + dh0)      = cvt2(oacc0[2*r2]*inv, oacc0[2*r2+1]*inv);
        *(uint32_t*)(orow + 32 + dh0) = cvt2(oacc1[2*r2]*inv, oacc1[2*r2+1]*inv);
      }
    }
  }
}

// ---------------------------------------------------------------------------
extern "C" void kernel_launch(void* const* d_in, const int* in_sizes, int n_in,
                              void* d_out, int out_size, void* d_ws, size_t ws_size,
                              hipStream_t stream)
{
  const float* x  = (const float*)d_in[0];
  const float* Wq = (const float*)d_in[1];
  const float* bq = (const float*)d_in[2];
  const float* Wk = (const float*)d_in[3];
  const float* bk = (const float*)d_in[4];
  const float* Wv = (const float*)d_in[5];
  const float* bv = (const float*)d_in[6];
  const float* Wo = (const float*)d_in[7];
  const float* bo = (const float*)d_in[8];
  // d_in[9]: causal mask (int32) — implemented analytically, not read.

  const size_t MB = 1024*1024;
  char* ws = (char*)d_ws;
  u16*  xb   = (u16*)(ws);                 // [0,16MB)  x bf16; dead after QKV
  u16*  aw   = (u16*)(ws);                 // attn out reuses region
  u16*  vw   = (u16*)(ws + 16*MB);         // [16,32MB) V [B,H,S,Dh]
  u16*  wqkv = (u16*)(ws + 32*MB);         // [32,38MB) Wq|Wk|Wv bf16 [3072][1024]
  u16*  wob  = (u16*)(ws + 38*MB);         // [38,40MB)
  float* tab = (float*)(ws + 41*MB);       // 512KB
  // d_out (32MB f32) doubles as scratch for q/k (bf16, dead before final GEMM)
  u16*  qw = (u16*)d_out;
  u16*  kw = (u16*)d_out + 8*MB;

  prep<<<dim3(6400), dim3(256), 0, stream>>>(x, Wq, Wk, Wv, Wo, xb, wqkv, wob, tab);

  // fused QKV projection + RoPE epilogue: N=3072 (1D grid, XCD-remapped)
  gemm_bt<0><<<dim3(1536), dim3(256), 0, stream>>>(xb, wqkv, bq, bk, bv,
                                                   nullptr, qw, kw, vw, tab);

  attn_fwd<<<dim3(64, 8), dim3(256), 0, stream>>>(qw, kw, vw, aw);

  gemm_bt<1><<<dim3(512), dim3(256), 0, stream>>>(aw, wob, bo, nullptr, nullptr,
                                                  (float*)d_out, nullptr, nullptr, nullptr, nullptr);
}

// Round 13
// 162.921 us; speedup vs baseline: 2.4013x; 1.0208x over previous
//
#include <hip/hip_runtime.h>
#include <stdint.h>

typedef unsigned short u16;
typedef __bf16 bf16x8 __attribute__((ext_vector_type(8)));
typedef __bf16 bf16x2 __attribute__((ext_vector_type(2)));
typedef float f32x4 __attribute__((ext_vector_type(4)));
typedef float f32x16 __attribute__((ext_vector_type(16)));

#define SEQ    2048
#define NHEAD  16
#define DH     64
#define DMODEL 1024
#define NBH    64     // B*H

// native bf16 converts (compiler emits v_cvt_pk_bf16_f32 for pairs)
__device__ __forceinline__ u16 cvt1(float f){
  union { __bf16 h; u16 u; } c; c.h = (__bf16)f; return c.u;
}
__device__ __forceinline__ uint32_t cvt2(float a, float b){
  union { bf16x2 v; uint32_t u; } c; c.v = bf16x2{(__bf16)a, (__bf16)b}; return c.u;
}
// LDS XOR-swizzle: bits 4-6 (keeps 16B alignment for b128 reads)
__device__ __forceinline__ int swz(int row){ return (((row&7)^((row>>3)&7))<<4); }

#if __has_builtin(__builtin_amdgcn_exp2f)
__device__ __forceinline__ float EXP2(float x){ return __builtin_amdgcn_exp2f(x); }
#else
__device__ __forceinline__ float EXP2(float x){ return exp2f(x); }
#endif
__device__ __forceinline__ float max3f(float a, float b, float c){
  float r; asm("v_max3_f32 %0, %1, %2, %3" : "=v"(r) : "v"(a), "v"(b), "v"(c));
  return r;
}

typedef const __attribute__((address_space(1))) uint32_t* gas_t;
typedef __attribute__((address_space(3))) uint32_t* las_t;
__device__ __forceinline__ void async16(const void* g, void* l){
  __builtin_amdgcn_global_load_lds((gas_t)g, (las_t)l, 16, 0, 0);
}

// pack V rows (kv0, kv0+1) into sigma-permuted transposed LDS tile via v_perm
__device__ __forceinline__ void vstore8(char* dst, uint2 a0, uint2 a1,
                                        uint2 b0, uint2 b1, int dc, int vpos){
  uint32_t pk[8];
  pk[0] = __builtin_amdgcn_perm(b0.x, a0.x, 0x05040100u);
  pk[1] = __builtin_amdgcn_perm(b0.x, a0.x, 0x07060302u);
  pk[2] = __builtin_amdgcn_perm(b0.y, a0.y, 0x05040100u);
  pk[3] = __builtin_amdgcn_perm(b0.y, a0.y, 0x07060302u);
  pk[4] = __builtin_amdgcn_perm(b1.x, a1.x, 0x05040100u);
  pk[5] = __builtin_amdgcn_perm(b1.x, a1.x, 0x07060302u);
  pk[6] = __builtin_amdgcn_perm(b1.y, a1.y, 0x05040100u);
  pk[7] = __builtin_amdgcn_perm(b1.y, a1.y, 0x07060302u);
#pragma unroll
  for (int e=0;e<8;e++){
    const int row = dc*8 + e;
    *(uint32_t*)(dst + ((row*128 + vpos*2) ^ swz(row))) = pk[e];
  }
}

// ---------------- fused prep: 5x f32->bf16 convert + RoPE table -------------
__global__ void prep(const float* __restrict__ x,  const float* __restrict__ Wq,
                     const float* __restrict__ Wk, const float* __restrict__ Wv,
                     const float* __restrict__ Wo,
                     u16* __restrict__ xb, u16* __restrict__ wqkv,
                     u16* __restrict__ wob, float* __restrict__ tab)
{
  const int bid = blockIdx.x, tid = threadIdx.x;
  if (bid < 6144){
    const float* src; u16* dst; int lb;
    if      (bid < 4096){ src = x;  dst = xb;              lb = bid; }
    else if (bid < 4608){ src = Wq; dst = wqkv;            lb = bid-4096; }
    else if (bid < 5120){ src = Wk; dst = wqkv + 1048576;  lb = bid-4608; }
    else if (bid < 5632){ src = Wv; dst = wqkv + 2097152;  lb = bid-5120; }
    else                { src = Wo; dst = wob;             lb = bid-5632; }
    const size_t off = (size_t)lb*2048 + tid*8;
    float4 a = *(const float4*)(src+off);
    float4 b = *(const float4*)(src+off+4);
    bf16x8 o = { (__bf16)a.x,(__bf16)a.y,(__bf16)a.z,(__bf16)a.w,
                 (__bf16)b.x,(__bf16)b.y,(__bf16)b.z,(__bf16)b.w };
    *(bf16x8*)(dst+off) = o;
  } else {
    const int t = (bid-6144)*256 + tid;          // < 65536
    const int s = t >> 5, j = t & 31;
    double freq = exp(-(double)(2*j)/64.0*log(10000.0));
    double ang = (double)s*freq;
    tab[s*64 + 2*j]     = (float)cos(ang);
    tab[s*64 + 2*j + 1] = (float)sin(ang);
  }
}

// ---------------- GEMM: dst = A @ W^T + bias  (bf16 in, NT layout) ----------
// BK=64: 16 K-iterations (was 32) -> halves the per-barrier-pair fixed cost
// that R10/R11 isolated as the bottleneck. 128B LDS rows with 3-bit XOR
// swizzle (2-way bank access = free); linear LDS dest + pre-swizzled global
// source (rule #21). XCD-aware 1D block remap kept. dbuf + counted vmcnt(8).
template<int MODE>
__global__ __launch_bounds__(256, 2)
void gemm_bt(const u16* __restrict__ A, const u16* __restrict__ W,
             const float* __restrict__ b0, const float* __restrict__ b1,
             const float* __restrict__ b2, float* __restrict__ fout,
             u16* __restrict__ dq, u16* __restrict__ dk, u16* __restrict__ dv,
             const float* __restrict__ tab)
{
  __shared__ u16 Ab[2][128*64];   // 16KB per buffer
  __shared__ u16 Bb[2][128*64];
  const int tid = threadIdx.x;
  const int lane = tid & 63;
  const int w = tid >> 6, wr = w >> 1, wc = w & 1;
  const int id = blockIdx.x;
  const int bx = id >> 6;                              // N tile
  const int by = ((id & 7) << 3) | ((id >> 3) & 7);    // M tile (XCD-sliced)
  const int m0 = by * 128;
  const int n0 = bx * 128;
  const int c0 = lane & 15, g = lane >> 4;

  f32x4 acc[4][4] = {};

  // staging: thread covers rows (tid>>3)+{0,32,64,96}, 16B chunk (tid&7),
  // global col pre-swizzled by row&7 (row&7 == (tid>>3)&7 for all 4 rows)
  const int srow = tid >> 3;
  const int gcol = (((tid & 7) ^ (srow & 7)) << 4);
  const char* ga = (const char*)A + (size_t)(m0 + srow)*2048 + gcol;
  const char* gb = (const char*)W + (size_t)(n0 + srow)*2048 + gcol;
  const int ldst = tid*16;

#define STAGE_G(buf, kbyte) do{ \
    _Pragma("unroll") \
    for (int k=0;k<4;k++){ \
      async16(ga + (kbyte) + k*32*2048, (char*)Ab[buf] + k*4096 + ldst); \
      async16(gb + (kbyte) + k*32*2048, (char*)Bb[buf] + k*4096 + ldst); \
    } \
  }while(0)

#define COMPUTE_G(buf) do{ \
    bf16x8 afr[2][4], bfr[2][4]; \
    _Pragma("unroll") \
    for (int kk=0;kk<2;kk++){ \
      _Pragma("unroll") \
      for (int i=0;i<4;i++){ \
        const int ra = wr*64 + i*16 + c0; \
        afr[kk][i] = *(const bf16x8*)((const char*)Ab[buf] + ra*128 + ((((kk*4+g) ^ (ra&7))) << 4)); \
        const int rb = wc*64 + i*16 + c0; \
        bfr[kk][i] = *(const bf16x8*)((const char*)Bb[buf] + rb*128 + ((((kk*4+g) ^ (rb&7))) << 4)); \
      } \
    } \
    __builtin_amdgcn_s_setprio(1); \
    _Pragma("unroll") \
    for (int kk=0;kk<2;kk++) \
      _Pragma("unroll") \
      for (int i=0;i<4;i++) \
        _Pragma("unroll") \
        for (int j=0;j<4;j++) \
          acc[i][j] = __builtin_amdgcn_mfma_f32_16x16x32_bf16(afr[kk][i], bfr[kk][j], acc[i][j], 0,0,0); \
    __builtin_amdgcn_s_setprio(0); \
  }while(0)

  STAGE_G(0, 0);
#pragma unroll 1
  for (int it = 0; it < 15; ++it) {
    const int cur = it & 1;
    STAGE_G(cur ^ 1, (it+1)*128);                    // 8 new loads in flight
    asm volatile("s_waitcnt vmcnt(8)" ::: "memory"); // oldest 8 (cur) landed
    __builtin_amdgcn_s_barrier();
    __builtin_amdgcn_sched_barrier(0);
    COMPUTE_G(cur);
    __builtin_amdgcn_s_barrier();                    // all reads of cur done
    __builtin_amdgcn_sched_barrier(0);
  }
  asm volatile("s_waitcnt vmcnt(0)" ::: "memory");
  __builtin_amdgcn_s_barrier();
  __builtin_amdgcn_sched_barrier(0);
  COMPUTE_G(1);                                      // tile 15 in buf 1
#undef STAGE_G
#undef COMPUTE_G

  const int nbase = n0 + wc*64;
  const int t = n0 >> 10;                 // 0=q 1=k 2=v (tiles never cross)
  const float* bias = (MODE==1) ? b0 : (t==0) ? b0 : (t==1) ? b1 : b2;
  float bv4[4];
#pragma unroll
  for (int j=0;j<4;j++) bv4[j] = bias[(nbase & 1023) + j*16 + c0];

  if (MODE == 0) {
    u16* dst = (t==0) ? dq : (t==1) ? dk : dv;
    const float qs = (t==0) ? 0.18033688011f : 1.0f;   // 0.125*log2(e)
    const int h = (nbase >> 6) & (NHEAD-1);
#pragma unroll
    for (int i=0;i<4;i++){
      const int mbase = m0 + wr*64 + i*16 + g*4;
#pragma unroll
      for (int r=0;r<4;r++){
        const int mm = mbase + r;
        const int bb = mm >> 11, s = mm & (SEQ-1);
        const size_t rowbase = (((size_t)(bb*NHEAD + h))*SEQ + s)*DH;
        if (t < 2) {
#pragma unroll
          for (int j2=0;j2<2;j2++){
            const int dh = j2*16 + c0;
            const float xl = acc[i][j2][r]   + bv4[j2];
            const float xh = acc[i][j2+2][r] + bv4[j2+2];
            const float2 cs = *(const float2*)(tab + (size_t)s*64 + dh*2);
            dst[rowbase + dh]      = cvt1((xl*cs.x - xh*cs.y)*qs);
            dst[rowbase + dh + 32] = cvt1((xh*cs.x + xl*cs.y)*qs);
          }
        } else {
#pragma unroll
          for (int j=0;j<4;j++)
            dst[rowbase + j*16 + c0] = cvt1(acc[i][j][r] + bv4[j]);
        }
      }
    }
  } else {
#pragma unroll
    for (int i=0;i<4;i++){
      const int mbase = m0 + wr*64 + i*16 + g*4;
#pragma unroll
      for (int j=0;j<4;j++){
#pragma unroll
        for (int r=0;r<4;r++)
          fout[(size_t)(mbase + r) * DMODEL + nbase + j*16 + c0] = acc[i][j][r] + bv4[j];
      }
    }
  }
}

// ---------------- Flash attention: 4 waves x 32q (QB=128), 32x32x16 ---------
// grid (64, 8): x = bh (XCD: id%8 = bh%8), y = pair; qt = pair / 15-pair
__global__ __launch_bounds__(256, 2)
void attn_fwd(const u16* __restrict__ Q, const u16* __restrict__ K,
              const u16* __restrict__ V, u16* __restrict__ O)
{
  __shared__ u16 Kb[2][64*64];  // [kv][dh], swizzled (pre-swizzled source)
  __shared__ u16 Vt[2][64*64];  // [dh][pos], swizzled; pos = sigma^-1(kv)
  const int bh = blockIdx.x;
  const int pair = blockIdx.y;              // 0..7
  const int tid = threadIdx.x, lane = tid & 63, w = tid >> 6;  // w in [0,4)
  const int c31 = lane & 31, hi = lane >> 5;
  const size_t hb = (size_t)bh * SEQ * DH;
  const int b = bh >> 4, h = bh & 15;

  // K staging: two async16 per thread (256 x 2 x 16B = 8KB tile)
  const int boff1 = tid*16;
  const int ksw1  = boff1 ^ swz(boff1 >> 7);
  const int boff2 = boff1 + 4096;
  const int ksw2  = boff2 ^ swz(boff2 >> 7);
  // V staging: kv pair (2rp,2rp+1), dh 8-chunk dc
  const int rp = tid >> 3, dc = tid & 7;
  const int kv0 = 2*rp;
  const int vpos = (kv0 & 0x33) | ((kv0 & 4) << 1) | ((kv0 & 8) >> 1);

#pragma unroll 1
  for (int half = 0; half < 2; half++){
    const int qt = half ? (15 - pair) : pair;
    const int qrow_base = qt*128 + w*32;
    const int jt_last  = 2*qt + 1;
    const int jt_end_w = 2*qt + (w>>1);     // this wave's diagonal tile
    const int q = qrow_base + c31;          // this lane's q-row

    bf16x8 qf[4];
#pragma unroll
    for (int kc=0;kc<4;kc++)
      qf[kc] = *(const bf16x8*)(Q + hb + (size_t)q*DH + kc*16 + hi*8);

    f32x16 oacc0 = {}, oacc1 = {};          // O^T[dh][q]
    float mrun = -3.0e38f, lrun = 0.f;

    // ---- prologue: stage tile 0 into buffer 0 ----
    {
      const char* gk = (const char*)(K + hb);
      async16(gk + ksw1, (char*)Kb[0] + boff1);
      async16(gk + ksw2, (char*)Kb[0] + boff2);
      const u16* gv = V + hb;
      uint2 a0 = *(const uint2*)(gv + (kv0  )*DH + dc*8);
      uint2 a1 = *(const uint2*)(gv + (kv0  )*DH + dc*8 + 4);
      uint2 b0 = *(const uint2*)(gv + (kv0+1)*DH + dc*8);
      uint2 b1 = *(const uint2*)(gv + (kv0+1)*DH + dc*8 + 4);
      vstore8((char*)Vt[0], a0, a1, b0, b1, dc, vpos);
    }
    __syncthreads();

    uint2 pa0, pa1, pb0, pb1;   // V prefetch regs
    for (int jt = 0; jt <= jt_last; jt++){
      const int cur = jt & 1, nxt = cur ^ 1;
      const bool pre = (jt < jt_last);
      if (pre){
        const char* gk = (const char*)(K + hb + (size_t)(jt+1)*64*DH);
        async16(gk + ksw1, (char*)Kb[nxt] + boff1);
        async16(gk + ksw2, (char*)Kb[nxt] + boff2);
        const u16* gv = V + hb + (size_t)(jt+1)*64*DH;
        pa0 = *(const uint2*)(gv + (kv0  )*DH + dc*8);
        pa1 = *(const uint2*)(gv + (kv0  )*DH + dc*8 + 4);
        pb0 = *(const uint2*)(gv + (kv0+1)*DH + dc*8);
        pb1 = *(const uint2*)(gv + (kv0+1)*DH + dc*8 + 4);
      }

      if (jt <= jt_end_w){
        // ---- S^T = K Q'^T : sT[kvb][r] = S[kv][q], kv=(r&3)+8(r>>2)+4hi ----
        f32x16 sT[2] = {};
#pragma unroll
        for (int kc=0;kc<4;kc++){
          const int col = (kc*16 + hi*8)*2;
          const int r0 = c31, r1 = 32 + c31;
          const bf16x8 kf0 = *(const bf16x8*)((const char*)Kb[cur] + ((r0*128 + col) ^ swz(r0)));
          const bf16x8 kf1 = *(const bf16x8*)((const char*)Kb[cur] + ((r1*128 + col) ^ swz(r1)));
          __builtin_amdgcn_s_setprio(1);
          sT[0] = __builtin_amdgcn_mfma_f32_32x32x16_bf16(kf0, qf[kc], sT[0], 0,0,0);
          sT[1] = __builtin_amdgcn_mfma_f32_32x32x16_bf16(kf1, qf[kc], sT[1], 0,0,0);
          __builtin_amdgcn_s_setprio(0);
        }
        // ---- causal mask: only this wave's diagonal tile ----
        if (jt == jt_end_w){
#pragma unroll
          for (int kvb=0;kvb<2;kvb++)
#pragma unroll
            for (int r=0;r<16;r++){
              const int kv = jt*64 + kvb*32 + (r&3) + 8*(r>>2) + 4*hi;
              sT[kvb][r] = (kv <= q) ? sT[kvb][r] : -3.0e38f;
            }
        }
        // ---- online softmax (exp2 domain; defer-max; parallel chains) ----
        float mx0 = -3.0e38f, mx1 = -3.0e38f;
#pragma unroll
        for (int r=0;r<16;r+=2){
          mx0 = max3f(mx0, sT[0][r], sT[0][r+1]);
          mx1 = max3f(mx1, sT[1][r], sT[1][r+1]);
        }
        float mx = fmaxf(mx0, mx1);
        mx = fmaxf(mx, __shfl_xor(mx, 32));
        const bool grow = __any(mx > mrun + 8.0f);
        float corr = 1.0f;
        if (grow){
          const float mnew = fmaxf(mrun, mx);
          corr = EXP2(mrun - mnew);
          mrun = mnew;
        }
        float ls[4] = {0.f, 0.f, 0.f, 0.f};
#pragma unroll
        for (int kvb=0;kvb<2;kvb++)
#pragma unroll
          for (int r=0;r<16;r++){
            const float p = EXP2(sT[kvb][r] - mrun);
            sT[kvb][r] = p;
            ls[r & 3] += p;
          }
        float lsum = (ls[0] + ls[1]) + (ls[2] + ls[3]);
        lsum += __shfl_xor(lsum, 32);
        lrun = lrun*corr + lsum;
        if (grow){
#pragma unroll
          for (int r=0;r<16;r++){ oacc0[r] *= corr; oacc1[r] *= corr; }
        }
        // ---- O^T += V^T P^T (P in-register; V sigma-permuted in LDS) ----
#pragma unroll
        for (int kvb=0;kvb<2;kvb++)
#pragma unroll
          for (int s=0;s<2;s++){
            union { bf16x8 v; uint32_t d[4]; } pa;
#pragma unroll
            for (int j=0;j<4;j++)
              pa.d[j] = cvt2(sT[kvb][s*8+2*j], sT[kvb][s*8+2*j+1]);
            const int col = (kvb*32 + s*16 + hi*8)*2;
            const int r0 = c31, r1 = 32 + c31;
            const bf16x8 vf0 = *(const bf16x8*)((const char*)Vt[cur] + ((r0*128 + col) ^ swz(r0)));
            const bf16x8 vf1 = *(const bf16x8*)((const char*)Vt[cur] + ((r1*128 + col) ^ swz(r1)));
            __builtin_amdgcn_s_setprio(1);
            oacc0 = __builtin_amdgcn_mfma_f32_32x32x16_bf16(vf0, pa.v, oacc0, 0,0,0);
            oacc1 = __builtin_amdgcn_mfma_f32_32x32x16_bf16(vf1, pa.v, oacc1, 0,0,0);
            __builtin_amdgcn_s_setprio(0);
          }
      }

      if (pre) vstore8((char*)Vt[nxt], pa0, pa1, pb0, pb1, dc, vpos);
      __syncthreads();
    }

    // ---- write attn output (per-lane q-col): O[b, q, h*64 + dh] ----
    {
      const float inv = 1.0f / lrun;
      u16* orow = O + ((size_t)b*SEQ + q)*DMODEL + h*DH;
#pragma unroll
      for (int r2=0;r2<8;r2++){
        const int dh0 = 2*(r2&1) + 8*(r2>>1) + 4*hi;
        *(uint32_t*)(orow + dh0)      = cvt2(oacc0[2*r2]*inv, oacc0[2*r2+1]*inv);
        *(uint32_t*)(orow + 32 + dh0) = cvt2(oacc1[2*r2]*inv, oacc1[2*r2+1]*inv);
      }
    }
  }
}

// ---------------------------------------------------------------------------
extern "C" void kernel_launch(void* const* d_in, const int* in_sizes, int n_in,
                              void* d_out, int out_size, void* d_ws, size_t ws_size,
                              hipStream_t stream)
{
  const float* x  = (const float*)d_in[0];
  const float* Wq = (const float*)d_in[1];
  const float* bq = (const float*)d_in[2];
  const float* Wk = (const float*)d_in[3];
  const float* bk = (const float*)d_in[4];
  const float* Wv = (const float*)d_in[5];
  const float* bv = (const float*)d_in[6];
  const float* Wo = (const float*)d_in[7];
  const float* bo = (const float*)d_in[8];
  // d_in[9]: causal mask (int32) — implemented analytically, not read.

  const size_t MB = 1024*1024;
  char* ws = (char*)d_ws;
  u16*  xb   = (u16*)(ws);                 // [0,16MB)  x bf16; dead after QKV
  u16*  aw   = (u16*)(ws);                 // attn out reuses region
  u16*  vw   = (u16*)(ws + 16*MB);         // [16,32MB) V [B,H,S,Dh]
  u16*  wqkv = (u16*)(ws + 32*MB);         // [32,38MB) Wq|Wk|Wv bf16 [3072][1024]
  u16*  wob  = (u16*)(ws + 38*MB);         // [38,40MB)
  float* tab = (float*)(ws + 41*MB);       // 512KB
  // d_out (32MB f32) doubles as scratch for q/k (bf16, dead before final GEMM)
  u16*  qw = (u16*)d_out;
  u16*  kw = (u16*)d_out + 8*MB;

  prep<<<dim3(6400), dim3(256), 0, stream>>>(x, Wq, Wk, Wv, Wo, xb, wqkv, wob, tab);

  // fused QKV projection + RoPE epilogue: N=3072 (1D grid, XCD-remapped)
  gemm_bt<0><<<dim3(1536), dim3(256), 0, stream>>>(xb, wqkv, bq, bk, bv,
                                                   nullptr, qw, kw, vw, tab);

  attn_fwd<<<dim3(64, 8), dim3(256), 0, stream>>>(qw, kw, vw, aw);

  gemm_bt<1><<<dim3(512), dim3(256), 0, stream>>>(aw, wob, bo, nullptr, nullptr,
                                                  (float*)d_out, nullptr, nullptr, nullptr, nullptr);
}